// Round 1
// baseline (4377.584 us; speedup 1.0000x reference)
//
#include <hip/hip_runtime.h>
#include <stdint.h>

#define TT 4
#define BB 8
#define NN 2048
#define KNB 16
#define PP (NN*KNB)
#define VTH 1.0f
#define EPSB 1e-5f

typedef unsigned long long u64;
typedef unsigned int u32;
typedef unsigned char u8;

__device__ __forceinline__ float lif_step(float& v, float x) {
    v = v + (x - v) / 2.0f;
    float s = (v - VTH >= 0.0f) ? 1.0f : 0.0f;
    v = v * (1.0f - s);
    return s;
}

// ---------------- T-Net ----------------
// conv1: 3->64, input identical across t; pack spikes as 64-bit mask per (t,b,n)
__global__ __launch_bounds__(256) void k_tnet1(const float* __restrict__ x, const float* __restrict__ w,
        const float* __restrict__ bi, u64* __restrict__ s1b) {
    int i = blockIdx.x*256 + threadIdx.x;
    int b = i >> 11, n = i & 2047;
    float p0 = x[((size_t)b*14+0)*NN+n];
    float p1 = x[((size_t)b*14+1)*NN+n];
    float p2 = x[((size_t)b*14+2)*NN+n];
    u64 m[TT] = {0,0,0,0};
    for (int d = 0; d < 64; ++d) {
        float z = ((w[d*3+0]*p0 + w[d*3+1]*p1) + w[d*3+2]*p2) + bi[d];
        float v = 0.f;
        #pragma unroll
        for (int t = 0; t < TT; ++t) {
            float s = lif_step(v, z);
            if (s != 0.f) m[t] |= (1ull << d);
        }
    }
    #pragma unroll
    for (int t = 0; t < TT; ++t) s1b[((size_t)t*BB + b)*NN + n] = m[t];
}

// conv2: 64->128 from bitmask spikes; LIF over t; pack 128-bit spikes
__global__ __launch_bounds__(256) void k_tnet2(const u64* __restrict__ s1b, const float* __restrict__ w,
        const float* __restrict__ bi, u64* __restrict__ s2b) {
    __shared__ float ws[128*64];
    int tid = threadIdx.x;
    for (int l = tid; l < 128*64; l += 256) ws[l] = w[l];
    __syncthreads();
    int i = blockIdx.x*256 + tid;
    int b = i >> 11, n = i & 2047;
    u64 m[TT];
    #pragma unroll
    for (int t = 0; t < TT; ++t) m[t] = s1b[((size_t)t*BB+b)*NN+n];
    u64 o[TT][2] = {{0,0},{0,0},{0,0},{0,0}};
    for (int e = 0; e < 128; ++e) {
        float z[TT] = {0.f,0.f,0.f,0.f};
        #pragma unroll 8
        for (int d = 0; d < 64; ++d) {
            float wv = ws[e*64+d];
            #pragma unroll
            for (int t = 0; t < TT; ++t) z[t] += ((m[t]>>d)&1ull) ? wv : 0.f;
        }
        float v = 0.f, bb = bi[e];
        #pragma unroll
        for (int t = 0; t < TT; ++t) {
            float s = lif_step(v, z[t] + bb);
            if (s != 0.f) o[t][e>>6] |= (1ull << (e&63));
        }
    }
    #pragma unroll
    for (int t = 0; t < TT; ++t) {
        s2b[(((size_t)t*BB+b)*NN+n)*2+0] = o[t][0];
        s2b[(((size_t)t*BB+b)*NN+n)*2+1] = o[t][1];
    }
}

// conv3: 128->1024, LIF, max over n (OR of spikes) -> mx[t][b][1024]
__global__ __launch_bounds__(256) void k_tnet3(const u64* __restrict__ s2b, const float* __restrict__ w3,
        const float* __restrict__ b3, u32* __restrict__ mx) {
    __shared__ float As[64][33];
    __shared__ float Bs[TT][32][68];
    __shared__ u32 mxs[TT][64];
    int nt = blockIdx.x, ft = blockIdx.y, b = blockIdx.z;
    int n0 = nt*64, f0 = ft*64;
    int tid = threadIdx.x;
    int fi = tid >> 4, nj = tid & 15;
    for (int l = tid; l < TT*64; l += 256) mxs[l>>6][l&63] = 0u;
    float acc[4][4][TT];
    #pragma unroll
    for (int a=0;a<4;++a)
        #pragma unroll
        for (int c=0;c<4;++c)
            #pragma unroll
            for (int t=0;t<TT;++t) acc[a][c][t]=0.f;
    for (int ec = 0; ec < 128; ec += 32) {
        for (int l = tid; l < 64*32; l += 256) { int f = l>>5, e = l&31; As[f][e] = w3[(size_t)(f0+f)*128 + ec + e]; }
        for (int l = tid; l < TT*32*64; l += 256) {
            int t = l >> 11, r = l & 2047, e = r >> 6, n = r & 63;
            int ee = ec + e;
            u64 wb = s2b[(((size_t)t*BB+b)*NN + n0+n)*2 + (ee>>6)];
            Bs[t][e][n] = (float)((wb >> (ee & 63)) & 1ull);
        }
        __syncthreads();
        #pragma unroll 2
        for (int e = 0; e < 32; ++e) {
            float a0 = As[fi*4+0][e], a1 = As[fi*4+1][e], a2 = As[fi*4+2][e], a3 = As[fi*4+3][e];
            #pragma unroll
            for (int t = 0; t < TT; ++t) {
                float4 bq = *((const float4*)&Bs[t][e][nj*4]);
                acc[0][0][t] += a0*bq.x; acc[0][1][t] += a0*bq.y; acc[0][2][t] += a0*bq.z; acc[0][3][t] += a0*bq.w;
                acc[1][0][t] += a1*bq.x; acc[1][1][t] += a1*bq.y; acc[1][2][t] += a1*bq.z; acc[1][3][t] += a1*bq.w;
                acc[2][0][t] += a2*bq.x; acc[2][1][t] += a2*bq.y; acc[2][2][t] += a2*bq.z; acc[2][3][t] += a2*bq.w;
                acc[3][0][t] += a3*bq.x; acc[3][1][t] += a3*bq.y; acc[3][2][t] += a3*bq.z; acc[3][3][t] += a3*bq.w;
            }
        }
        __syncthreads();
    }
    #pragma unroll
    for (int ff=0; ff<4; ++ff) {
        float bb = b3[f0 + fi*4 + ff];
        u32 any[TT] = {0,0,0,0};
        #pragma unroll
        for (int nn=0; nn<4; ++nn) {
            float v = 0.f;
            #pragma unroll
            for (int t=0;t<TT;++t) {
                float s = lif_step(v, acc[ff][nn][t] + bb);
                if (s != 0.f) any[t] = 1u;
            }
        }
        #pragma unroll
        for (int t=0;t<TT;++t) if (any[t]) atomicOr(&mxs[t][fi*4+ff], 1u);
    }
    __syncthreads();
    for (int l=tid; l<TT*64; l+=256) if (mxs[l>>6][l&63]) atomicOr(&mx[((size_t)(l>>6)*BB+b)*1024 + f0 + (l&63)], 1u);
}

// FC head: 1024->512->256->9, LIF on first two, mean over t, +I -> trans[b][9]
__global__ __launch_bounds__(512) void k_fc(const u32* __restrict__ mx, const float* __restrict__ fw1, const float* __restrict__ fb1,
        const float* __restrict__ fw2, const float* __restrict__ fb2, const float* __restrict__ fw3, const float* __restrict__ fb3,
        float* __restrict__ trans) {
    __shared__ float h0[TT][1024];
    __shared__ float h1[TT][512];
    __shared__ float h2[TT][256];
    __shared__ float h3s[TT][9];
    int b = blockIdx.x, tid = threadIdx.x;
    for (int l = tid; l < TT*1024; l += 512) h0[l>>10][l&1023] = (float)mx[((size_t)(l>>10)*BB + b)*1024 + (l&1023)];
    __syncthreads();
    {
        float z[TT] = {0.f,0.f,0.f,0.f};
        #pragma unroll 4
        for (int f = 0; f < 1024; ++f) {
            float wv = fw1[(size_t)tid*1024 + f];
            #pragma unroll
            for (int t = 0; t < TT; ++t) z[t] += wv * h0[t][f];
        }
        float v = 0.f;
        #pragma unroll
        for (int t = 0; t < TT; ++t) h1[t][tid] = lif_step(v, z[t] + fb1[tid]);
    }
    __syncthreads();
    if (tid < 256) {
        float z[TT] = {0.f,0.f,0.f,0.f};
        #pragma unroll 4
        for (int f = 0; f < 512; ++f) {
            float wv = fw2[(size_t)tid*512 + f];
            #pragma unroll
            for (int t = 0; t < TT; ++t) z[t] += wv * h1[t][f];
        }
        float v = 0.f;
        #pragma unroll
        for (int t = 0; t < TT; ++t) h2[t][tid] = lif_step(v, z[t] + fb2[tid]);
    }
    __syncthreads();
    if (tid < TT*9) {
        int t = tid/9, oo = tid%9;
        float z = 0.f;
        for (int f = 0; f < 256; ++f) z += fw3[oo*256+f]*h2[t][f];
        h3s[t][oo] = z + fb3[oo];
    }
    __syncthreads();
    if (tid < 9) {
        float m = ((h3s[0][tid]+h3s[1][tid]) + (h3s[2][tid]+h3s[3][tid])) * 0.25f;
        int c = tid/3, dd = tid%3;
        trans[b*9+tid] = m + ((c==dd)?1.0f:0.0f);
    }
}

// apply transform: xa[:, :3] = pos @ trans, xa[:, 3:] = x[:, 3:], and sq of pos_a
__global__ __launch_bounds__(256) void k_trans(const float* __restrict__ x, const float* __restrict__ tr,
        float* __restrict__ xa, float* __restrict__ sqb) {
    int i = blockIdx.x*256 + threadIdx.x;
    int b = i >> 11, n = i & 2047;
    float p0 = x[((size_t)b*14+0)*NN+n];
    float p1 = x[((size_t)b*14+1)*NN+n];
    float p2 = x[((size_t)b*14+2)*NN+n];
    const float* tb = tr + b*9;
    float a0 = (p0*tb[0] + p1*tb[3]) + p2*tb[6];
    float a1 = (p0*tb[1] + p1*tb[4]) + p2*tb[7];
    float a2 = (p0*tb[2] + p1*tb[5]) + p2*tb[8];
    xa[((size_t)b*14+0)*NN+n] = a0;
    xa[((size_t)b*14+1)*NN+n] = a1;
    xa[((size_t)b*14+2)*NN+n] = a2;
    for (int c = 3; c < 14; ++c) xa[((size_t)b*14+c)*NN+n] = x[((size_t)b*14+c)*NN+n];
    sqb[(size_t)b*NN+n] = (a0*a0 + a1*a1) + a2*a2;
}

// KNN: block per (b, n) row; top-16 by repeated argmax with (value desc, index asc) order
__global__ __launch_bounds__(256) void k_knn(const float* __restrict__ xa, const float* __restrict__ sqb, int* __restrict__ idx) {
    __shared__ float pm0[NN], pm1[NN], pm2[NN], sm[NN];
    __shared__ u64 red[4];
    __shared__ u64 winner;
    int n = blockIdx.x, b = blockIdx.y;
    int tid = threadIdx.x;
    for (int l = tid; l < NN; l += 256) {
        pm0[l] = xa[((size_t)b*14+0)*NN+l];
        pm1[l] = xa[((size_t)b*14+1)*NN+l];
        pm2[l] = xa[((size_t)b*14+2)*NN+l];
        sm[l]  = sqb[(size_t)b*NN+l];
    }
    __syncthreads();
    float q0 = pm0[n], q1 = pm1[n], q2 = pm2[n], sn = sm[n];
    float vals[8];
    #pragma unroll
    for (int j = 0; j < 8; ++j) {
        int mm = j*256 + tid;
        float inner = (q0*pm0[mm] + q1*pm1[mm]) + q2*pm2[mm];
        vals[j] = (2.0f*inner - sn) - sm[mm];
    }
    for (int k = 0; k < KNB; ++k) {
        float bv = -3.4e38f; int bj = -1;
        #pragma unroll
        for (int j = 0; j < 8; ++j) if (vals[j] > bv) { bv = vals[j]; bj = j; }
        int bm = (bj < 0) ? -1 : (bj*256 + tid);
        u32 fb = __float_as_uint(bv);
        fb = (fb & 0x80000000u) ? ~fb : (fb | 0x80000000u);
        u64 key = ((u64)fb << 32) | (u32)(~bm);
        #pragma unroll
        for (int o2 = 1; o2 < 64; o2 <<= 1) {
            u64 other = __shfl_xor(key, o2, 64);
            key = (other > key) ? other : key;
        }
        if ((tid & 63) == 0) red[tid >> 6] = key;
        __syncthreads();
        if (tid == 0) {
            u64 k0 = (red[0] > red[1]) ? red[0] : red[1];
            u64 k1 = (red[2] > red[3]) ? red[2] : red[3];
            u64 km = (k0 > k1) ? k0 : k1;
            winner = km;
            idx[((size_t)b*NN + n)*KNB + k] = (int)(~(u32)km);
        }
        __syncthreads();
        int wm = (int)(~(u32)winner);
        if ((wm & 255) == tid) vals[wm >> 8] = -3.4e38f;
        __syncthreads();
    }
}

// graph feature: gf[b][c][p] with p = n*16+k; c<14: center, c>=14: nbr - center
__global__ __launch_bounds__(256) void k_gfeat(const float* __restrict__ xa, const int* __restrict__ idx, float* __restrict__ gf) {
    int i = blockIdx.x*256 + threadIdx.x;
    int b = i >> 15;
    int r = i & 32767;
    int n = r >> 4, kk = r & 15;
    int mm = idx[((size_t)b*NN+n)*KNB + kk];
    size_t pbase = (size_t)b*28*PP + r;
    #pragma unroll
    for (int c = 0; c < 14; ++c) {
        float ctr = xa[((size_t)b*14+c)*NN + n];
        float nb  = xa[((size_t)b*14+c)*NN + mm];
        gf[pbase + (size_t)c*PP] = ctr;
        gf[pbase + (size_t)(14+c)*PP] = nb - ctr;
    }
}

// edge conv1 stats: z1 = w1 * gf (same for all t); block partial sum/sumsq per d
__global__ __launch_bounds__(256) void k_estats1(const float* __restrict__ gf, const float* __restrict__ w1, float* __restrict__ part1) {
    __shared__ float gfs[28][256];
    __shared__ float w1s[64*28];
    __shared__ float wsum[4][64], wsq[4][64];
    int pt = blockIdx.x, b = blockIdx.y;
    int p0 = pt*256, tid = threadIdx.x;
    for (int l = tid; l < 28*256; l += 256) gfs[l>>8][l&255] = gf[((size_t)b*28 + (l>>8))*PP + p0 + (l&255)];
    for (int l = tid; l < 64*28; l += 256) w1s[l] = w1[l];
    __syncthreads();
    int wv = tid>>6, lane = tid&63;
    for (int d = 0; d < 64; ++d) {
        float z = 0.f;
        #pragma unroll
        for (int c = 0; c < 28; ++c) z += w1s[d*28+c]*gfs[c][tid];
        float s = z, q = z*z;
        #pragma unroll
        for (int o = 1; o < 64; o <<= 1) { s += __shfl_xor(s, o, 64); q += __shfl_xor(q, o, 64); }
        if (lane == 0) { wsum[wv][d] = s; wsq[wv][d] = q; }
    }
    __syncthreads();
    if (tid < 64) {
        float s = (wsum[0][tid]+wsum[1][tid])+(wsum[2][tid]+wsum[3][tid]);
        float q = (wsq[0][tid]+wsq[1][tid])+(wsq[2][tid]+wsq[3][tid]);
        size_t blk = (size_t)b*128 + pt;
        part1[(blk*64 + tid)*2+0] = s;
        part1[(blk*64 + tid)*2+1] = q;
    }
}

// deterministic reduce of block partials -> (mean, inv_std)
__global__ void k_reduce(const float* __restrict__ part, float* __restrict__ stats, int nch, int nblk, double M) {
    int ch = blockIdx.x*64 + threadIdx.x;
    if (ch >= nch) return;
    double s = 0.0, q = 0.0;
    for (int i = 0; i < nblk; ++i) {
        s += (double)part[((size_t)i*nch + ch)*2 + 0];
        q += (double)part[((size_t)i*nch + ch)*2 + 1];
    }
    double mu = s / M;
    double var = q / M - mu*mu;
    stats[ch*2+0] = (float)mu;
    stats[ch*2+1] = 1.0f / sqrtf((float)var + EPSB);
}

// edge conv1(norm+LIF) + conv2; APPLY=false: accumulate conv2 stats; APPLY=true: norm+LIF+max over k -> m2
template<bool APPLY>
__global__ __launch_bounds__(256) void k_edge12(
        const float* __restrict__ gf, const float* __restrict__ w1, const float* __restrict__ w2,
        const float* __restrict__ st1, const float* __restrict__ g1, const float* __restrict__ be1,
        const float* __restrict__ st2, const float* __restrict__ g2, const float* __restrict__ be2,
        float* __restrict__ part2, u8* __restrict__ m2) {
    __shared__ float gfs[28][68];
    __shared__ float h1f[64][68];
    __shared__ float w2t[64][132];
    __shared__ float red[128][4][2];
    int pt = blockIdx.x, b = blockIdx.y;
    int p0 = pt*64, tid = threadIdx.x;
    for (int l = tid; l < 28*64; l += 256) gfs[l>>6][l&63] = gf[((size_t)b*28 + (l>>6))*PP + p0 + (l&63)];
    for (int l = tid; l < 128*64; l += 256) { int e = l>>6, d = l&63; w2t[d][e] = w2[l]; }
    __syncthreads();
    int d0 = tid >> 2, q = tid & 3;
    float z1r[16], v1r[16];
    #pragma unroll
    for (int j = 0; j < 16; ++j) {
        float z = 0.f;
        #pragma unroll
        for (int c = 0; c < 28; ++c) z += w1[d0*28+c] * gfs[c][q*16+j];
        z1r[j] = z; v1r[j] = 0.f;
    }
    float mu1 = st1[d0*2+0], iv1 = st1[d0*2+1];
    int e0 = d0*2;
    float v2a[16], v2b[16];
    #pragma unroll
    for (int i=0;i<16;++i){ v2a[i]=0.f; v2b[i]=0.f; }
    for (int t = 0; t < TT; ++t) {
        float ga = g1[t*64+d0], bb = be1[t*64+d0];
        #pragma unroll
        for (int j = 0; j < 16; ++j) {
            float y = (z1r[j] - mu1) * iv1 * ga + bb;
            float s = lif_step(v1r[j], y);
            h1f[d0][q*16+j] = s;
        }
        __syncthreads();
        float acc0[16], acc1[16];
        #pragma unroll
        for (int i=0;i<16;++i){acc0[i]=0.f;acc1[i]=0.f;}
        #pragma unroll 4
        for (int d = 0; d < 64; ++d) {
            float wa = w2t[d][e0], wb = w2t[d][e0+1];
            const float4* h4 = (const float4*)&h1f[d][q*16];
            #pragma unroll
            for (int i4 = 0; i4 < 4; ++i4) {
                float4 hv = h4[i4];
                acc0[i4*4+0] += wa*hv.x; acc0[i4*4+1] += wa*hv.y; acc0[i4*4+2] += wa*hv.z; acc0[i4*4+3] += wa*hv.w;
                acc1[i4*4+0] += wb*hv.x; acc1[i4*4+1] += wb*hv.y; acc1[i4*4+2] += wb*hv.z; acc1[i4*4+3] += wb*hv.w;
            }
        }
        if (!APPLY) {
            float s0=0.f,s1=0.f,q0s=0.f,q1s=0.f;
            #pragma unroll
            for (int i=0;i<16;++i){ s0+=acc0[i]; q0s+=acc0[i]*acc0[i]; s1+=acc1[i]; q1s+=acc1[i]*acc1[i]; }
            red[e0+0][q][0]=s0; red[e0+0][q][1]=q0s;
            red[e0+1][q][0]=s1; red[e0+1][q][1]=q1s;
            __syncthreads();
            if (tid < 128) {
                float s = (red[tid][0][0]+red[tid][1][0])+(red[tid][2][0]+red[tid][3][0]);
                float qq = (red[tid][0][1]+red[tid][1][1])+(red[tid][2][1]+red[tid][3][1]);
                size_t blk = (size_t)b*512 + pt;
                part2[(blk*512 + (size_t)t*128 + tid)*2+0] = s;
                part2[(blk*512 + (size_t)t*128 + tid)*2+1] = qq;
            }
            __syncthreads();
        } else {
            {
                int e = e0;
                float mu2 = st2[((size_t)t*128+e)*2+0], iv2 = st2[((size_t)t*128+e)*2+1];
                float ga2 = g2[t*128+e], bb2 = be2[t*128+e];
                u32 any = 0u;
                #pragma unroll
                for (int i=0;i<16;++i) {
                    float y = (acc0[i]-mu2)*iv2*ga2 + bb2;
                    float s = lif_step(v2a[i], y);
                    if (s != 0.f) any = 1u;
                }
                m2[(((size_t)t*BB+b)*128 + e)*NN + pt*4 + q] = (u8)any;
            }
            {
                int e = e0+1;
                float mu2 = st2[((size_t)t*128+e)*2+0], iv2 = st2[((size_t)t*128+e)*2+1];
                float ga2 = g2[t*128+e], bb2 = be2[t*128+e];
                u32 any = 0u;
                #pragma unroll
                for (int i=0;i<16;++i) {
                    float y = (acc1[i]-mu2)*iv2*ga2 + bb2;
                    float s = lif_step(v2b[i], y);
                    if (s != 0.f) any = 1u;
                }
                m2[(((size_t)t*BB+b)*128 + e)*NN + pt*4 + q] = (u8)any;
            }
            __syncthreads();
        }
    }
}

// generic tiled GEMM over u8 spike input; MODE 0: stats partials, 1: norm+LIF -> u8 spikes, 2: norm+LIF+OR over n -> mx4
template<int MODE, int CI>
__global__ __launch_bounds__(256) void k_gconv(const u8* __restrict__ in, const float* __restrict__ w,
        const float* __restrict__ st, const float* __restrict__ ga, const float* __restrict__ be,
        float* __restrict__ part, u8* __restrict__ outs, u32* __restrict__ outm, int COUT) {
    __shared__ float As[64][33];
    __shared__ float Bs[TT][32][68];
    __shared__ float red[64][16][2];
    __shared__ u32 morr[TT][64];
    int nt = blockIdx.x, ft = blockIdx.y, b = blockIdx.z;
    int n0 = nt*64, f0 = ft*64;
    int tid = threadIdx.x;
    int fi = tid >> 4, nj = tid & 15;
    if (MODE == 2) for (int l = tid; l < TT*64; l += 256) morr[l>>6][l&63] = 0u;
    float acc[4][4][TT];
    #pragma unroll
    for (int a=0;a<4;++a)
        #pragma unroll
        for (int c=0;c<4;++c)
            #pragma unroll
            for (int t=0;t<TT;++t) acc[a][c][t]=0.f;
    for (int kc = 0; kc < CI; kc += 32) {
        for (int l = tid; l < 64*32; l += 256) { int f = l>>5, e = l&31; As[f][e] = w[(size_t)(f0+f)*CI + kc + e]; }
        for (int l = tid; l < TT*32*64; l += 256) {
            int t = l >> 11, r = l & 2047, e = r >> 6, n = r & 63;
            Bs[t][e][n] = (float)in[(((size_t)t*BB+b)*CI + kc + e)*NN + n0 + n];
        }
        __syncthreads();
        #pragma unroll 2
        for (int e = 0; e < 32; ++e) {
            float a0 = As[fi*4+0][e], a1 = As[fi*4+1][e], a2 = As[fi*4+2][e], a3 = As[fi*4+3][e];
            #pragma unroll
            for (int t = 0; t < TT; ++t) {
                float4 bq = *((const float4*)&Bs[t][e][nj*4]);
                acc[0][0][t] += a0*bq.x; acc[0][1][t] += a0*bq.y; acc[0][2][t] += a0*bq.z; acc[0][3][t] += a0*bq.w;
                acc[1][0][t] += a1*bq.x; acc[1][1][t] += a1*bq.y; acc[1][2][t] += a1*bq.z; acc[1][3][t] += a1*bq.w;
                acc[2][0][t] += a2*bq.x; acc[2][1][t] += a2*bq.y; acc[2][2][t] += a2*bq.z; acc[2][3][t] += a2*bq.w;
                acc[3][0][t] += a3*bq.x; acc[3][1][t] += a3*bq.y; acc[3][2][t] += a3*bq.z; acc[3][3][t] += a3*bq.w;
            }
        }
        __syncthreads();
    }
    if (MODE == 0) {
        for (int t = 0; t < TT; ++t) {
            #pragma unroll
            for (int ff = 0; ff < 4; ++ff) {
                float s = (acc[ff][0][t]+acc[ff][1][t])+(acc[ff][2][t]+acc[ff][3][t]);
                float qq = (acc[ff][0][t]*acc[ff][0][t]+acc[ff][1][t]*acc[ff][1][t])+(acc[ff][2][t]*acc[ff][2][t]+acc[ff][3][t]*acc[ff][3][t]);
                red[fi*4+ff][nj][0] = s;
                red[fi*4+ff][nj][1] = qq;
            }
            __syncthreads();
            if (tid < 64) {
                float s = 0.f, qq = 0.f;
                #pragma unroll
                for (int j = 0; j < 16; ++j) { s += red[tid][j][0]; qq += red[tid][j][1]; }
                size_t blk = (size_t)b*32 + nt;
                size_t ch = (size_t)t*COUT + f0 + tid;
                part[(blk*((size_t)TT*COUT) + ch)*2 + 0] = s;
                part[(blk*((size_t)TT*COUT) + ch)*2 + 1] = qq;
            }
            __syncthreads();
        }
    } else if (MODE == 1) {
        #pragma unroll
        for (int ff=0; ff<4; ++ff) {
            int f = f0 + fi*4 + ff;
            #pragma unroll
            for (int nn=0; nn<4; ++nn) {
                int n = n0 + nj*4 + nn;
                float v = 0.f;
                #pragma unroll
                for (int t=0;t<TT;++t) {
                    int ch = t*COUT + f;
                    float y = (acc[ff][nn][t] - st[(size_t)ch*2+0])*st[(size_t)ch*2+1]*ga[ch] + be[ch];
                    float s = lif_step(v, y);
                    outs[(((size_t)t*BB+b)*COUT + f)*NN + n] = (u8)(s != 0.f);
                }
            }
        }
    } else {
        #pragma unroll
        for (int ff=0; ff<4; ++ff) {
            int f = f0 + fi*4 + ff;
            u32 any[TT] = {0,0,0,0};
            #pragma unroll
            for (int nn=0; nn<4; ++nn) {
                float v = 0.f;
                #pragma unroll
                for (int t=0;t<TT;++t) {
                    int ch = t*COUT + f;
                    float y = (acc[ff][nn][t] - st[(size_t)ch*2+0])*st[(size_t)ch*2+1]*ga[ch] + be[ch];
                    float s = lif_step(v, y);
                    if (s != 0.f) any[t] = 1u;
                }
            }
            #pragma unroll
            for (int t=0;t<TT;++t) if (any[t]) atomicOr(&morr[t][fi*4+ff], 1u);
        }
        __syncthreads();
        for (int l=tid; l<TT*64; l+=256) if (morr[l>>6][l&63]) atomicOr(&outm[((size_t)(l>>6)*BB+b)*COUT + f0 + (l&63)], 1u);
    }
}

__global__ __launch_bounds__(256) void k_out(const u32* __restrict__ mx4, float* __restrict__ out) {
    int i = blockIdx.x*256 + threadIdx.x;
    int b = i >> 10, g = i & 1023;
    float s = (float)(mx4[((size_t)0*BB+b)*1024+g] + mx4[((size_t)1*BB+b)*1024+g]
                    + mx4[((size_t)2*BB+b)*1024+g] + mx4[((size_t)3*BB+b)*1024+g]);
    out[i] = s * 0.25f;
}

extern "C" void kernel_launch(void* const* d_in, const int* in_sizes, int n_in,
                              void* d_out, int out_size, void* d_ws, size_t ws_size,
                              hipStream_t stream) {
    (void)in_sizes; (void)n_in; (void)out_size;
    const float* x    = (const float*)d_in[0];
    const float* tw1  = (const float*)d_in[1];
    const float* tb1  = (const float*)d_in[2];
    const float* tw2  = (const float*)d_in[3];
    const float* tb2  = (const float*)d_in[4];
    const float* tw3  = (const float*)d_in[5];
    const float* tb3  = (const float*)d_in[6];
    const float* tfw1 = (const float*)d_in[7];
    const float* tfb1 = (const float*)d_in[8];
    const float* tfw2 = (const float*)d_in[9];
    const float* tfb2 = (const float*)d_in[10];
    const float* tfw3 = (const float*)d_in[11];
    const float* tfb3 = (const float*)d_in[12];
    const float* w1   = (const float*)d_in[13];
    const float* w2   = (const float*)d_in[14];
    const float* w3   = (const float*)d_in[15];
    const float* w4   = (const float*)d_in[16];
    const float* g1   = (const float*)d_in[17];
    const float* be1  = (const float*)d_in[18];
    const float* g2   = (const float*)d_in[19];
    const float* be2  = (const float*)d_in[20];
    const float* g3   = (const float*)d_in[21];
    const float* be3  = (const float*)d_in[22];
    const float* g4   = (const float*)d_in[23];
    const float* be4  = (const float*)d_in[24];

    char* wsb = (char*)d_ws;
    size_t off = 0;
    auto alloc = [&](size_t bytes) -> void* {
        void* p = wsb + off;
        off = (off + bytes + 255) & ~(size_t)255;
        return p;
    };
    u64* s1b   = (u64*)alloc(sizeof(u64)*(size_t)TT*BB*NN);
    u64* s2b   = (u64*)alloc(sizeof(u64)*(size_t)TT*BB*NN*2);
    u32* mx    = (u32*)alloc(sizeof(u32)*(size_t)TT*BB*1024);
    u32* mx4   = (u32*)alloc(sizeof(u32)*(size_t)TT*BB*1024);
    float* trs = (float*)alloc(sizeof(float)*BB*9);
    float* xa  = (float*)alloc(sizeof(float)*(size_t)BB*14*NN);
    float* sqb = (float*)alloc(sizeof(float)*(size_t)BB*NN);
    int* idx   = (int*)alloc(sizeof(int)*(size_t)BB*NN*KNB);
    float* gf  = (float*)alloc(sizeof(float)*(size_t)BB*28*PP);
    float* part1 = (float*)alloc(sizeof(float)*(size_t)1024*64*2);
    float* part2 = (float*)alloc(sizeof(float)*(size_t)4096*512*2);
    float* part3 = (float*)alloc(sizeof(float)*(size_t)256*1024*2);
    float* part4 = (float*)alloc(sizeof(float)*(size_t)256*4096*2);
    float* st1 = (float*)alloc(sizeof(float)*64*2);
    float* st2 = (float*)alloc(sizeof(float)*512*2);
    float* st3 = (float*)alloc(sizeof(float)*1024*2);
    float* st4 = (float*)alloc(sizeof(float)*4096*2);
    u8* m2 = (u8*)alloc((size_t)TT*BB*128*NN);
    u8* h3 = (u8*)alloc((size_t)TT*BB*256*NN);
    if (off > ws_size) return;  // insufficient workspace: bail (bench will flag)

    hipMemsetAsync(mx, 0, sizeof(u32)*(size_t)TT*BB*1024, stream);
    hipMemsetAsync(mx4, 0, sizeof(u32)*(size_t)TT*BB*1024, stream);

    // T-Net
    k_tnet1<<<dim3(64), dim3(256), 0, stream>>>(x, tw1, tb1, s1b);
    k_tnet2<<<dim3(64), dim3(256), 0, stream>>>(s1b, tw2, tb2, s2b);
    k_tnet3<<<dim3(32,16,8), dim3(256), 0, stream>>>(s2b, tw3, tb3, mx);
    k_fc<<<dim3(8), dim3(512), 0, stream>>>(mx, tfw1, tfb1, tfw2, tfb2, tfw3, tfb3, trs);
    k_trans<<<dim3(64), dim3(256), 0, stream>>>(x, trs, xa, sqb);
    // KNN + graph feature
    k_knn<<<dim3(NN, BB), dim3(256), 0, stream>>>(xa, sqb, idx);
    k_gfeat<<<dim3((BB*NN*KNB)/256), dim3(256), 0, stream>>>(xa, idx, gf);
    // edge conv1 stats
    k_estats1<<<dim3(128, 8), dim3(256), 0, stream>>>(gf, w1, part1);
    k_reduce<<<dim3(1), dim3(64), 0, stream>>>(part1, st1, 64, 1024, 262144.0);
    // edge conv2 stats (recompute conv1 inside)
    k_edge12<false><<<dim3(512, 8), dim3(256), 0, stream>>>(gf, w1, w2, st1, g1, be1, nullptr, nullptr, nullptr, part2, nullptr);
    k_reduce<<<dim3(8), dim3(64), 0, stream>>>(part2, st2, 512, 4096, 262144.0);
    // edge conv2 apply + max over k
    k_edge12<true><<<dim3(512, 8), dim3(256), 0, stream>>>(gf, w1, w2, st1, g1, be1, st2, g2, be2, nullptr, m2);
    // conv3 (128->256)
    k_gconv<0,128><<<dim3(32,4,8), dim3(256), 0, stream>>>(m2, w3, nullptr, nullptr, nullptr, part3, nullptr, nullptr, 256);
    k_reduce<<<dim3(16), dim3(64), 0, stream>>>(part3, st3, 1024, 256, 16384.0);
    k_gconv<1,128><<<dim3(32,4,8), dim3(256), 0, stream>>>(m2, w3, st3, g3, be3, nullptr, h3, nullptr, 256);
    // conv4 (256->1024)
    k_gconv<0,256><<<dim3(32,16,8), dim3(256), 0, stream>>>(h3, w4, nullptr, nullptr, nullptr, part4, nullptr, nullptr, 1024);
    k_reduce<<<dim3(64), dim3(64), 0, stream>>>(part4, st4, 4096, 256, 16384.0);
    k_gconv<2,256><<<dim3(32,16,8), dim3(256), 0, stream>>>(h3, w4, st4, g4, be4, nullptr, nullptr, mx4, 1024);
    // output: mean over t of (max over n)
    k_out<<<dim3(32), dim3(256), 0, stream>>>(mx4, (float*)d_out);
}

// Round 2
// 2224.269 us; speedup vs baseline: 1.9681x; 1.9681x over previous
//
#include <hip/hip_runtime.h>
#include <stdint.h>

#define TT 4
#define BB 8
#define NN 2048
#define KNB 16
#define PP (NN*KNB)
#define VTH 1.0f
#define EPSB 1e-5f

typedef unsigned long long u64;
typedef unsigned int u32;
typedef unsigned char u8;

__device__ __forceinline__ float lif_step(float& v, float x) {
    v = v + (x - v) / 2.0f;
    float s = (v - VTH >= 0.0f) ? 1.0f : 0.0f;
    v = v * (1.0f - s);
    return s;
}

// ---------------- T-Net ----------------
__global__ __launch_bounds__(256) void k_tnet1(const float* __restrict__ x, const float* __restrict__ w,
        const float* __restrict__ bi, u64* __restrict__ s1b) {
    int i = blockIdx.x*256 + threadIdx.x;
    int b = i >> 11, n = i & 2047;
    float p0 = x[((size_t)b*14+0)*NN+n];
    float p1 = x[((size_t)b*14+1)*NN+n];
    float p2 = x[((size_t)b*14+2)*NN+n];
    u64 m[TT] = {0,0,0,0};
    for (int d = 0; d < 64; ++d) {
        float z = ((w[d*3+0]*p0 + w[d*3+1]*p1) + w[d*3+2]*p2) + bi[d];
        float v = 0.f;
        #pragma unroll
        for (int t = 0; t < TT; ++t) {
            float s = lif_step(v, z);
            if (s != 0.f) m[t] |= (1ull << d);
        }
    }
    #pragma unroll
    for (int t = 0; t < TT; ++t) s1b[((size_t)t*BB + b)*NN + n] = m[t];
}

__global__ __launch_bounds__(256) void k_tnet2(const u64* __restrict__ s1b, const float* __restrict__ w,
        const float* __restrict__ bi, u64* __restrict__ s2b) {
    __shared__ float ws[128*64];
    int tid = threadIdx.x;
    for (int l = tid; l < 128*64; l += 256) ws[l] = w[l];
    __syncthreads();
    int i = blockIdx.x*256 + tid;
    int b = i >> 11, n = i & 2047;
    u64 m[TT];
    #pragma unroll
    for (int t = 0; t < TT; ++t) m[t] = s1b[((size_t)t*BB+b)*NN+n];
    u64 o[TT][2] = {{0,0},{0,0},{0,0},{0,0}};
    for (int e = 0; e < 128; ++e) {
        float z[TT] = {0.f,0.f,0.f,0.f};
        #pragma unroll 8
        for (int d = 0; d < 64; ++d) {
            float wv = ws[e*64+d];
            #pragma unroll
            for (int t = 0; t < TT; ++t) z[t] += ((m[t]>>d)&1ull) ? wv : 0.f;
        }
        float v = 0.f, bb = bi[e];
        #pragma unroll
        for (int t = 0; t < TT; ++t) {
            float s = lif_step(v, z[t] + bb);
            if (s != 0.f) o[t][e>>6] |= (1ull << (e&63));
        }
    }
    #pragma unroll
    for (int t = 0; t < TT; ++t) {
        s2b[(((size_t)t*BB+b)*NN+n)*2+0] = o[t][0];
        s2b[(((size_t)t*BB+b)*NN+n)*2+1] = o[t][1];
    }
}

__global__ __launch_bounds__(256) void k_tnet3(const u64* __restrict__ s2b, const float* __restrict__ w3,
        const float* __restrict__ b3, u32* __restrict__ mx) {
    __shared__ float As[64][33];
    __shared__ float Bs[TT][32][68];
    __shared__ u32 mxs[TT][64];
    int nt = blockIdx.x, ft = blockIdx.y, b = blockIdx.z;
    int n0 = nt*64, f0 = ft*64;
    int tid = threadIdx.x;
    int fi = tid >> 4, nj = tid & 15;
    for (int l = tid; l < TT*64; l += 256) mxs[l>>6][l&63] = 0u;
    float acc[4][4][TT];
    #pragma unroll
    for (int a=0;a<4;++a)
        #pragma unroll
        for (int c=0;c<4;++c)
            #pragma unroll
            for (int t=0;t<TT;++t) acc[a][c][t]=0.f;
    for (int ec = 0; ec < 128; ec += 32) {
        for (int l = tid; l < 64*32; l += 256) { int f = l>>5, e = l&31; As[f][e] = w3[(size_t)(f0+f)*128 + ec + e]; }
        for (int l = tid; l < TT*32*64; l += 256) {
            int t = l >> 11, r = l & 2047, e = r >> 6, n = r & 63;
            int ee = ec + e;
            u64 wb = s2b[(((size_t)t*BB+b)*NN + n0+n)*2 + (ee>>6)];
            Bs[t][e][n] = (float)((wb >> (ee & 63)) & 1ull);
        }
        __syncthreads();
        #pragma unroll 2
        for (int e = 0; e < 32; ++e) {
            float a0 = As[fi*4+0][e], a1 = As[fi*4+1][e], a2 = As[fi*4+2][e], a3 = As[fi*4+3][e];
            #pragma unroll
            for (int t = 0; t < TT; ++t) {
                float4 bq = *((const float4*)&Bs[t][e][nj*4]);
                acc[0][0][t] += a0*bq.x; acc[0][1][t] += a0*bq.y; acc[0][2][t] += a0*bq.z; acc[0][3][t] += a0*bq.w;
                acc[1][0][t] += a1*bq.x; acc[1][1][t] += a1*bq.y; acc[1][2][t] += a1*bq.z; acc[1][3][t] += a1*bq.w;
                acc[2][0][t] += a2*bq.x; acc[2][1][t] += a2*bq.y; acc[2][2][t] += a2*bq.z; acc[2][3][t] += a2*bq.w;
                acc[3][0][t] += a3*bq.x; acc[3][1][t] += a3*bq.y; acc[3][2][t] += a3*bq.z; acc[3][3][t] += a3*bq.w;
            }
        }
        __syncthreads();
    }
    #pragma unroll
    for (int ff=0; ff<4; ++ff) {
        float bb = b3[f0 + fi*4 + ff];
        u32 any[TT] = {0,0,0,0};
        #pragma unroll
        for (int nn=0; nn<4; ++nn) {
            float v = 0.f;
            #pragma unroll
            for (int t=0;t<TT;++t) {
                float s = lif_step(v, acc[ff][nn][t] + bb);
                if (s != 0.f) any[t] = 1u;
            }
        }
        #pragma unroll
        for (int t=0;t<TT;++t) if (any[t]) atomicOr(&mxs[t][fi*4+ff], 1u);
    }
    __syncthreads();
    for (int l=tid; l<TT*64; l+=256) if (mxs[l>>6][l&63]) atomicOr(&mx[((size_t)(l>>6)*BB+b)*1024 + f0 + (l&63)], 1u);
}

__global__ __launch_bounds__(512) void k_fc(const u32* __restrict__ mx, const float* __restrict__ fw1, const float* __restrict__ fb1,
        const float* __restrict__ fw2, const float* __restrict__ fb2, const float* __restrict__ fw3, const float* __restrict__ fb3,
        float* __restrict__ trans) {
    __shared__ float h0[TT][1024];
    __shared__ float h1[TT][512];
    __shared__ float h2[TT][256];
    __shared__ float h3s[TT][9];
    int b = blockIdx.x, tid = threadIdx.x;
    for (int l = tid; l < TT*1024; l += 512) h0[l>>10][l&1023] = (float)mx[((size_t)(l>>10)*BB + b)*1024 + (l&1023)];
    __syncthreads();
    {
        float z[TT] = {0.f,0.f,0.f,0.f};
        #pragma unroll 4
        for (int f = 0; f < 1024; ++f) {
            float wv = fw1[(size_t)tid*1024 + f];
            #pragma unroll
            for (int t = 0; t < TT; ++t) z[t] += wv * h0[t][f];
        }
        float v = 0.f;
        #pragma unroll
        for (int t = 0; t < TT; ++t) h1[t][tid] = lif_step(v, z[t] + fb1[tid]);
    }
    __syncthreads();
    if (tid < 256) {
        float z[TT] = {0.f,0.f,0.f,0.f};
        #pragma unroll 4
        for (int f = 0; f < 512; ++f) {
            float wv = fw2[(size_t)tid*512 + f];
            #pragma unroll
            for (int t = 0; t < TT; ++t) z[t] += wv * h1[t][f];
        }
        float v = 0.f;
        #pragma unroll
        for (int t = 0; t < TT; ++t) h2[t][tid] = lif_step(v, z[t] + fb2[tid]);
    }
    __syncthreads();
    if (tid < TT*9) {
        int t = tid/9, oo = tid%9;
        float z = 0.f;
        for (int f = 0; f < 256; ++f) z += fw3[oo*256+f]*h2[t][f];
        h3s[t][oo] = z + fb3[oo];
    }
    __syncthreads();
    if (tid < 9) {
        float m = ((h3s[0][tid]+h3s[1][tid]) + (h3s[2][tid]+h3s[3][tid])) * 0.25f;
        int c = tid/3, dd = tid%3;
        trans[b*9+tid] = m + ((c==dd)?1.0f:0.0f);
    }
}

__global__ __launch_bounds__(256) void k_trans(const float* __restrict__ x, const float* __restrict__ tr,
        float* __restrict__ xa, float* __restrict__ sqb) {
    int i = blockIdx.x*256 + threadIdx.x;
    int b = i >> 11, n = i & 2047;
    float p0 = x[((size_t)b*14+0)*NN+n];
    float p1 = x[((size_t)b*14+1)*NN+n];
    float p2 = x[((size_t)b*14+2)*NN+n];
    const float* tb = tr + b*9;
    float a0 = (p0*tb[0] + p1*tb[3]) + p2*tb[6];
    float a1 = (p0*tb[1] + p1*tb[4]) + p2*tb[7];
    float a2 = (p0*tb[2] + p1*tb[5]) + p2*tb[8];
    xa[((size_t)b*14+0)*NN+n] = a0;
    xa[((size_t)b*14+1)*NN+n] = a1;
    xa[((size_t)b*14+2)*NN+n] = a2;
    for (int c = 3; c < 14; ++c) xa[((size_t)b*14+c)*NN+n] = x[((size_t)b*14+c)*NN+n];
    sqb[(size_t)b*NN+n] = (a0*a0 + a1*a1) + a2*a2;
}

__global__ __launch_bounds__(256) void k_knn(const float* __restrict__ xa, const float* __restrict__ sqb, int* __restrict__ idx) {
    __shared__ float pm0[NN], pm1[NN], pm2[NN], sm[NN];
    __shared__ u64 red[4];
    __shared__ u64 winner;
    int n = blockIdx.x, b = blockIdx.y;
    int tid = threadIdx.x;
    for (int l = tid; l < NN; l += 256) {
        pm0[l] = xa[((size_t)b*14+0)*NN+l];
        pm1[l] = xa[((size_t)b*14+1)*NN+l];
        pm2[l] = xa[((size_t)b*14+2)*NN+l];
        sm[l]  = sqb[(size_t)b*NN+l];
    }
    __syncthreads();
    float q0 = pm0[n], q1 = pm1[n], q2 = pm2[n], sn = sm[n];
    float vals[8];
    #pragma unroll
    for (int j = 0; j < 8; ++j) {
        int mm = j*256 + tid;
        float inner = (q0*pm0[mm] + q1*pm1[mm]) + q2*pm2[mm];
        vals[j] = (2.0f*inner - sn) - sm[mm];
    }
    for (int k = 0; k < KNB; ++k) {
        float bv = -3.4e38f; int bj = -1;
        #pragma unroll
        for (int j = 0; j < 8; ++j) if (vals[j] > bv) { bv = vals[j]; bj = j; }
        int bm = (bj < 0) ? -1 : (bj*256 + tid);
        u32 fb = __float_as_uint(bv);
        fb = (fb & 0x80000000u) ? ~fb : (fb | 0x80000000u);
        u64 key = ((u64)fb << 32) | (u32)(~bm);
        #pragma unroll
        for (int o2 = 1; o2 < 64; o2 <<= 1) {
            u64 other = __shfl_xor(key, o2, 64);
            key = (other > key) ? other : key;
        }
        if ((tid & 63) == 0) red[tid >> 6] = key;
        __syncthreads();
        if (tid == 0) {
            u64 k0 = (red[0] > red[1]) ? red[0] : red[1];
            u64 k1 = (red[2] > red[3]) ? red[2] : red[3];
            u64 km = (k0 > k1) ? k0 : k1;
            winner = km;
            idx[((size_t)b*NN + n)*KNB + k] = (int)(~(u32)km);
        }
        __syncthreads();
        int wm = (int)(~(u32)winner);
        if ((wm & 255) == tid) vals[wm >> 8] = -3.4e38f;
        __syncthreads();
    }
}

__global__ __launch_bounds__(256) void k_gfeat(const float* __restrict__ xa, const int* __restrict__ idx, float* __restrict__ gf) {
    int i = blockIdx.x*256 + threadIdx.x;
    int b = i >> 15;
    int r = i & 32767;
    int n = r >> 4;
    int mm = idx[((size_t)b*NN+n)*KNB + (r & 15)];
    size_t pbase = (size_t)b*28*PP + r;
    #pragma unroll
    for (int c = 0; c < 14; ++c) {
        float ctr = xa[((size_t)b*14+c)*NN + n];
        float nb  = xa[((size_t)b*14+c)*NN + mm];
        gf[pbase + (size_t)c*PP] = ctr;
        gf[pbase + (size_t)(14+c)*PP] = nb - ctr;
    }
}

// edge conv1 stats partials (z identical across t)
__global__ __launch_bounds__(256) void k_estats1(const float* __restrict__ gf, const float* __restrict__ w1, float* __restrict__ part1) {
    __shared__ float gfs[28][256];
    __shared__ float w1s[64*28];
    __shared__ float wsum[4][64], wsq[4][64];
    int pt = blockIdx.x, b = blockIdx.y;
    int p0 = pt*256, tid = threadIdx.x;
    for (int l = tid; l < 28*256; l += 256) gfs[l>>8][l&255] = gf[((size_t)b*28 + (l>>8))*PP + p0 + (l&255)];
    for (int l = tid; l < 64*28; l += 256) w1s[l] = w1[l];
    __syncthreads();
    int wv = tid>>6, lane = tid&63;
    for (int d = 0; d < 64; ++d) {
        float z = 0.f;
        #pragma unroll
        for (int c = 0; c < 28; ++c) z += w1s[d*28+c]*gfs[c][tid];
        float s = z, q = z*z;
        #pragma unroll
        for (int o = 1; o < 64; o <<= 1) { s += __shfl_xor(s, o, 64); q += __shfl_xor(q, o, 64); }
        if (lane == 0) { wsum[wv][d] = s; wsq[wv][d] = q; }
    }
    __syncthreads();
    if (tid < 64) {
        float s = (wsum[0][tid]+wsum[1][tid])+(wsum[2][tid]+wsum[3][tid]);
        float q = (wsq[0][tid]+wsq[1][tid])+(wsq[2][tid]+wsq[3][tid]);
        size_t blk = (size_t)b*128 + pt;
        part1[(blk*64 + tid)*2+0] = s;
        part1[(blk*64 + tid)*2+1] = q;
    }
}

// parallel deterministic reduce: one block per channel, 256-thread f64 tree
__global__ __launch_bounds__(256) void k_reduce(const float* __restrict__ part, float* __restrict__ stats, int nch, int nblk, double M) {
    __shared__ double sred[256], qred[256];
    int ch = blockIdx.x, tid = threadIdx.x;
    double s = 0.0, q = 0.0;
    for (int i = tid; i < nblk; i += 256) {
        s += (double)part[((size_t)i*nch + ch)*2 + 0];
        q += (double)part[((size_t)i*nch + ch)*2 + 1];
    }
    sred[tid] = s; qred[tid] = q;
    __syncthreads();
    for (int off = 128; off > 0; off >>= 1) {
        if (tid < off) { sred[tid] += sred[tid+off]; qred[tid] += qred[tid+off]; }
        __syncthreads();
    }
    if (tid == 0) {
        double mu = sred[0] / M;
        double var = qred[0] / M - mu*mu;
        if (var < 0.0) var = 0.0;
        stats[ch*2+0] = (float)mu;
        stats[ch*2+1] = 1.0f / sqrtf((float)var + EPSB);
    }
}

// edge conv1 apply: z1=w1*gf, norm+LIF, ballot-pack bits along p -> h1b[t][b][64][512]
__global__ __launch_bounds__(256) void k_h1(const float* __restrict__ gf, const float* __restrict__ w1,
        const float* __restrict__ st1, const float* __restrict__ g1, const float* __restrict__ be1,
        u64* __restrict__ h1b) {
    __shared__ float w1s[64*28];
    int tid = threadIdx.x;
    int b = blockIdx.y;
    int p0 = blockIdx.x*256;
    int p = p0 + tid;
    for (int l = tid; l < 64*28; l += 256) w1s[l] = w1[l];
    __syncthreads();
    float gr[28];
    #pragma unroll
    for (int c = 0; c < 28; ++c) gr[c] = gf[((size_t)b*28 + c)*PP + p];
    int wordbase = (p0>>6) + (tid>>6);
    for (int d = 0; d < 64; ++d) {
        float z = 0.f;
        #pragma unroll
        for (int c = 0; c < 28; ++c) z += w1s[d*28+c]*gr[c];
        float mu = st1[d*2+0], iv = st1[d*2+1];
        float v = 0.f;
        #pragma unroll
        for (int t = 0; t < TT; ++t) {
            float y = (z - mu) * iv * g1[t*64+d] + be1[t*64+d];
            float s = lif_step(v, y);
            u64 m = __ballot(s != 0.f);
            if ((tid & 63) == 0) h1b[((size_t)(t*BB+b)*64 + d)*512 + wordbase] = m;
        }
    }
}

// Gram of h1 bits: M[t][64][64] exact popcount counts (as float)
__global__ __launch_bounds__(256) void k_gram_h1(const u64* __restrict__ h1b, float* __restrict__ Mf) {
    __shared__ u64 row[4096];
    __shared__ int red[64][4];
    int c = blockIdx.x, t = blockIdx.y, tid = threadIdx.x;
    for (int l = tid; l < 4096; l += 256) {
        int b = l >> 9, w = l & 511;
        row[l] = h1b[((size_t)(t*BB+b)*64 + c)*512 + w];
    }
    __syncthreads();
    int cp = tid >> 2, part = tid & 3;
    int acc = 0;
    for (int j = 0; j < 1024; ++j) {
        int i = part*1024 + j;
        int b = i >> 9, w = i & 511;
        acc += __popcll(row[i] & h1b[((size_t)(t*BB+b)*64 + cp)*512 + w]);
    }
    red[cp][part] = acc;
    __syncthreads();
    if (part == 0)
        Mf[((size_t)t*64 + c)*64 + cp] = (float)(red[cp][0]+red[cp][1]+red[cp][2]+red[cp][3]);
}

// Gram for bit-packed [t][b][C][32] spikes
template<int C>
__global__ __launch_bounds__(256) void k_gram(const u64* __restrict__ bits, float* __restrict__ Mf) {
    __shared__ u64 row[256];
    int c = blockIdx.x, t = blockIdx.y, tid = threadIdx.x;
    row[tid] = bits[((size_t)(t*BB+(tid>>5))*C + c)*32 + (tid&31)];
    __syncthreads();
    if (tid < C) {
        int acc = 0;
        for (int i = 0; i < 256; ++i)
            acc += __popcll(row[i] & bits[((size_t)(t*BB+(i>>5))*C + tid)*32 + (i&31)]);
        Mf[((size_t)t*C + c)*C + tid] = (float)acc;
    }
}

// project Gram through weights -> per-(t,ch) (mean, inv_std)
template<int CIN>
__global__ void k_proj(const float* __restrict__ Mf, const float* __restrict__ w,
        float* __restrict__ st, int COUT, double cnt) {
    __shared__ double z2s[256], mns[256];
    int ch = blockIdx.x, t = blockIdx.y, c2 = threadIdx.x;
    const float* Mt = Mf + (size_t)t*CIN*CIN;
    double y = 0.0;
    for (int c = 0; c < CIN; ++c)
        y += (double)w[(size_t)ch*CIN+c] * (double)Mt[(size_t)c*CIN + c2];
    double wc2 = (double)w[(size_t)ch*CIN+c2];
    z2s[c2] = wc2 * y;
    mns[c2] = wc2 * (double)Mt[(size_t)c2*CIN + c2];
    __syncthreads();
    for (int off = CIN>>1; off > 0; off >>= 1) {
        if (c2 < off) { z2s[c2] += z2s[c2+off]; mns[c2] += mns[c2+off]; }
        __syncthreads();
    }
    if (c2 == 0) {
        double mu = mns[0] / cnt;
        double var = z2s[0] / cnt - mu*mu;
        if (var < 0.0) var = 0.0;
        st[((size_t)t*COUT+ch)*2+0] = (float)mu;
        st[((size_t)t*COUT+ch)*2+1] = 1.0f / sqrtf((float)var + EPSB);
    }
}

// bitpack u8 spikes [tb][C][2048] -> [tb][C][32]
__global__ __launch_bounds__(256) void k_pack(const u8* __restrict__ in, u64* __restrict__ outb, int C) {
    int wave = threadIdx.x >> 6, lane = threadIdx.x & 63;
    int wi = blockIdx.x*4 + wave;
    int w = wi & 31;
    int rc = wi >> 5;           // rc = tb*C + c
    u8 v = in[(size_t)rc*2048 + w*64 + lane];
    u64 m = __ballot(v != 0);
    if (lane == 0) outb[(size_t)rc*32 + w] = m;
}

// edge conv2 apply from h1 bits: GEMM(64->128) + norm + LIF + max over k -> m2 u8
__global__ __launch_bounds__(256) void k_edge2(const u64* __restrict__ h1b, const float* __restrict__ w2,
        const float* __restrict__ st2, const float* __restrict__ g2, const float* __restrict__ be2,
        u8* __restrict__ m2) {
    __shared__ float h1f[64][68];
    __shared__ float w2t[64][132];
    int pt = blockIdx.x, b = blockIdx.y;
    int tid = threadIdx.x;
    for (int l = tid; l < 128*64; l += 256) { int e = l>>6, d = l&63; w2t[d][e] = w2[l]; }
    int d0 = tid >> 2, q = tid & 3;
    int e0 = d0*2;
    float v2a[16], v2b[16];
    #pragma unroll
    for (int i=0;i<16;++i){ v2a[i]=0.f; v2b[i]=0.f; }
    for (int t = 0; t < TT; ++t) {
        __syncthreads();
        u64 wd = h1b[((size_t)(t*BB+b)*64 + d0)*512 + pt];
        #pragma unroll
        for (int j = 0; j < 16; ++j) h1f[d0][q*16+j] = (float)((wd >> (q*16+j)) & 1ull);
        __syncthreads();
        float acc0[16], acc1[16];
        #pragma unroll
        for (int i=0;i<16;++i){acc0[i]=0.f;acc1[i]=0.f;}
        #pragma unroll 4
        for (int d = 0; d < 64; ++d) {
            float wa = w2t[d][e0], wb = w2t[d][e0+1];
            const float4* h4 = (const float4*)&h1f[d][q*16];
            #pragma unroll
            for (int i4 = 0; i4 < 4; ++i4) {
                float4 hv = h4[i4];
                acc0[i4*4+0] += wa*hv.x; acc0[i4*4+1] += wa*hv.y; acc0[i4*4+2] += wa*hv.z; acc0[i4*4+3] += wa*hv.w;
                acc1[i4*4+0] += wb*hv.x; acc1[i4*4+1] += wb*hv.y; acc1[i4*4+2] += wb*hv.z; acc1[i4*4+3] += wb*hv.w;
            }
        }
        {
            float mu2 = st2[((size_t)t*128+e0)*2+0], iv2 = st2[((size_t)t*128+e0)*2+1];
            float ga2 = g2[t*128+e0], bb2 = be2[t*128+e0];
            u32 any = 0u;
            #pragma unroll
            for (int i=0;i<16;++i) {
                float y = (acc0[i]-mu2)*iv2*ga2 + bb2;
                float s = lif_step(v2a[i], y);
                if (s != 0.f) any = 1u;
            }
            m2[(((size_t)t*BB+b)*128 + e0)*NN + pt*4 + q] = (u8)any;
        }
        {
            int e = e0+1;
            float mu2 = st2[((size_t)t*128+e)*2+0], iv2 = st2[((size_t)t*128+e)*2+1];
            float ga2 = g2[t*128+e], bb2 = be2[t*128+e];
            u32 any = 0u;
            #pragma unroll
            for (int i=0;i<16;++i) {
                float y = (acc1[i]-mu2)*iv2*ga2 + bb2;
                float s = lif_step(v2b[i], y);
                if (s != 0.f) any = 1u;
            }
            m2[(((size_t)t*BB+b)*128 + e)*NN + pt*4 + q] = (u8)any;
        }
    }
}

// tiled GEMM over u8 spike input; MODE 1: norm+LIF -> u8 spikes, 2: norm+LIF+OR over n -> mx4
template<int MODE, int CI>
__global__ __launch_bounds__(256) void k_gconv(const u8* __restrict__ in, const float* __restrict__ w,
        const float* __restrict__ st, const float* __restrict__ ga, const float* __restrict__ be,
        u8* __restrict__ outs, u32* __restrict__ outm, int COUT) {
    __shared__ float As[64][33];
    __shared__ float Bs[TT][32][68];
    __shared__ u32 morr[TT][64];
    int nt = blockIdx.x, ft = blockIdx.y, b = blockIdx.z;
    int n0 = nt*64, f0 = ft*64;
    int tid = threadIdx.x;
    int fi = tid >> 4, nj = tid & 15;
    if (MODE == 2) for (int l = tid; l < TT*64; l += 256) morr[l>>6][l&63] = 0u;
    float acc[4][4][TT];
    #pragma unroll
    for (int a=0;a<4;++a)
        #pragma unroll
        for (int c=0;c<4;++c)
            #pragma unroll
            for (int t=0;t<TT;++t) acc[a][c][t]=0.f;
    for (int kc = 0; kc < CI; kc += 32) {
        for (int l = tid; l < 64*32; l += 256) { int f = l>>5, e = l&31; As[f][e] = w[(size_t)(f0+f)*CI + kc + e]; }
        for (int l = tid; l < TT*32*64; l += 256) {
            int t = l >> 11, r = l & 2047, e = r >> 6, n = r & 63;
            Bs[t][e][n] = (float)in[(((size_t)t*BB+b)*CI + kc + e)*NN + n0 + n];
        }
        __syncthreads();
        #pragma unroll 2
        for (int e = 0; e < 32; ++e) {
            float a0 = As[fi*4+0][e], a1 = As[fi*4+1][e], a2 = As[fi*4+2][e], a3 = As[fi*4+3][e];
            #pragma unroll
            for (int t = 0; t < TT; ++t) {
                float4 bq = *((const float4*)&Bs[t][e][nj*4]);
                acc[0][0][t] += a0*bq.x; acc[0][1][t] += a0*bq.y; acc[0][2][t] += a0*bq.z; acc[0][3][t] += a0*bq.w;
                acc[1][0][t] += a1*bq.x; acc[1][1][t] += a1*bq.y; acc[1][2][t] += a1*bq.z; acc[1][3][t] += a1*bq.w;
                acc[2][0][t] += a2*bq.x; acc[2][1][t] += a2*bq.y; acc[2][2][t] += a2*bq.z; acc[2][3][t] += a2*bq.w;
                acc[3][0][t] += a3*bq.x; acc[3][1][t] += a3*bq.y; acc[3][2][t] += a3*bq.z; acc[3][3][t] += a3*bq.w;
            }
        }
        __syncthreads();
    }
    if (MODE == 1) {
        #pragma unroll
        for (int ff=0; ff<4; ++ff) {
            int f = f0 + fi*4 + ff;
            #pragma unroll
            for (int nn=0; nn<4; ++nn) {
                int n = n0 + nj*4 + nn;
                float v = 0.f;
                #pragma unroll
                for (int t=0;t<TT;++t) {
                    int ch = t*COUT + f;
                    float y = (acc[ff][nn][t] - st[(size_t)ch*2+0])*st[(size_t)ch*2+1]*ga[ch] + be[ch];
                    float s = lif_step(v, y);
                    outs[(((size_t)t*BB+b)*COUT + f)*NN + n] = (u8)(s != 0.f);
                }
            }
        }
    } else {
        #pragma unroll
        for (int ff=0; ff<4; ++ff) {
            int f = f0 + fi*4 + ff;
            u32 any[TT] = {0,0,0,0};
            #pragma unroll
            for (int nn=0; nn<4; ++nn) {
                float v = 0.f;
                #pragma unroll
                for (int t=0;t<TT;++t) {
                    int ch = t*COUT + f;
                    float y = (acc[ff][nn][t] - st[(size_t)ch*2+0])*st[(size_t)ch*2+1]*ga[ch] + be[ch];
                    float s = lif_step(v, y);
                    if (s != 0.f) any[t] = 1u;
                }
            }
            #pragma unroll
            for (int t=0;t<TT;++t) if (any[t]) atomicOr(&morr[t][fi*4+ff], 1u);
        }
        __syncthreads();
        for (int l=tid; l<TT*64; l+=256) if (morr[l>>6][l&63]) atomicOr(&outm[((size_t)(l>>6)*BB+b)*COUT + f0 + (l&63)], 1u);
    }
}

__global__ __launch_bounds__(256) void k_out(const u32* __restrict__ mx4, float* __restrict__ out) {
    int i = blockIdx.x*256 + threadIdx.x;
    int b = i >> 10, g = i & 1023;
    float s = (float)(mx4[((size_t)0*BB+b)*1024+g] + mx4[((size_t)1*BB+b)*1024+g]
                    + mx4[((size_t)2*BB+b)*1024+g] + mx4[((size_t)3*BB+b)*1024+g]);
    out[i] = s * 0.25f;
}

extern "C" void kernel_launch(void* const* d_in, const int* in_sizes, int n_in,
                              void* d_out, int out_size, void* d_ws, size_t ws_size,
                              hipStream_t stream) {
    (void)in_sizes; (void)n_in; (void)out_size;
    const float* x    = (const float*)d_in[0];
    const float* tw1  = (const float*)d_in[1];
    const float* tb1  = (const float*)d_in[2];
    const float* tw2  = (const float*)d_in[3];
    const float* tb2  = (const float*)d_in[4];
    const float* tw3  = (const float*)d_in[5];
    const float* tb3  = (const float*)d_in[6];
    const float* tfw1 = (const float*)d_in[7];
    const float* tfb1 = (const float*)d_in[8];
    const float* tfw2 = (const float*)d_in[9];
    const float* tfb2 = (const float*)d_in[10];
    const float* tfw3 = (const float*)d_in[11];
    const float* tfb3 = (const float*)d_in[12];
    const float* w1   = (const float*)d_in[13];
    const float* w2   = (const float*)d_in[14];
    const float* w3   = (const float*)d_in[15];
    const float* w4   = (const float*)d_in[16];
    const float* g1   = (const float*)d_in[17];
    const float* be1  = (const float*)d_in[18];
    const float* g2   = (const float*)d_in[19];
    const float* be2  = (const float*)d_in[20];
    const float* g3   = (const float*)d_in[21];
    const float* be3  = (const float*)d_in[22];
    const float* g4   = (const float*)d_in[23];
    const float* be4  = (const float*)d_in[24];

    char* wsb = (char*)d_ws;
    size_t off = 0;
    auto alloc = [&](size_t bytes) -> void* {
        void* p = wsb + off;
        off = (off + bytes + 255) & ~(size_t)255;
        return p;
    };
    u64* s1b   = (u64*)alloc(sizeof(u64)*(size_t)TT*BB*NN);
    u64* s2b   = (u64*)alloc(sizeof(u64)*(size_t)TT*BB*NN*2);
    u32* mx    = (u32*)alloc(sizeof(u32)*(size_t)TT*BB*1024);
    u32* mx4   = (u32*)alloc(sizeof(u32)*(size_t)TT*BB*1024);
    float* trs = (float*)alloc(sizeof(float)*BB*9);
    float* xa  = (float*)alloc(sizeof(float)*(size_t)BB*14*NN);
    float* sqb = (float*)alloc(sizeof(float)*(size_t)BB*NN);
    int* idx   = (int*)alloc(sizeof(int)*(size_t)BB*NN*KNB);
    float* gf  = (float*)alloc(sizeof(float)*(size_t)BB*28*PP);
    float* part1 = (float*)alloc(sizeof(float)*(size_t)1024*64*2);
    float* st1 = (float*)alloc(sizeof(float)*64*2);
    float* st2 = (float*)alloc(sizeof(float)*512*2);
    float* st3 = (float*)alloc(sizeof(float)*1024*2);
    float* st4 = (float*)alloc(sizeof(float)*4096*2);
    u64* h1b = (u64*)alloc(sizeof(u64)*(size_t)TT*BB*64*512);
    u8*  m2  = (u8*)alloc((size_t)TT*BB*128*NN);
    u8*  h3  = (u8*)alloc((size_t)TT*BB*256*NN);
    u64* m2b = (u64*)alloc(sizeof(u64)*(size_t)TT*BB*128*32);
    u64* h3b = (u64*)alloc(sizeof(u64)*(size_t)TT*BB*256*32);
    float* Mf64  = (float*)alloc(sizeof(float)*(size_t)TT*64*64);
    float* Mf128 = (float*)alloc(sizeof(float)*(size_t)TT*128*128);
    float* Mf256 = (float*)alloc(sizeof(float)*(size_t)TT*256*256);
    if (off > ws_size) return;

    hipMemsetAsync(mx, 0, sizeof(u32)*(size_t)TT*BB*1024, stream);
    hipMemsetAsync(mx4, 0, sizeof(u32)*(size_t)TT*BB*1024, stream);

    // T-Net
    k_tnet1<<<dim3(64), dim3(256), 0, stream>>>(x, tw1, tb1, s1b);
    k_tnet2<<<dim3(64), dim3(256), 0, stream>>>(s1b, tw2, tb2, s2b);
    k_tnet3<<<dim3(32,16,8), dim3(256), 0, stream>>>(s2b, tw3, tb3, mx);
    k_fc<<<dim3(8), dim3(512), 0, stream>>>(mx, tfw1, tfb1, tfw2, tfb2, tfw3, tfb3, trs);
    k_trans<<<dim3(64), dim3(256), 0, stream>>>(x, trs, xa, sqb);
    // KNN + graph feature
    k_knn<<<dim3(NN, BB), dim3(256), 0, stream>>>(xa, sqb, idx);
    k_gfeat<<<dim3((BB*NN*KNB)/256), dim3(256), 0, stream>>>(xa, idx, gf);
    // edge conv1 stats (partials + parallel reduce)
    k_estats1<<<dim3(128, 8), dim3(256), 0, stream>>>(gf, w1, part1);
    k_reduce<<<dim3(64), dim3(256), 0, stream>>>(part1, st1, 64, 1024, 262144.0);
    // edge conv1 apply -> bit-packed spikes
    k_h1<<<dim3(128, 8), dim3(256), 0, stream>>>(gf, w1, st1, g1, be1, h1b);
    // edge conv2 stats via exact Gram + projection
    k_gram_h1<<<dim3(64, TT), dim3(256), 0, stream>>>(h1b, Mf64);
    k_proj<64><<<dim3(128, TT), dim3(64), 0, stream>>>(Mf64, w2, st2, 128, 262144.0);
    // edge conv2 apply + max over k
    k_edge2<<<dim3(512, 8), dim3(256), 0, stream>>>(h1b, w2, st2, g2, be2, m2);
    k_pack<<<dim3(TT*BB*128*32/4), dim3(256), 0, stream>>>(m2, m2b, 128);
    // conv3 (128->256)
    k_gram<128><<<dim3(128, TT), dim3(256), 0, stream>>>(m2b, Mf128);
    k_proj<128><<<dim3(256, TT), dim3(128), 0, stream>>>(Mf128, w3, st3, 256, 16384.0);
    k_gconv<1,128><<<dim3(32,4,8), dim3(256), 0, stream>>>(m2, w3, st3, g3, be3, h3, nullptr, 256);
    k_pack<<<dim3(TT*BB*256*32/4), dim3(256), 0, stream>>>(h3, h3b, 256);
    // conv4 (256->1024)
    k_gram<256><<<dim3(256, TT), dim3(256), 0, stream>>>(h3b, Mf256);
    k_proj<256><<<dim3(1024, TT), dim3(256), 0, stream>>>(Mf256, w4, st4, 1024, 16384.0);
    k_gconv<2,256><<<dim3(32,16,8), dim3(256), 0, stream>>>(h3, w4, st4, g4, be4, nullptr, mx4, 1024);
    // output: mean over t of (max over n)
    k_out<<<dim3(32), dim3(256), 0, stream>>>(mx4, (float*)d_out);
}

// Round 3
// 1219.807 us; speedup vs baseline: 3.5888x; 1.8235x over previous
//
#include <hip/hip_runtime.h>
#include <stdint.h>

#define TT 4
#define BB 8
#define NN 2048
#define KNB 16
#define PP (NN*KNB)
#define VTH 1.0f
#define EPSB 1e-5f

typedef unsigned long long u64;
typedef unsigned int u32;
typedef unsigned char u8;
typedef __attribute__((ext_vector_type(8))) short short8;
typedef __attribute__((ext_vector_type(4))) float f4;

__device__ __forceinline__ float lif_step(float& v, float x) {
    v = v + (x - v) / 2.0f;
    float s = (v - VTH >= 0.0f) ? 1.0f : 0.0f;
    v = v * (1.0f - s);
    return s;
}

// ---------------- T-Net ----------------
__global__ __launch_bounds__(256) void k_tnet1(const float* __restrict__ x, const float* __restrict__ w,
        const float* __restrict__ bi, u64* __restrict__ s1b) {
    int i = blockIdx.x*256 + threadIdx.x;
    int b = i >> 11, n = i & 2047;
    float p0 = x[((size_t)b*14+0)*NN+n];
    float p1 = x[((size_t)b*14+1)*NN+n];
    float p2 = x[((size_t)b*14+2)*NN+n];
    u64 m[TT] = {0,0,0,0};
    for (int d = 0; d < 64; ++d) {
        float z = ((w[d*3+0]*p0 + w[d*3+1]*p1) + w[d*3+2]*p2) + bi[d];
        float v = 0.f;
        #pragma unroll
        for (int t = 0; t < TT; ++t) {
            float s = lif_step(v, z);
            if (s != 0.f) m[t] |= (1ull << d);
        }
    }
    #pragma unroll
    for (int t = 0; t < TT; ++t) s1b[((size_t)t*BB + b)*NN + n] = m[t];
}

// conv2: 64->128, split over 4 channel-chunks of 32 for occupancy
__global__ __launch_bounds__(256) void k_tnet2(const u64* __restrict__ s1b, const float* __restrict__ w,
        const float* __restrict__ bi, u32* __restrict__ s2b32) {
    __shared__ float ws[32*64];
    int tid = threadIdx.x;
    int ec = blockIdx.y;            // channel chunk: e in [ec*32, ec*32+32)
    for (int l = tid; l < 32*64; l += 256) ws[l] = w[ec*32*64 + l];
    __syncthreads();
    int i = blockIdx.x*256 + tid;
    int b = i >> 11, n = i & 2047;
    u64 m[TT];
    #pragma unroll
    for (int t = 0; t < TT; ++t) m[t] = s1b[((size_t)t*BB+b)*NN+n];
    u32 o[TT] = {0,0,0,0};
    for (int el = 0; el < 32; ++el) {
        float z[TT] = {0.f,0.f,0.f,0.f};
        #pragma unroll 8
        for (int d = 0; d < 64; ++d) {
            float wv = ws[el*64+d];
            #pragma unroll
            for (int t = 0; t < TT; ++t) z[t] += ((m[t]>>d)&1ull) ? wv : 0.f;
        }
        float v = 0.f, bb = bi[ec*32 + el];
        #pragma unroll
        for (int t = 0; t < TT; ++t) {
            float s = lif_step(v, z[t] + bb);
            if (s != 0.f) o[t] |= (1u << el);
        }
    }
    #pragma unroll
    for (int t = 0; t < TT; ++t)
        s2b32[(((size_t)t*BB+b)*NN+n)*4 + ec] = o[t];
}

// FC head: 1024->512->256->9
__global__ __launch_bounds__(512) void k_fc(const u32* __restrict__ mx, const float* __restrict__ fw1, const float* __restrict__ fb1,
        const float* __restrict__ fw2, const float* __restrict__ fb2, const float* __restrict__ fw3, const float* __restrict__ fb3,
        float* __restrict__ trans) {
    __shared__ float h0[TT][1024];
    __shared__ float h1[TT][512];
    __shared__ float h2[TT][256];
    __shared__ float h3s[TT][9];
    int b = blockIdx.x, tid = threadIdx.x;
    for (int l = tid; l < TT*1024; l += 512) h0[l>>10][l&1023] = (float)mx[((size_t)(l>>10)*BB + b)*1024 + (l&1023)];
    __syncthreads();
    {
        float z[TT] = {0.f,0.f,0.f,0.f};
        #pragma unroll 4
        for (int f = 0; f < 1024; ++f) {
            float wv = fw1[(size_t)tid*1024 + f];
            #pragma unroll
            for (int t = 0; t < TT; ++t) z[t] += wv * h0[t][f];
        }
        float v = 0.f;
        #pragma unroll
        for (int t = 0; t < TT; ++t) h1[t][tid] = lif_step(v, z[t] + fb1[tid]);
    }
    __syncthreads();
    if (tid < 256) {
        float z[TT] = {0.f,0.f,0.f,0.f};
        #pragma unroll 4
        for (int f = 0; f < 512; ++f) {
            float wv = fw2[(size_t)tid*512 + f];
            #pragma unroll
            for (int t = 0; t < TT; ++t) z[t] += wv * h1[t][f];
        }
        float v = 0.f;
        #pragma unroll
        for (int t = 0; t < TT; ++t) h2[t][tid] = lif_step(v, z[t] + fb2[tid]);
    }
    __syncthreads();
    if (tid < TT*9) {
        int t = tid/9, oo = tid%9;
        float z = 0.f;
        for (int f = 0; f < 256; ++f) z += fw3[oo*256+f]*h2[t][f];
        h3s[t][oo] = z + fb3[oo];
    }
    __syncthreads();
    if (tid < 9) {
        float m = ((h3s[0][tid]+h3s[1][tid]) + (h3s[2][tid]+h3s[3][tid])) * 0.25f;
        int c = tid/3, dd = tid%3;
        trans[b*9+tid] = m + ((c==dd)?1.0f:0.0f);
    }
}

__global__ __launch_bounds__(256) void k_trans(const float* __restrict__ x, const float* __restrict__ tr,
        float* __restrict__ xa, float* __restrict__ sqb) {
    int i = blockIdx.x*256 + threadIdx.x;
    int b = i >> 11, n = i & 2047;
    float p0 = x[((size_t)b*14+0)*NN+n];
    float p1 = x[((size_t)b*14+1)*NN+n];
    float p2 = x[((size_t)b*14+2)*NN+n];
    const float* tb = tr + b*9;
    float a0 = (p0*tb[0] + p1*tb[3]) + p2*tb[6];
    float a1 = (p0*tb[1] + p1*tb[4]) + p2*tb[7];
    float a2 = (p0*tb[2] + p1*tb[5]) + p2*tb[8];
    xa[((size_t)b*14+0)*NN+n] = a0;
    xa[((size_t)b*14+1)*NN+n] = a1;
    xa[((size_t)b*14+2)*NN+n] = a2;
    for (int c = 3; c < 14; ++c) xa[((size_t)b*14+c)*NN+n] = x[((size_t)b*14+c)*NN+n];
    sqb[(size_t)b*NN+n] = (a0*a0 + a1*a1) + a2*a2;
}

__global__ __launch_bounds__(256) void k_knn(const float* __restrict__ xa, const float* __restrict__ sqb, int* __restrict__ idx) {
    __shared__ float pm0[NN], pm1[NN], pm2[NN], sm[NN];
    __shared__ u64 red[4];
    __shared__ u64 winner;
    int n = blockIdx.x, b = blockIdx.y;
    int tid = threadIdx.x;
    for (int l = tid; l < NN; l += 256) {
        pm0[l] = xa[((size_t)b*14+0)*NN+l];
        pm1[l] = xa[((size_t)b*14+1)*NN+l];
        pm2[l] = xa[((size_t)b*14+2)*NN+l];
        sm[l]  = sqb[(size_t)b*NN+l];
    }
    __syncthreads();
    float q0 = pm0[n], q1 = pm1[n], q2 = pm2[n], sn = sm[n];
    float vals[8];
    #pragma unroll
    for (int j = 0; j < 8; ++j) {
        int mm = j*256 + tid;
        float inner = (q0*pm0[mm] + q1*pm1[mm]) + q2*pm2[mm];
        vals[j] = (2.0f*inner - sn) - sm[mm];
    }
    for (int k = 0; k < KNB; ++k) {
        float bv = -3.4e38f; int bj = -1;
        #pragma unroll
        for (int j = 0; j < 8; ++j) if (vals[j] > bv) { bv = vals[j]; bj = j; }
        int bm = (bj < 0) ? -1 : (bj*256 + tid);
        u32 fb = __float_as_uint(bv);
        fb = (fb & 0x80000000u) ? ~fb : (fb | 0x80000000u);
        u64 key = ((u64)fb << 32) | (u32)(~bm);
        #pragma unroll
        for (int o2 = 1; o2 < 64; o2 <<= 1) {
            u64 other = __shfl_xor(key, o2, 64);
            key = (other > key) ? other : key;
        }
        if ((tid & 63) == 0) red[tid >> 6] = key;
        __syncthreads();
        if (tid == 0) {
            u64 k0 = (red[0] > red[1]) ? red[0] : red[1];
            u64 k1 = (red[2] > red[3]) ? red[2] : red[3];
            u64 km = (k0 > k1) ? k0 : k1;
            winner = km;
            idx[((size_t)b*NN + n)*KNB + k] = (int)(~(u32)km);
        }
        __syncthreads();
        int wm = (int)(~(u32)winner);
        if ((wm & 255) == tid) vals[wm >> 8] = -3.4e38f;
        __syncthreads();
    }
}

__global__ __launch_bounds__(256) void k_gfeat(const float* __restrict__ xa, const int* __restrict__ idx, float* __restrict__ gf) {
    int i = blockIdx.x*256 + threadIdx.x;
    int b = i >> 15;
    int r = i & 32767;
    int n = r >> 4;
    int mm = idx[((size_t)b*NN+n)*KNB + (r & 15)];
    size_t pbase = (size_t)b*28*PP + r;
    #pragma unroll
    for (int c = 0; c < 14; ++c) {
        float ctr = xa[((size_t)b*14+c)*NN + n];
        float nb  = xa[((size_t)b*14+c)*NN + mm];
        gf[pbase + (size_t)c*PP] = ctr;
        gf[pbase + (size_t)(14+c)*PP] = nb - ctr;
    }
}

// edge conv1 stats partials
__global__ __launch_bounds__(256) void k_estats1(const float* __restrict__ gf, const float* __restrict__ w1, float* __restrict__ part1) {
    __shared__ float gfs[28][256];
    __shared__ float w1s[64*28];
    __shared__ float wsum[4][64], wsq[4][64];
    int pt = blockIdx.x, b = blockIdx.y;
    int p0 = pt*256, tid = threadIdx.x;
    for (int l = tid; l < 28*256; l += 256) gfs[l>>8][l&255] = gf[((size_t)b*28 + (l>>8))*PP + p0 + (l&255)];
    for (int l = tid; l < 64*28; l += 256) w1s[l] = w1[l];
    __syncthreads();
    int wv = tid>>6, lane = tid&63;
    for (int d = 0; d < 64; ++d) {
        float z = 0.f;
        #pragma unroll
        for (int c = 0; c < 28; ++c) z += w1s[d*28+c]*gfs[c][tid];
        float s = z, q = z*z;
        #pragma unroll
        for (int o = 1; o < 64; o <<= 1) { s += __shfl_xor(s, o, 64); q += __shfl_xor(q, o, 64); }
        if (lane == 0) { wsum[wv][d] = s; wsq[wv][d] = q; }
    }
    __syncthreads();
    if (tid < 64) {
        float s = (wsum[0][tid]+wsum[1][tid])+(wsum[2][tid]+wsum[3][tid]);
        float q = (wsq[0][tid]+wsq[1][tid])+(wsq[2][tid]+wsq[3][tid]);
        size_t blk = (size_t)b*128 + pt;
        part1[(blk*64 + tid)*2+0] = s;
        part1[(blk*64 + tid)*2+1] = q;
    }
}

__global__ __launch_bounds__(256) void k_reduce(const float* __restrict__ part, float* __restrict__ stats, int nch, int nblk, double M) {
    __shared__ double sred[256], qred[256];
    int ch = blockIdx.x, tid = threadIdx.x;
    double s = 0.0, q = 0.0;
    for (int i = tid; i < nblk; i += 256) {
        s += (double)part[((size_t)i*nch + ch)*2 + 0];
        q += (double)part[((size_t)i*nch + ch)*2 + 1];
    }
    sred[tid] = s; qred[tid] = q;
    __syncthreads();
    for (int off = 128; off > 0; off >>= 1) {
        if (tid < off) { sred[tid] += sred[tid+off]; qred[tid] += qred[tid+off]; }
        __syncthreads();
    }
    if (tid == 0) {
        double mu = sred[0] / M;
        double var = qred[0] / M - mu*mu;
        if (var < 0.0) var = 0.0;
        stats[ch*2+0] = (float)mu;
        stats[ch*2+1] = 1.0f / sqrtf((float)var + EPSB);
    }
}

// edge conv1 apply: norm+LIF -> h1b (channel-major bits, for Gram) + h1n (u64 mask per point, for MFMA)
__global__ __launch_bounds__(256) void k_h1(const float* __restrict__ gf, const float* __restrict__ w1,
        const float* __restrict__ st1, const float* __restrict__ g1, const float* __restrict__ be1,
        u64* __restrict__ h1b, u64* __restrict__ h1n) {
    __shared__ float w1s[64*28];
    int tid = threadIdx.x;
    int b = blockIdx.y;
    int p0 = blockIdx.x*256;
    int p = p0 + tid;
    for (int l = tid; l < 64*28; l += 256) w1s[l] = w1[l];
    __syncthreads();
    float gr[28];
    #pragma unroll
    for (int c = 0; c < 28; ++c) gr[c] = gf[((size_t)b*28 + c)*PP + p];
    int wordbase = (p0>>6) + (tid>>6);
    u64 pm[TT] = {0,0,0,0};
    for (int d = 0; d < 64; ++d) {
        float z = 0.f;
        #pragma unroll
        for (int c = 0; c < 28; ++c) z += w1s[d*28+c]*gr[c];
        float mu = st1[d*2+0], iv = st1[d*2+1];
        float v = 0.f;
        #pragma unroll
        for (int t = 0; t < TT; ++t) {
            float y = (z - mu) * iv * g1[t*64+d] + be1[t*64+d];
            float s = lif_step(v, y);
            u64 m = __ballot(s != 0.f);
            if ((tid & 63) == 0) h1b[((size_t)(t*BB+b)*64 + d)*512 + wordbase] = m;
            pm[t] |= ((u64)(s != 0.f)) << d;
        }
    }
    #pragma unroll
    for (int t = 0; t < TT; ++t) h1n[(size_t)(t*BB+b)*PP + p] = pm[t];
}

// Gram of h1 bits
__global__ __launch_bounds__(256) void k_gram_h1(const u64* __restrict__ h1b, float* __restrict__ Mf) {
    __shared__ u64 row[4096];
    __shared__ int red[64][4];
    int c = blockIdx.x, t = blockIdx.y, tid = threadIdx.x;
    for (int l = tid; l < 4096; l += 256) {
        int b = l >> 9, w = l & 511;
        row[l] = h1b[((size_t)(t*BB+b)*64 + c)*512 + w];
    }
    __syncthreads();
    int cp = tid >> 2, part = tid & 3;
    int acc = 0;
    for (int j = 0; j < 1024; ++j) {
        int i = part*1024 + j;
        int b = i >> 9, w = i & 511;
        acc += __popcll(row[i] & h1b[((size_t)(t*BB+b)*64 + cp)*512 + w]);
    }
    red[cp][part] = acc;
    __syncthreads();
    if (part == 0)
        Mf[((size_t)t*64 + c)*64 + cp] = (float)(red[cp][0]+red[cp][1]+red[cp][2]+red[cp][3]);
}

// Gram for bit-packed [tb][C][32] spikes
template<int C>
__global__ __launch_bounds__(256) void k_gram(const u64* __restrict__ bits, float* __restrict__ Mf) {
    __shared__ u64 row[256];
    int c = blockIdx.x, t = blockIdx.y, tid = threadIdx.x;
    row[tid] = bits[((size_t)(t*BB+(tid>>5))*C + c)*32 + (tid&31)];
    __syncthreads();
    if (tid < C) {
        int acc = 0;
        for (int i = 0; i < 256; ++i)
            acc += __popcll(row[i] & bits[((size_t)(t*BB+(i>>5))*C + tid)*32 + (i&31)]);
        Mf[((size_t)t*C + c)*C + tid] = (float)acc;
    }
}

// project Gram through weights -> per-(t,ch) (mean, inv_std)
template<int CIN>
__global__ void k_proj(const float* __restrict__ Mf, const float* __restrict__ w,
        float* __restrict__ st, int COUT, double cnt) {
    __shared__ double z2s[256], mns[256];
    int ch = blockIdx.x, t = blockIdx.y, c2 = threadIdx.x;
    const float* Mt = Mf + (size_t)t*CIN*CIN;
    double y = 0.0;
    for (int c = 0; c < CIN; ++c)
        y += (double)w[(size_t)ch*CIN+c] * (double)Mt[(size_t)c*CIN + c2];
    double wc2 = (double)w[(size_t)ch*CIN+c2];
    z2s[c2] = wc2 * y;
    mns[c2] = wc2 * (double)Mt[(size_t)c2*CIN + c2];
    __syncthreads();
    for (int off = CIN>>1; off > 0; off >>= 1) {
        if (c2 < off) { z2s[c2] += z2s[c2+off]; mns[c2] += mns[c2+off]; }
        __syncthreads();
    }
    if (c2 == 0) {
        double mu = mns[0] / cnt;
        double var = z2s[0] / cnt - mu*mu;
        if (var < 0.0) var = 0.0;
        st[((size_t)t*COUT+ch)*2+0] = (float)mu;
        st[((size_t)t*COUT+ch)*2+1] = 1.0f / sqrtf((float)var + EPSB);
    }
}

// weight prep: fp32 w[F][K] -> exact 3-way bf16 split in MFMA-frag layout [K/8][F][8]
__global__ __launch_bounds__(256) void k_wprep(const float* __restrict__ w,
        short* __restrict__ hi, short* __restrict__ mid, short* __restrict__ lo, int F, int K) {
    int i = blockIdx.x*256 + threadIdx.x;
    if (i >= F*K) return;
    int f = i / K, k = i % K;
    float wv = w[i];
    u32 b0 = __float_as_uint(wv);
    float h = __uint_as_float(b0 & 0xFFFF0000u);     // truncate: exact bf16
    float r1 = wv - h;                                // exact in fp32
    u32 b1 = __float_as_uint(r1);
    float m = __uint_as_float(b1 & 0xFFFF0000u);
    float r2 = r1 - m;                                // exact, <=8 significand bits
    u32 b2 = __float_as_uint(r2);
    size_t o = ((size_t)(k>>3)*F + f)*8 + (k&7);
    hi[o]  = (short)(b0 >> 16);
    mid[o] = (short)(b1 >> 16);
    lo[o]  = (short)(b2 >> 16);
}

// ---------------- MFMA spike conv ----------------
// D[n][f] = S[n][k] * W^T[k][f], exact 3-split bf16. 4 waves: wave w owns n-rows [bx*64+w*16, +16).
// MODE 0: +bias, LIF, OR over n -> outm (tnet3)
// MODE 1: BNTT norm, LIF -> point-major u8 spikes outp[t][b][n][F] (conv3)
// MODE 2: BNTT norm, LIF, OR over n -> outm (conv4)
// MODE 3: BNTT norm, LIF, OR over wave's 16 rows (=k-neighbors) -> outp[t][b][n/16][F] (edge conv2)
// BITS: A rows are u64 bitmasks (K/64 words/row); else u8 rows (stride K).
template<int K, int F, int MODE, bool BITS>
__global__ __launch_bounds__(256) void k_mconv(
        const void* __restrict__ Asrc,
        const short* __restrict__ Whi, const short* __restrict__ Wmd, const short* __restrict__ Wlo,
        const float* __restrict__ st, const float* __restrict__ ga, const float* __restrict__ be,
        const float* __restrict__ bias,
        u8* __restrict__ outp, u32* __restrict__ outm, int NPTS) {
    __shared__ u32 morr[TT][64];
    int tid = threadIdx.x;
    int wave = tid >> 6, lane = tid & 63;
    int l15 = lane & 15, lg = lane >> 4;
    int b = blockIdx.z;
    int n_base = blockIdx.x*64 + wave*16;
    int f0 = blockIdx.y*64;
    if (MODE == 0 || MODE == 2) {
        for (int l = tid; l < TT*64; l += 256) morr[l>>6][l&63] = 0u;
        __syncthreads();
    }
    f4 acc[4][TT];
    #pragma unroll
    for (int i = 0; i < 4; ++i)
        #pragma unroll
        for (int t = 0; t < TT; ++t) acc[i][t] = (f4)0.f;

    const u64* Ab[TT];
    const u8*  Au[TT];
    #pragma unroll
    for (int t = 0; t < TT; ++t) {
        if (BITS) Ab[t] = (const u64*)Asrc + ((size_t)(t*BB+b)*NPTS + n_base + l15)*(K/64);
        else      Au[t] = (const u8*)Asrc  + ((size_t)(t*BB+b)*NPTS + n_base + l15)*K + lg*8;
    }
    for (int k0 = 0; k0 < K; k0 += 32) {
        short8 a[TT];
        #pragma unroll
        for (int t = 0; t < TT; ++t) {
            if (BITS) {
                int kk = k0 + lg*8;
                u64 word = Ab[t][kk >> 6];
                u32 byte = (u32)(word >> (kk & 63)) & 0xFFu;
                #pragma unroll
                for (int j = 0; j < 8; ++j) a[t][j] = (short)(((byte>>j)&1u) * 0x3F80u);
            } else {
                u64 w8 = *(const u64*)(Au[t] + k0);
                #pragma unroll
                for (int j = 0; j < 8; ++j) a[t][j] = (short)(((u32)(w8>>(8*j))&1u) * 0x3F80u);
            }
        }
        size_t wrow = ((size_t)((k0>>3) + lg)*F + f0 + l15)*8;
        #pragma unroll
        for (int fs = 0; fs < 4; ++fs) {
            size_t wo = wrow + (size_t)fs*128;
            short8 whi = *(const short8*)(Whi + wo);
            short8 wmd = *(const short8*)(Wmd + wo);
            short8 wlo = *(const short8*)(Wlo + wo);
            #pragma unroll
            for (int t = 0; t < TT; ++t) {
                acc[fs][t] = __builtin_amdgcn_mfma_f32_16x16x32_bf16(a[t], whi, acc[fs][t], 0, 0, 0);
                acc[fs][t] = __builtin_amdgcn_mfma_f32_16x16x32_bf16(a[t], wmd, acc[fs][t], 0, 0, 0);
                acc[fs][t] = __builtin_amdgcn_mfma_f32_16x16x32_bf16(a[t], wlo, acc[fs][t], 0, 0, 0);
            }
        }
    }
    // epilogue: D row = n_base + lg*4 + reg, col f = f0 + fs*16 + l15
    if (MODE == 1) {
        #pragma unroll
        for (int fs = 0; fs < 4; ++fs) {
            int f = f0 + fs*16 + l15;
            #pragma unroll
            for (int reg = 0; reg < 4; ++reg) {
                int n = n_base + lg*4 + reg;
                float v = 0.f;
                #pragma unroll
                for (int t = 0; t < TT; ++t) {
                    int ch = t*F + f;
                    float y = (acc[fs][t][reg] - st[(size_t)ch*2+0])*st[(size_t)ch*2+1]*ga[ch] + be[ch];
                    float s = lif_step(v, y);
                    outp[((size_t)(t*BB+b)*NPTS + n)*F + f] = (u8)(s != 0.f);
                }
            }
        }
    } else if (MODE == 3) {
        #pragma unroll
        for (int fs = 0; fs < 4; ++fs) {
            int f = f0 + fs*16 + l15;
            u32 nib = 0u;
            #pragma unroll
            for (int reg = 0; reg < 4; ++reg) {
                float v = 0.f;
                #pragma unroll
                for (int t = 0; t < TT; ++t) {
                    int ch = t*F + f;
                    float y = (acc[fs][t][reg] - st[(size_t)ch*2+0])*st[(size_t)ch*2+1]*ga[ch] + be[ch];
                    float s = lif_step(v, y);
                    if (s != 0.f) nib |= (1u << t);
                }
            }
            nib |= __shfl_xor(nib, 16, 64);
            nib |= __shfl_xor(nib, 32, 64);
            if (lg == 0) {
                int n_pt = n_base >> 4;
                #pragma unroll
                for (int t = 0; t < TT; ++t)
                    outp[((size_t)(t*BB+b)*(NPTS>>4) + n_pt)*F + f] = (u8)((nib>>t)&1u);
            }
        }
    } else {
        #pragma unroll
        for (int fs = 0; fs < 4; ++fs) {
            int f = f0 + fs*16 + l15;
            u32 any[TT] = {0,0,0,0};
            float bb = (MODE == 0) ? bias[f] : 0.f;
            #pragma unroll
            for (int reg = 0; reg < 4; ++reg) {
                float v = 0.f;
                #pragma unroll
                for (int t = 0; t < TT; ++t) {
                    float y;
                    if (MODE == 0) y = acc[fs][t][reg] + bb;
                    else {
                        int ch = t*F + f;
                        y = (acc[fs][t][reg] - st[(size_t)ch*2+0])*st[(size_t)ch*2+1]*ga[ch] + be[ch];
                    }
                    float s = lif_step(v, y);
                    if (s != 0.f) any[t] = 1u;
                }
            }
            #pragma unroll
            for (int t = 0; t < TT; ++t) if (any[t]) atomicOr(&morr[t][fs*16+l15], 1u);
        }
        __syncthreads();
        for (int l = tid; l < TT*64; l += 256)
            if (morr[l>>6][l&63]) atomicOr(&outm[((size_t)((l>>6)*BB+b))*F + f0 + (l&63)], 1u);
    }
}

// repack point-major u8 spikes [t][b][n][C] -> channel-major bits [t][b][C][32 words over n]
template<int C>
__global__ __launch_bounds__(256) void k_repack(const u8* __restrict__ sp, u64* __restrict__ bits) {
    __shared__ u8 tile[64][C+4];
    int tid = threadIdx.x;
    int nw = blockIdx.x, b = blockIdx.y, t = blockIdx.z;
    const u8* src = sp + ((size_t)(t*BB+b)*NN + nw*64)*C;
    for (int i = tid*4; i < 64*C; i += 1024) {
        u32 v = *(const u32*)(src + i);
        int r = i / C, c = i % C;
        *(u32*)&tile[r][c] = v;
    }
    __syncthreads();
    int wave = tid >> 6, lane = tid & 63;
    for (int c = wave; c < C; c += 4) {
        u64 m = __ballot(tile[lane][c] != 0);
        if (lane == 0) bits[((size_t)(t*BB+b)*C + c)*32 + nw] = m;
    }
}

__global__ __launch_bounds__(256) void k_out(const u32* __restrict__ mx4, float* __restrict__ out) {
    int i = blockIdx.x*256 + threadIdx.x;
    int b = i >> 10, g = i & 1023;
    float s = (float)(mx4[((size_t)0*BB+b)*1024+g] + mx4[((size_t)1*BB+b)*1024+g]
                    + mx4[((size_t)2*BB+b)*1024+g] + mx4[((size_t)3*BB+b)*1024+g]);
    out[i] = s * 0.25f;
}

extern "C" void kernel_launch(void* const* d_in, const int* in_sizes, int n_in,
                              void* d_out, int out_size, void* d_ws, size_t ws_size,
                              hipStream_t stream) {
    (void)in_sizes; (void)n_in; (void)out_size;
    const float* x    = (const float*)d_in[0];
    const float* tw1  = (const float*)d_in[1];
    const float* tb1  = (const float*)d_in[2];
    const float* tw2  = (const float*)d_in[3];
    const float* tb2  = (const float*)d_in[4];
    const float* tw3  = (const float*)d_in[5];
    const float* tb3  = (const float*)d_in[6];
    const float* tfw1 = (const float*)d_in[7];
    const float* tfb1 = (const float*)d_in[8];
    const float* tfw2 = (const float*)d_in[9];
    const float* tfb2 = (const float*)d_in[10];
    const float* tfw3 = (const float*)d_in[11];
    const float* tfb3 = (const float*)d_in[12];
    const float* w1   = (const float*)d_in[13];
    const float* w2   = (const float*)d_in[14];
    const float* w3   = (const float*)d_in[15];
    const float* w4   = (const float*)d_in[16];
    const float* g1   = (const float*)d_in[17];
    const float* be1  = (const float*)d_in[18];
    const float* g2   = (const float*)d_in[19];
    const float* be2  = (const float*)d_in[20];
    const float* g3   = (const float*)d_in[21];
    const float* be3  = (const float*)d_in[22];
    const float* g4   = (const float*)d_in[23];
    const float* be4  = (const float*)d_in[24];

    char* wsb = (char*)d_ws;
    size_t off = 0;
    auto alloc = [&](size_t bytes) -> void* {
        void* p = wsb + off;
        off = (off + bytes + 255) & ~(size_t)255;
        return p;
    };
    u64* s1b   = (u64*)alloc(sizeof(u64)*(size_t)TT*BB*NN);
    u64* s2b   = (u64*)alloc(sizeof(u64)*(size_t)TT*BB*NN*2);   // [t][b][n] 2 u64 (128 ch bits)
    u32* mx    = (u32*)alloc(sizeof(u32)*(size_t)TT*BB*1024);
    u32* mx4   = (u32*)alloc(sizeof(u32)*(size_t)TT*BB*1024);
    float* trs = (float*)alloc(sizeof(float)*BB*9);
    float* xa  = (float*)alloc(sizeof(float)*(size_t)BB*14*NN);
    float* sqb = (float*)alloc(sizeof(float)*(size_t)BB*NN);
    int* idx   = (int*)alloc(sizeof(int)*(size_t)BB*NN*KNB);
    float* gf  = (float*)alloc(sizeof(float)*(size_t)BB*28*PP);
    float* part1 = (float*)alloc(sizeof(float)*(size_t)1024*64*2);
    float* st1 = (float*)alloc(sizeof(float)*64*2);
    float* st2 = (float*)alloc(sizeof(float)*512*2);
    float* st3 = (float*)alloc(sizeof(float)*1024*2);
    float* st4 = (float*)alloc(sizeof(float)*4096*2);
    u64* h1b = (u64*)alloc(sizeof(u64)*(size_t)TT*BB*64*512);   // channel-major bits (Gram)
    u64* h1n = (u64*)alloc(sizeof(u64)*(size_t)TT*BB*PP);       // per-point 64ch mask (MFMA A)
    u8*  m2p = (u8*)alloc((size_t)TT*BB*NN*128);                // point-major spikes
    u8*  h3p = (u8*)alloc((size_t)TT*BB*NN*256);
    u64* m2b = (u64*)alloc(sizeof(u64)*(size_t)TT*BB*128*32);
    u64* h3b = (u64*)alloc(sizeof(u64)*(size_t)TT*BB*256*32);
    float* Mf64  = (float*)alloc(sizeof(float)*(size_t)TT*64*64);
    float* Mf128 = (float*)alloc(sizeof(float)*(size_t)TT*128*128);
    float* Mf256 = (float*)alloc(sizeof(float)*(size_t)TT*256*256);
    short* wp2h = (short*)alloc(sizeof(short)*(size_t)128*64);   // edge conv2 (F=128,K=64)
    short* wp2m = (short*)alloc(sizeof(short)*(size_t)128*64);
    short* wp2l = (short*)alloc(sizeof(short)*(size_t)128*64);
    short* wp3h = (short*)alloc(sizeof(short)*(size_t)256*128);  // conv3
    short* wp3m = (short*)alloc(sizeof(short)*(size_t)256*128);
    short* wp3l = (short*)alloc(sizeof(short)*(size_t)256*128);
    short* wp4h = (short*)alloc(sizeof(short)*(size_t)1024*256); // conv4
    short* wp4m = (short*)alloc(sizeof(short)*(size_t)1024*256);
    short* wp4l = (short*)alloc(sizeof(short)*(size_t)1024*256);
    short* wpth = (short*)alloc(sizeof(short)*(size_t)1024*128); // tnet conv3
    short* wptm = (short*)alloc(sizeof(short)*(size_t)1024*128);
    short* wptl = (short*)alloc(sizeof(short)*(size_t)1024*128);
    if (off > ws_size) return;

    hipMemsetAsync(mx, 0, sizeof(u32)*(size_t)TT*BB*1024, stream);
    hipMemsetAsync(mx4, 0, sizeof(u32)*(size_t)TT*BB*1024, stream);

    // weight prep (exact 3-way bf16 split)
    k_wprep<<<dim3((128*64+255)/256), dim3(256), 0, stream>>>(w2, wp2h, wp2m, wp2l, 128, 64);
    k_wprep<<<dim3((256*128+255)/256), dim3(256), 0, stream>>>(w3, wp3h, wp3m, wp3l, 256, 128);
    k_wprep<<<dim3((1024*256+255)/256), dim3(256), 0, stream>>>(w4, wp4h, wp4m, wp4l, 1024, 256);
    k_wprep<<<dim3((1024*128+255)/256), dim3(256), 0, stream>>>(tw3, wpth, wptm, wptl, 1024, 128);

    // T-Net
    k_tnet1<<<dim3(64), dim3(256), 0, stream>>>(x, tw1, tb1, s1b);
    k_tnet2<<<dim3(64, 4), dim3(256), 0, stream>>>(s1b, tw2, tb2, (u32*)s2b);
    k_mconv<128,1024,0,true><<<dim3(32,16,8), dim3(256), 0, stream>>>(
        s2b, wpth, wptm, wptl, nullptr, nullptr, nullptr, tb3, nullptr, mx, NN);
    k_fc<<<dim3(8), dim3(512), 0, stream>>>(mx, tfw1, tfb1, tfw2, tfb2, tfw3, tfb3, trs);
    k_trans<<<dim3(64), dim3(256), 0, stream>>>(x, trs, xa, sqb);
    // KNN + graph feature
    k_knn<<<dim3(NN, BB), dim3(256), 0, stream>>>(xa, sqb, idx);
    k_gfeat<<<dim3((BB*NN*KNB)/256), dim3(256), 0, stream>>>(xa, idx, gf);
    // edge conv1 stats + apply
    k_estats1<<<dim3(128, 8), dim3(256), 0, stream>>>(gf, w1, part1);
    k_reduce<<<dim3(64), dim3(256), 0, stream>>>(part1, st1, 64, 1024, 262144.0);
    k_h1<<<dim3(128, 8), dim3(256), 0, stream>>>(gf, w1, st1, g1, be1, h1b, h1n);
    // edge conv2: stats via Gram, apply via MFMA (+ max over k)
    k_gram_h1<<<dim3(64, TT), dim3(256), 0, stream>>>(h1b, Mf64);
    k_proj<64><<<dim3(128, TT), dim3(64), 0, stream>>>(Mf64, w2, st2, 128, 262144.0);
    k_mconv<64,128,3,true><<<dim3(PP/64,2,8), dim3(256), 0, stream>>>(
        h1n, wp2h, wp2m, wp2l, st2, g2, be2, nullptr, m2p, nullptr, PP);
    k_repack<128><<<dim3(32,8,4), dim3(256), 0, stream>>>(m2p, m2b);
    // conv3
    k_gram<128><<<dim3(128, TT), dim3(256), 0, stream>>>(m2b, Mf128);
    k_proj<128><<<dim3(256, TT), dim3(128), 0, stream>>>(Mf128, w3, st3, 256, 16384.0);
    k_mconv<128,256,1,false><<<dim3(32,4,8), dim3(256), 0, stream>>>(
        m2p, wp3h, wp3m, wp3l, st3, g3, be3, nullptr, h3p, nullptr, NN);
    k_repack<256><<<dim3(32,8,4), dim3(256), 0, stream>>>(h3p, h3b);
    // conv4
    k_gram<256><<<dim3(256, TT), dim3(256), 0, stream>>>(h3b, Mf256);
    k_proj<256><<<dim3(1024, TT), dim3(256), 0, stream>>>(Mf256, w4, st4, 1024, 16384.0);
    k_mconv<256,1024,2,false><<<dim3(32,16,8), dim3(256), 0, stream>>>(
        h3p, wp4h, wp4m, wp4l, st4, g4, be4, nullptr, nullptr, mx4, NN);
    // output
    k_out<<<dim3(32), dim3(256), 0, stream>>>(mx4, (float*)d_out);
}

// Round 4
// 1083.168 us; speedup vs baseline: 4.0415x; 1.1261x over previous
//
#include <hip/hip_runtime.h>
#include <stdint.h>

#define TT 4
#define BB 8
#define NN 2048
#define KNB 16
#define PP (NN*KNB)
#define VTH 1.0f
#define EPSB 1e-5f

typedef unsigned long long u64;
typedef unsigned int u32;
typedef unsigned char u8;
typedef __attribute__((ext_vector_type(8))) short short8;
typedef __attribute__((ext_vector_type(4))) float f4;

__device__ __forceinline__ float lif_step(float& v, float x) {
    v = v + (x - v) / 2.0f;
    float s = (v - VTH >= 0.0f) ? 1.0f : 0.0f;
    v = v * (1.0f - s);
    return s;
}

// ---------------- T-Net ----------------
__global__ __launch_bounds__(256) void k_tnet1(const float* __restrict__ x, const float* __restrict__ w,
        const float* __restrict__ bi, u64* __restrict__ s1b) {
    int i = blockIdx.x*256 + threadIdx.x;
    int b = i >> 11, n = i & 2047;
    float p0 = x[((size_t)b*14+0)*NN+n];
    float p1 = x[((size_t)b*14+1)*NN+n];
    float p2 = x[((size_t)b*14+2)*NN+n];
    u64 m[TT] = {0,0,0,0};
    for (int d = 0; d < 64; ++d) {
        float z = ((w[d*3+0]*p0 + w[d*3+1]*p1) + w[d*3+2]*p2) + bi[d];
        float v = 0.f;
        #pragma unroll
        for (int t = 0; t < TT; ++t) {
            float s = lif_step(v, z);
            if (s != 0.f) m[t] |= (1ull << d);
        }
    }
    #pragma unroll
    for (int t = 0; t < TT; ++t) s1b[((size_t)t*BB + b)*NN + n] = m[t];
}

// conv2: 64->128, split over 4 channel-chunks of 32 for occupancy
__global__ __launch_bounds__(256) void k_tnet2(const u64* __restrict__ s1b, const float* __restrict__ w,
        const float* __restrict__ bi, u32* __restrict__ s2b32) {
    __shared__ float ws[32*64];
    int tid = threadIdx.x;
    int ec = blockIdx.y;            // channel chunk: e in [ec*32, ec*32+32)
    for (int l = tid; l < 32*64; l += 256) ws[l] = w[ec*32*64 + l];
    __syncthreads();
    int i = blockIdx.x*256 + tid;
    int b = i >> 11, n = i & 2047;
    u64 m[TT];
    #pragma unroll
    for (int t = 0; t < TT; ++t) m[t] = s1b[((size_t)t*BB+b)*NN+n];
    u32 o[TT] = {0,0,0,0};
    for (int el = 0; el < 32; ++el) {
        float z[TT] = {0.f,0.f,0.f,0.f};
        #pragma unroll 8
        for (int d = 0; d < 64; ++d) {
            float wv = ws[el*64+d];
            #pragma unroll
            for (int t = 0; t < TT; ++t) z[t] += ((m[t]>>d)&1ull) ? wv : 0.f;
        }
        float v = 0.f, bb = bi[ec*32 + el];
        #pragma unroll
        for (int t = 0; t < TT; ++t) {
            float s = lif_step(v, z[t] + bb);
            if (s != 0.f) o[t] |= (1u << el);
        }
    }
    #pragma unroll
    for (int t = 0; t < TT; ++t)
        s2b32[(((size_t)t*BB+b)*NN+n)*4 + ec] = o[t];
}

// FC head: 1024->512->256->9
__global__ __launch_bounds__(512) void k_fc(const u32* __restrict__ mx, const float* __restrict__ fw1, const float* __restrict__ fb1,
        const float* __restrict__ fw2, const float* __restrict__ fb2, const float* __restrict__ fw3, const float* __restrict__ fb3,
        float* __restrict__ trans) {
    __shared__ float h0[TT][1024];
    __shared__ float h1[TT][512];
    __shared__ float h2[TT][256];
    __shared__ float h3s[TT][9];
    int b = blockIdx.x, tid = threadIdx.x;
    for (int l = tid; l < TT*1024; l += 512) h0[l>>10][l&1023] = (float)mx[((size_t)(l>>10)*BB + b)*1024 + (l&1023)];
    __syncthreads();
    {
        float z[TT] = {0.f,0.f,0.f,0.f};
        #pragma unroll 4
        for (int f = 0; f < 1024; ++f) {
            float wv = fw1[(size_t)tid*1024 + f];
            #pragma unroll
            for (int t = 0; t < TT; ++t) z[t] += wv * h0[t][f];
        }
        float v = 0.f;
        #pragma unroll
        for (int t = 0; t < TT; ++t) h1[t][tid] = lif_step(v, z[t] + fb1[tid]);
    }
    __syncthreads();
    if (tid < 256) {
        float z[TT] = {0.f,0.f,0.f,0.f};
        #pragma unroll 4
        for (int f = 0; f < 512; ++f) {
            float wv = fw2[(size_t)tid*512 + f];
            #pragma unroll
            for (int t = 0; t < TT; ++t) z[t] += wv * h1[t][f];
        }
        float v = 0.f;
        #pragma unroll
        for (int t = 0; t < TT; ++t) h2[t][tid] = lif_step(v, z[t] + fb2[tid]);
    }
    __syncthreads();
    if (tid < TT*9) {
        int t = tid/9, oo = tid%9;
        float z = 0.f;
        for (int f = 0; f < 256; ++f) z += fw3[oo*256+f]*h2[t][f];
        h3s[t][oo] = z + fb3[oo];
    }
    __syncthreads();
    if (tid < 9) {
        float m = ((h3s[0][tid]+h3s[1][tid]) + (h3s[2][tid]+h3s[3][tid])) * 0.25f;
        int c = tid/3, dd = tid%3;
        trans[b*9+tid] = m + ((c==dd)?1.0f:0.0f);
    }
}

// apply transform; also emit packed float4 (x,y,z,sq) for KNN
__global__ __launch_bounds__(256) void k_trans(const float* __restrict__ x, const float* __restrict__ tr,
        float* __restrict__ xa, float4* __restrict__ xa4) {
    int i = blockIdx.x*256 + threadIdx.x;
    int b = i >> 11, n = i & 2047;
    float p0 = x[((size_t)b*14+0)*NN+n];
    float p1 = x[((size_t)b*14+1)*NN+n];
    float p2 = x[((size_t)b*14+2)*NN+n];
    const float* tb = tr + b*9;
    float a0 = (p0*tb[0] + p1*tb[3]) + p2*tb[6];
    float a1 = (p0*tb[1] + p1*tb[4]) + p2*tb[7];
    float a2 = (p0*tb[2] + p1*tb[5]) + p2*tb[8];
    xa[((size_t)b*14+0)*NN+n] = a0;
    xa[((size_t)b*14+1)*NN+n] = a1;
    xa[((size_t)b*14+2)*NN+n] = a2;
    for (int c = 3; c < 14; ++c) xa[((size_t)b*14+c)*NN+n] = x[((size_t)b*14+c)*NN+n];
    float4 p;
    p.x = a0; p.y = a1; p.z = a2;
    p.w = (a0*a0 + a1*a1) + a2*a2;
    xa4[(size_t)b*NN+n] = p;
}

// KNN: one wave per query point; 32 candidate distances per lane in registers;
// 16 rounds of (local argmax + wave shuffle-max on packed u64 key). No LDS, no barriers.
__global__ __launch_bounds__(256) void k_knn(const float4* __restrict__ xa4, int* __restrict__ idx) {
    int wave = threadIdx.x >> 6, lane = threadIdx.x & 63;
    int b = blockIdx.y;
    int n = blockIdx.x*4 + wave;
    const float4* P = xa4 + (size_t)b*NN;
    float4 q = P[n];
    float sn = q.w;
    float vals[32];
    #pragma unroll
    for (int j = 0; j < 32; ++j) {
        float4 p = P[j*64 + lane];
        float inner = (q.x*p.x + q.y*p.y) + q.z*p.z;
        vals[j] = (2.0f*inner - sn) - p.w;
    }
    for (int k = 0; k < KNB; ++k) {
        float bv = -3.4e38f; int bj = 0;
        #pragma unroll
        for (int j = 0; j < 32; ++j) if (vals[j] > bv) { bv = vals[j]; bj = j; }
        int bm = bj*64 + lane;
        u32 fb = __float_as_uint(bv);
        fb = (fb & 0x80000000u) ? ~fb : (fb | 0x80000000u);
        u64 key = ((u64)fb << 32) | (u32)(~bm);
        #pragma unroll
        for (int o2 = 1; o2 < 64; o2 <<= 1) {
            u64 other = __shfl_xor(key, o2, 64);
            key = (other > key) ? other : key;
        }
        int wm = (int)(~(u32)key);
        if (lane == 0) idx[((size_t)b*NN + n)*KNB + k] = wm;
        int wl = wm & 63, wj = wm >> 6;
        if (lane == wl) {
            #pragma unroll
            for (int j = 0; j < 32; ++j) if (j == wj) vals[j] = -3.4e38f;
        }
    }
}

__global__ __launch_bounds__(256) void k_gfeat(const float* __restrict__ xa, const int* __restrict__ idx, float* __restrict__ gf) {
    int i = blockIdx.x*256 + threadIdx.x;
    int b = i >> 15;
    int r = i & 32767;
    int n = r >> 4;
    int mm = idx[((size_t)b*NN+n)*KNB + (r & 15)];
    size_t pbase = (size_t)b*28*PP + r;
    #pragma unroll
    for (int c = 0; c < 14; ++c) {
        float ctr = xa[((size_t)b*14+c)*NN + n];
        float nb  = xa[((size_t)b*14+c)*NN + mm];
        gf[pbase + (size_t)c*PP] = ctr;
        gf[pbase + (size_t)(14+c)*PP] = nb - ctr;
    }
}

// edge conv1 stats partials
__global__ __launch_bounds__(256) void k_estats1(const float* __restrict__ gf, const float* __restrict__ w1, float* __restrict__ part1) {
    __shared__ float gfs[28][256];
    __shared__ float w1s[64*28];
    __shared__ float wsum[4][64], wsq[4][64];
    int pt = blockIdx.x, b = blockIdx.y;
    int p0 = pt*256, tid = threadIdx.x;
    for (int l = tid; l < 28*256; l += 256) gfs[l>>8][l&255] = gf[((size_t)b*28 + (l>>8))*PP + p0 + (l&255)];
    for (int l = tid; l < 64*28; l += 256) w1s[l] = w1[l];
    __syncthreads();
    int wv = tid>>6, lane = tid&63;
    for (int d = 0; d < 64; ++d) {
        float z = 0.f;
        #pragma unroll
        for (int c = 0; c < 28; ++c) z += w1s[d*28+c]*gfs[c][tid];
        float s = z, q = z*z;
        #pragma unroll
        for (int o = 1; o < 64; o <<= 1) { s += __shfl_xor(s, o, 64); q += __shfl_xor(q, o, 64); }
        if (lane == 0) { wsum[wv][d] = s; wsq[wv][d] = q; }
    }
    __syncthreads();
    if (tid < 64) {
        float s = (wsum[0][tid]+wsum[1][tid])+(wsum[2][tid]+wsum[3][tid]);
        float q = (wsq[0][tid]+wsq[1][tid])+(wsq[2][tid]+wsq[3][tid]);
        size_t blk = (size_t)b*128 + pt;
        part1[(blk*64 + tid)*2+0] = s;
        part1[(blk*64 + tid)*2+1] = q;
    }
}

__global__ __launch_bounds__(256) void k_reduce(const float* __restrict__ part, float* __restrict__ stats, int nch, int nblk, double M) {
    __shared__ double sred[256], qred[256];
    int ch = blockIdx.x, tid = threadIdx.x;
    double s = 0.0, q = 0.0;
    for (int i = tid; i < nblk; i += 256) {
        s += (double)part[((size_t)i*nch + ch)*2 + 0];
        q += (double)part[((size_t)i*nch + ch)*2 + 1];
    }
    sred[tid] = s; qred[tid] = q;
    __syncthreads();
    for (int off = 128; off > 0; off >>= 1) {
        if (tid < off) { sred[tid] += sred[tid+off]; qred[tid] += qred[tid+off]; }
        __syncthreads();
    }
    if (tid == 0) {
        double mu = sred[0] / M;
        double var = qred[0] / M - mu*mu;
        if (var < 0.0) var = 0.0;
        stats[ch*2+0] = (float)mu;
        stats[ch*2+1] = 1.0f / sqrtf((float)var + EPSB);
    }
}

// edge conv1 apply: norm+LIF -> h1b (channel-major bits, for Gram) + h1n (u64 mask per point, for MFMA)
__global__ __launch_bounds__(256) void k_h1(const float* __restrict__ gf, const float* __restrict__ w1,
        const float* __restrict__ st1, const float* __restrict__ g1, const float* __restrict__ be1,
        u64* __restrict__ h1b, u64* __restrict__ h1n) {
    __shared__ float w1s[64*28];
    int tid = threadIdx.x;
    int b = blockIdx.y;
    int p0 = blockIdx.x*256;
    int p = p0 + tid;
    for (int l = tid; l < 64*28; l += 256) w1s[l] = w1[l];
    __syncthreads();
    float gr[28];
    #pragma unroll
    for (int c = 0; c < 28; ++c) gr[c] = gf[((size_t)b*28 + c)*PP + p];
    int wordbase = (p0>>6) + (tid>>6);
    u64 pm[TT] = {0,0,0,0};
    for (int d = 0; d < 64; ++d) {
        float z = 0.f;
        #pragma unroll
        for (int c = 0; c < 28; ++c) z += w1s[d*28+c]*gr[c];
        float mu = st1[d*2+0], iv = st1[d*2+1];
        float v = 0.f;
        #pragma unroll
        for (int t = 0; t < TT; ++t) {
            float y = (z - mu) * iv * g1[t*64+d] + be1[t*64+d];
            float s = lif_step(v, y);
            u64 m = __ballot(s != 0.f);
            if ((tid & 63) == 0) h1b[((size_t)(t*BB+b)*64 + d)*512 + wordbase] = m;
            pm[t] |= ((u64)(s != 0.f)) << d;
        }
    }
    #pragma unroll
    for (int t = 0; t < TT; ++t) h1n[(size_t)(t*BB+b)*PP + p] = pm[t];
}

// Gram of h1 bits
__global__ __launch_bounds__(256) void k_gram_h1(const u64* __restrict__ h1b, float* __restrict__ Mf) {
    __shared__ u64 row[4096];
    __shared__ int red[64][4];
    int c = blockIdx.x, t = blockIdx.y, tid = threadIdx.x;
    for (int l = tid; l < 4096; l += 256) {
        int b = l >> 9, w = l & 511;
        row[l] = h1b[((size_t)(t*BB+b)*64 + c)*512 + w];
    }
    __syncthreads();
    int cp = tid >> 2, part = tid & 3;
    int acc = 0;
    for (int j = 0; j < 1024; ++j) {
        int i = part*1024 + j;
        int b = i >> 9, w = i & 511;
        acc += __popcll(row[i] & h1b[((size_t)(t*BB+b)*64 + cp)*512 + w]);
    }
    red[cp][part] = acc;
    __syncthreads();
    if (part == 0)
        Mf[((size_t)t*64 + c)*64 + cp] = (float)(red[cp][0]+red[cp][1]+red[cp][2]+red[cp][3]);
}

// Gram for bit-packed [tb][C][32] spikes
template<int C>
__global__ __launch_bounds__(256) void k_gram(const u64* __restrict__ bits, float* __restrict__ Mf) {
    __shared__ u64 row[256];
    int c = blockIdx.x, t = blockIdx.y, tid = threadIdx.x;
    row[tid] = bits[((size_t)(t*BB+(tid>>5))*C + c)*32 + (tid&31)];
    __syncthreads();
    if (tid < C) {
        int acc = 0;
        for (int i = 0; i < 256; ++i)
            acc += __popcll(row[i] & bits[((size_t)(t*BB+(i>>5))*C + tid)*32 + (i&31)]);
        Mf[((size_t)t*C + c)*C + tid] = (float)acc;
    }
}

// project Gram through weights -> per-(t,ch) (mean, inv_std)
template<int CIN>
__global__ void k_proj(const float* __restrict__ Mf, const float* __restrict__ w,
        float* __restrict__ st, int COUT, double cnt) {
    __shared__ double z2s[256], mns[256];
    int ch = blockIdx.x, t = blockIdx.y, c2 = threadIdx.x;
    const float* Mt = Mf + (size_t)t*CIN*CIN;
    double y = 0.0;
    for (int c = 0; c < CIN; ++c)
        y += (double)w[(size_t)ch*CIN+c] * (double)Mt[(size_t)c*CIN + c2];
    double wc2 = (double)w[(size_t)ch*CIN+c2];
    z2s[c2] = wc2 * y;
    mns[c2] = wc2 * (double)Mt[(size_t)c2*CIN + c2];
    __syncthreads();
    for (int off = CIN>>1; off > 0; off >>= 1) {
        if (c2 < off) { z2s[c2] += z2s[c2+off]; mns[c2] += mns[c2+off]; }
        __syncthreads();
    }
    if (c2 == 0) {
        double mu = mns[0] / cnt;
        double var = z2s[0] / cnt - mu*mu;
        if (var < 0.0) var = 0.0;
        st[((size_t)t*COUT+ch)*2+0] = (float)mu;
        st[((size_t)t*COUT+ch)*2+1] = 1.0f / sqrtf((float)var + EPSB);
    }
}

// weight prep: fp32 w[F][K] -> exact 3-way bf16 split in MFMA-frag layout [K/8][F][8]
__global__ __launch_bounds__(256) void k_wprep(const float* __restrict__ w,
        short* __restrict__ hi, short* __restrict__ mid, short* __restrict__ lo, int F, int K) {
    int i = blockIdx.x*256 + threadIdx.x;
    if (i >= F*K) return;
    int f = i / K, k = i % K;
    float wv = w[i];
    u32 b0 = __float_as_uint(wv);
    float h = __uint_as_float(b0 & 0xFFFF0000u);     // truncate: exact bf16
    float r1 = wv - h;                                // exact in fp32
    u32 b1 = __float_as_uint(r1);
    float m = __uint_as_float(b1 & 0xFFFF0000u);
    float r2 = r1 - m;                                // exact, <=8 significand bits
    u32 b2 = __float_as_uint(r2);
    size_t o = ((size_t)(k>>3)*F + f)*8 + (k&7);
    hi[o]  = (short)(b0 >> 16);
    mid[o] = (short)(b1 >> 16);
    lo[o]  = (short)(b2 >> 16);
}

// ---------------- MFMA spike conv ----------------
// D[n][f] = S[n][k] * W^T[k][f], exact 3-split bf16. 4 waves: wave w owns n-rows [bx*64+w*16, +16).
// MODE 0: +bias, LIF, OR over n -> outm (tnet3)
// MODE 1: BNTT norm, LIF -> point-major u8 spikes outp[t][b][n][F] (conv3)
// MODE 2: BNTT norm, LIF, OR over n -> outm (conv4)
// MODE 3: BNTT norm, LIF, OR over wave's 16 rows (=k-neighbors) -> outp[t][b][n/16][F] (edge conv2)
// BITS: A rows are u64 bitmasks (K/64 words/row); else u8 rows (stride K).
template<int K, int F, int MODE, bool BITS>
__global__ __launch_bounds__(256) void k_mconv(
        const void* __restrict__ Asrc,
        const short* __restrict__ Whi, const short* __restrict__ Wmd, const short* __restrict__ Wlo,
        const float* __restrict__ st, const float* __restrict__ ga, const float* __restrict__ be,
        const float* __restrict__ bias,
        u8* __restrict__ outp, u32* __restrict__ outm, int NPTS) {
    __shared__ u32 morr[TT][64];
    int tid = threadIdx.x;
    int wave = tid >> 6, lane = tid & 63;
    int l15 = lane & 15, lg = lane >> 4;
    int b = blockIdx.z;
    int n_base = blockIdx.x*64 + wave*16;
    int f0 = blockIdx.y*64;
    if (MODE == 0 || MODE == 2) {
        for (int l = tid; l < TT*64; l += 256) morr[l>>6][l&63] = 0u;
        __syncthreads();
    }
    f4 acc[4][TT];
    #pragma unroll
    for (int i = 0; i < 4; ++i)
        #pragma unroll
        for (int t = 0; t < TT; ++t) acc[i][t] = (f4)0.f;

    const u64* Ab[TT];
    const u8*  Au[TT];
    #pragma unroll
    for (int t = 0; t < TT; ++t) {
        if (BITS) Ab[t] = (const u64*)Asrc + ((size_t)(t*BB+b)*NPTS + n_base + l15)*(K/64);
        else      Au[t] = (const u8*)Asrc  + ((size_t)(t*BB+b)*NPTS + n_base + l15)*K + lg*8;
    }
    for (int k0 = 0; k0 < K; k0 += 32) {
        short8 a[TT];
        #pragma unroll
        for (int t = 0; t < TT; ++t) {
            if (BITS) {
                int kk = k0 + lg*8;
                u64 word = Ab[t][kk >> 6];
                u32 byte = (u32)(word >> (kk & 63)) & 0xFFu;
                #pragma unroll
                for (int j = 0; j < 8; ++j) a[t][j] = (short)(((byte>>j)&1u) * 0x3F80u);
            } else {
                u64 w8 = *(const u64*)(Au[t] + k0);
                #pragma unroll
                for (int j = 0; j < 8; ++j) a[t][j] = (short)(((u32)(w8>>(8*j))&1u) * 0x3F80u);
            }
        }
        size_t wrow = ((size_t)((k0>>3) + lg)*F + f0 + l15)*8;
        #pragma unroll
        for (int fs = 0; fs < 4; ++fs) {
            size_t wo = wrow + (size_t)fs*128;
            short8 whi = *(const short8*)(Whi + wo);
            short8 wmd = *(const short8*)(Wmd + wo);
            short8 wlo = *(const short8*)(Wlo + wo);
            #pragma unroll
            for (int t = 0; t < TT; ++t) {
                acc[fs][t] = __builtin_amdgcn_mfma_f32_16x16x32_bf16(a[t], whi, acc[fs][t], 0, 0, 0);
                acc[fs][t] = __builtin_amdgcn_mfma_f32_16x16x32_bf16(a[t], wmd, acc[fs][t], 0, 0, 0);
                acc[fs][t] = __builtin_amdgcn_mfma_f32_16x16x32_bf16(a[t], wlo, acc[fs][t], 0, 0, 0);
            }
        }
    }
    // epilogue: D row = n_base + lg*4 + reg, col f = f0 + fs*16 + l15
    if (MODE == 1) {
        #pragma unroll
        for (int fs = 0; fs < 4; ++fs) {
            int f = f0 + fs*16 + l15;
            #pragma unroll
            for (int reg = 0; reg < 4; ++reg) {
                int n = n_base + lg*4 + reg;
                float v = 0.f;
                #pragma unroll
                for (int t = 0; t < TT; ++t) {
                    int ch = t*F + f;
                    float y = (acc[fs][t][reg] - st[(size_t)ch*2+0])*st[(size_t)ch*2+1]*ga[ch] + be[ch];
                    float s = lif_step(v, y);
                    outp[((size_t)(t*BB+b)*NPTS + n)*F + f] = (u8)(s != 0.f);
                }
            }
        }
    } else if (MODE == 3) {
        #pragma unroll
        for (int fs = 0; fs < 4; ++fs) {
            int f = f0 + fs*16 + l15;
            u32 nib = 0u;
            #pragma unroll
            for (int reg = 0; reg < 4; ++reg) {
                float v = 0.f;
                #pragma unroll
                for (int t = 0; t < TT; ++t) {
                    int ch = t*F + f;
                    float y = (acc[fs][t][reg] - st[(size_t)ch*2+0])*st[(size_t)ch*2+1]*ga[ch] + be[ch];
                    float s = lif_step(v, y);
                    if (s != 0.f) nib |= (1u << t);
                }
            }
            nib |= __shfl_xor(nib, 16, 64);
            nib |= __shfl_xor(nib, 32, 64);
            if (lg == 0) {
                int n_pt = n_base >> 4;
                #pragma unroll
                for (int t = 0; t < TT; ++t)
                    outp[((size_t)(t*BB+b)*(NPTS>>4) + n_pt)*F + f] = (u8)((nib>>t)&1u);
            }
        }
    } else {
        #pragma unroll
        for (int fs = 0; fs < 4; ++fs) {
            int f = f0 + fs*16 + l15;
            u32 any[TT] = {0,0,0,0};
            float bb = (MODE == 0) ? bias[f] : 0.f;
            #pragma unroll
            for (int reg = 0; reg < 4; ++reg) {
                float v = 0.f;
                #pragma unroll
                for (int t = 0; t < TT; ++t) {
                    float y;
                    if (MODE == 0) y = acc[fs][t][reg] + bb;
                    else {
                        int ch = t*F + f;
                        y = (acc[fs][t][reg] - st[(size_t)ch*2+0])*st[(size_t)ch*2+1]*ga[ch] + be[ch];
                    }
                    float s = lif_step(v, y);
                    if (s != 0.f) any[t] = 1u;
                }
            }
            #pragma unroll
            for (int t = 0; t < TT; ++t) if (any[t]) atomicOr(&morr[t][fs*16+l15], 1u);
        }
        __syncthreads();
        for (int l = tid; l < TT*64; l += 256)
            if (morr[l>>6][l&63]) atomicOr(&outm[((size_t)((l>>6)*BB+b))*F + f0 + (l&63)], 1u);
    }
}

// repack point-major u8 spikes [t][b][n][C] -> channel-major bits [t][b][C][32 words over n]
template<int C>
__global__ __launch_bounds__(256) void k_repack(const u8* __restrict__ sp, u64* __restrict__ bits) {
    __shared__ u8 tile[64][C+4];
    int tid = threadIdx.x;
    int nw = blockIdx.x, b = blockIdx.y, t = blockIdx.z;
    const u8* src = sp + ((size_t)(t*BB+b)*NN + nw*64)*C;
    for (int i = tid*4; i < 64*C; i += 1024) {
        u32 v = *(const u32*)(src + i);
        int r = i / C, c = i % C;
        *(u32*)&tile[r][c] = v;
    }
    __syncthreads();
    int wave = tid >> 6, lane = tid & 63;
    for (int c = wave; c < C; c += 4) {
        u64 m = __ballot(tile[lane][c] != 0);
        if (lane == 0) bits[((size_t)(t*BB+b)*C + c)*32 + nw] = m;
    }
}

__global__ __launch_bounds__(256) void k_out(const u32* __restrict__ mx4, float* __restrict__ out) {
    int i = blockIdx.x*256 + threadIdx.x;
    int b = i >> 10, g = i & 1023;
    float s = (float)(mx4[((size_t)0*BB+b)*1024+g] + mx4[((size_t)1*BB+b)*1024+g]
                    + mx4[((size_t)2*BB+b)*1024+g] + mx4[((size_t)3*BB+b)*1024+g]);
    out[i] = s * 0.25f;
}

extern "C" void kernel_launch(void* const* d_in, const int* in_sizes, int n_in,
                              void* d_out, int out_size, void* d_ws, size_t ws_size,
                              hipStream_t stream) {
    (void)in_sizes; (void)n_in; (void)out_size;
    const float* x    = (const float*)d_in[0];
    const float* tw1  = (const float*)d_in[1];
    const float* tb1  = (const float*)d_in[2];
    const float* tw2  = (const float*)d_in[3];
    const float* tb2  = (const float*)d_in[4];
    const float* tw3  = (const float*)d_in[5];
    const float* tb3  = (const float*)d_in[6];
    const float* tfw1 = (const float*)d_in[7];
    const float* tfb1 = (const float*)d_in[8];
    const float* tfw2 = (const float*)d_in[9];
    const float* tfb2 = (const float*)d_in[10];
    const float* tfw3 = (const float*)d_in[11];
    const float* tfb3 = (const float*)d_in[12];
    const float* w1   = (const float*)d_in[13];
    const float* w2   = (const float*)d_in[14];
    const float* w3   = (const float*)d_in[15];
    const float* w4   = (const float*)d_in[16];
    const float* g1   = (const float*)d_in[17];
    const float* be1  = (const float*)d_in[18];
    const float* g2   = (const float*)d_in[19];
    const float* be2  = (const float*)d_in[20];
    const float* g3   = (const float*)d_in[21];
    const float* be3  = (const float*)d_in[22];
    const float* g4   = (const float*)d_in[23];
    const float* be4  = (const float*)d_in[24];

    char* wsb = (char*)d_ws;
    size_t off = 0;
    auto alloc = [&](size_t bytes) -> void* {
        void* p = wsb + off;
        off = (off + bytes + 255) & ~(size_t)255;
        return p;
    };
    u64* s1b   = (u64*)alloc(sizeof(u64)*(size_t)TT*BB*NN);
    u64* s2b   = (u64*)alloc(sizeof(u64)*(size_t)TT*BB*NN*2);   // [t][b][n] 2 u64 (128 ch bits)
    u32* mx    = (u32*)alloc(sizeof(u32)*(size_t)TT*BB*1024);
    u32* mx4   = (u32*)alloc(sizeof(u32)*(size_t)TT*BB*1024);
    float* trs = (float*)alloc(sizeof(float)*BB*9);
    float* xa  = (float*)alloc(sizeof(float)*(size_t)BB*14*NN);
    float4* xa4 = (float4*)alloc(sizeof(float4)*(size_t)BB*NN);
    int* idx   = (int*)alloc(sizeof(int)*(size_t)BB*NN*KNB);
    float* gf  = (float*)alloc(sizeof(float)*(size_t)BB*28*PP);
    float* part1 = (float*)alloc(sizeof(float)*(size_t)1024*64*2);
    float* st1 = (float*)alloc(sizeof(float)*64*2);
    float* st2 = (float*)alloc(sizeof(float)*512*2);
    float* st3 = (float*)alloc(sizeof(float)*1024*2);
    float* st4 = (float*)alloc(sizeof(float)*4096*2);
    u64* h1b = (u64*)alloc(sizeof(u64)*(size_t)TT*BB*64*512);   // channel-major bits (Gram)
    u64* h1n = (u64*)alloc(sizeof(u64)*(size_t)TT*BB*PP);       // per-point 64ch mask (MFMA A)
    u8*  m2p = (u8*)alloc((size_t)TT*BB*NN*128);                // point-major spikes
    u8*  h3p = (u8*)alloc((size_t)TT*BB*NN*256);
    u64* m2b = (u64*)alloc(sizeof(u64)*(size_t)TT*BB*128*32);
    u64* h3b = (u64*)alloc(sizeof(u64)*(size_t)TT*BB*256*32);
    float* Mf64  = (float*)alloc(sizeof(float)*(size_t)TT*64*64);
    float* Mf128 = (float*)alloc(sizeof(float)*(size_t)TT*128*128);
    float* Mf256 = (float*)alloc(sizeof(float)*(size_t)TT*256*256);
    short* wp2h = (short*)alloc(sizeof(short)*(size_t)128*64);   // edge conv2 (F=128,K=64)
    short* wp2m = (short*)alloc(sizeof(short)*(size_t)128*64);
    short* wp2l = (short*)alloc(sizeof(short)*(size_t)128*64);
    short* wp3h = (short*)alloc(sizeof(short)*(size_t)256*128);  // conv3
    short* wp3m = (short*)alloc(sizeof(short)*(size_t)256*128);
    short* wp3l = (short*)alloc(sizeof(short)*(size_t)256*128);
    short* wp4h = (short*)alloc(sizeof(short)*(size_t)1024*256); // conv4
    short* wp4m = (short*)alloc(sizeof(short)*(size_t)1024*256);
    short* wp4l = (short*)alloc(sizeof(short)*(size_t)1024*256);
    short* wpth = (short*)alloc(sizeof(short)*(size_t)1024*128); // tnet conv3
    short* wptm = (short*)alloc(sizeof(short)*(size_t)1024*128);
    short* wptl = (short*)alloc(sizeof(short)*(size_t)1024*128);
    if (off > ws_size) return;

    hipMemsetAsync(mx, 0, sizeof(u32)*(size_t)TT*BB*1024, stream);
    hipMemsetAsync(mx4, 0, sizeof(u32)*(size_t)TT*BB*1024, stream);

    // weight prep (exact 3-way bf16 split)
    k_wprep<<<dim3((128*64+255)/256), dim3(256), 0, stream>>>(w2, wp2h, wp2m, wp2l, 128, 64);
    k_wprep<<<dim3((256*128+255)/256), dim3(256), 0, stream>>>(w3, wp3h, wp3m, wp3l, 256, 128);
    k_wprep<<<dim3((1024*256+255)/256), dim3(256), 0, stream>>>(w4, wp4h, wp4m, wp4l, 1024, 256);
    k_wprep<<<dim3((1024*128+255)/256), dim3(256), 0, stream>>>(tw3, wpth, wptm, wptl, 1024, 128);

    // T-Net
    k_tnet1<<<dim3(64), dim3(256), 0, stream>>>(x, tw1, tb1, s1b);
    k_tnet2<<<dim3(64, 4), dim3(256), 0, stream>>>(s1b, tw2, tb2, (u32*)s2b);
    k_mconv<128,1024,0,true><<<dim3(32,16,8), dim3(256), 0, stream>>>(
        s2b, wpth, wptm, wptl, nullptr, nullptr, nullptr, tb3, nullptr, mx, NN);
    k_fc<<<dim3(8), dim3(512), 0, stream>>>(mx, tfw1, tfb1, tfw2, tfb2, tfw3, tfb3, trs);
    k_trans<<<dim3(64), dim3(256), 0, stream>>>(x, trs, xa, xa4);
    // KNN (wave-per-query) + graph feature
    k_knn<<<dim3(NN/4, BB), dim3(256), 0, stream>>>(xa4, idx);
    k_gfeat<<<dim3((BB*NN*KNB)/256), dim3(256), 0, stream>>>(xa, idx, gf);
    // edge conv1 stats + apply
    k_estats1<<<dim3(128, 8), dim3(256), 0, stream>>>(gf, w1, part1);
    k_reduce<<<dim3(64), dim3(256), 0, stream>>>(part1, st1, 64, 1024, 262144.0);
    k_h1<<<dim3(128, 8), dim3(256), 0, stream>>>(gf, w1, st1, g1, be1, h1b, h1n);
    // edge conv2: stats via Gram, apply via MFMA (+ max over k)
    k_gram_h1<<<dim3(64, TT), dim3(256), 0, stream>>>(h1b, Mf64);
    k_proj<64><<<dim3(128, TT), dim3(64), 0, stream>>>(Mf64, w2, st2, 128, 262144.0);
    k_mconv<64,128,3,true><<<dim3(PP/64,2,8), dim3(256), 0, stream>>>(
        h1n, wp2h, wp2m, wp2l, st2, g2, be2, nullptr, m2p, nullptr, PP);
    k_repack<128><<<dim3(32,8,4), dim3(256), 0, stream>>>(m2p, m2b);
    // conv3
    k_gram<128><<<dim3(128, TT), dim3(256), 0, stream>>>(m2b, Mf128);
    k_proj<128><<<dim3(256, TT), dim3(128), 0, stream>>>(Mf128, w3, st3, 256, 16384.0);
    k_mconv<128,256,1,false><<<dim3(32,4,8), dim3(256), 0, stream>>>(
        m2p, wp3h, wp3m, wp3l, st3, g3, be3, nullptr, h3p, nullptr, NN);
    k_repack<256><<<dim3(32,8,4), dim3(256), 0, stream>>>(h3p, h3b);
    // conv4
    k_gram<256><<<dim3(256, TT), dim3(256), 0, stream>>>(h3b, Mf256);
    k_proj<256><<<dim3(1024, TT), dim3(256), 0, stream>>>(Mf256, w4, st4, 1024, 16384.0);
    k_mconv<256,1024,2,false><<<dim3(32,16,8), dim3(256), 0, stream>>>(
        h3p, wp4h, wp4m, wp4l, st4, g4, be4, nullptr, nullptr, mx4, NN);
    // output
    k_out<<<dim3(32), dim3(256), 0, stream>>>(mx4, (float*)d_out);
}

// Round 5
// 1054.576 us; speedup vs baseline: 4.1510x; 1.0271x over previous
//
#include <hip/hip_runtime.h>
#include <stdint.h>

#define TT 4
#define BB 8
#define NN 2048
#define KNB 16
#define PP (NN*KNB)
#define VTH 1.0f
#define EPSB 1e-5f

typedef unsigned long long u64;
typedef unsigned int u32;
typedef unsigned short u16;
typedef unsigned char u8;
typedef __attribute__((ext_vector_type(8))) short short8;
typedef __attribute__((ext_vector_type(4))) float f4;

#define GLOAD_LDS16(g, l) __builtin_amdgcn_global_load_lds( \
    (const __attribute__((address_space(1))) u32*)(g), \
    (__attribute__((address_space(3))) u32*)(l), 16, 0, 0)

__device__ __forceinline__ float lif_step(float& v, float x) {
    v = v + (x - v) / 2.0f;
    float s = (v - VTH >= 0.0f) ? 1.0f : 0.0f;
    v = v * (1.0f - s);
    return s;
}

// ---------------- T-Net ----------------
__global__ __launch_bounds__(256) void k_tnet1(const float* __restrict__ x, const float* __restrict__ w,
        const float* __restrict__ bi, u64* __restrict__ s1b) {
    int i = blockIdx.x*256 + threadIdx.x;
    int b = i >> 11, n = i & 2047;
    float p0 = x[((size_t)b*14+0)*NN+n];
    float p1 = x[((size_t)b*14+1)*NN+n];
    float p2 = x[((size_t)b*14+2)*NN+n];
    u64 m[TT] = {0,0,0,0};
    for (int d = 0; d < 64; ++d) {
        float z = ((w[d*3+0]*p0 + w[d*3+1]*p1) + w[d*3+2]*p2) + bi[d];
        float v = 0.f;
        #pragma unroll
        for (int t = 0; t < TT; ++t) {
            float s = lif_step(v, z);
            if (s != 0.f) m[t] |= (1ull << d);
        }
    }
    #pragma unroll
    for (int t = 0; t < TT; ++t) s1b[((size_t)t*BB + b)*NN + n] = m[t];
}

// conv2: 64->128, split over 4 channel-chunks of 32 for occupancy
__global__ __launch_bounds__(256) void k_tnet2(const u64* __restrict__ s1b, const float* __restrict__ w,
        const float* __restrict__ bi, u32* __restrict__ s2b32) {
    __shared__ float ws[32*64];
    int tid = threadIdx.x;
    int ec = blockIdx.y;
    for (int l = tid; l < 32*64; l += 256) ws[l] = w[ec*32*64 + l];
    __syncthreads();
    int i = blockIdx.x*256 + tid;
    int b = i >> 11, n = i & 2047;
    u64 m[TT];
    #pragma unroll
    for (int t = 0; t < TT; ++t) m[t] = s1b[((size_t)t*BB+b)*NN+n];
    u32 o[TT] = {0,0,0,0};
    for (int el = 0; el < 32; ++el) {
        float z[TT] = {0.f,0.f,0.f,0.f};
        #pragma unroll 8
        for (int d = 0; d < 64; ++d) {
            float wv = ws[el*64+d];
            #pragma unroll
            for (int t = 0; t < TT; ++t) z[t] += ((m[t]>>d)&1ull) ? wv : 0.f;
        }
        float v = 0.f, bb = bi[ec*32 + el];
        #pragma unroll
        for (int t = 0; t < TT; ++t) {
            float s = lif_step(v, z[t] + bb);
            if (s != 0.f) o[t] |= (1u << el);
        }
    }
    #pragma unroll
    for (int t = 0; t < TT; ++t)
        s2b32[(((size_t)t*BB+b)*NN+n)*4 + ec] = o[t];
}

// FC head: 1024->512->256->9
__global__ __launch_bounds__(512) void k_fc(const u32* __restrict__ mx, const float* __restrict__ fw1, const float* __restrict__ fb1,
        const float* __restrict__ fw2, const float* __restrict__ fb2, const float* __restrict__ fw3, const float* __restrict__ fb3,
        float* __restrict__ trans) {
    __shared__ float h0[TT][1024];
    __shared__ float h1[TT][512];
    __shared__ float h2[TT][256];
    __shared__ float h3s[TT][9];
    int b = blockIdx.x, tid = threadIdx.x;
    for (int l = tid; l < TT*1024; l += 512) h0[l>>10][l&1023] = (float)mx[((size_t)(l>>10)*BB + b)*1024 + (l&1023)];
    __syncthreads();
    {
        float z[TT] = {0.f,0.f,0.f,0.f};
        #pragma unroll 4
        for (int f = 0; f < 1024; ++f) {
            float wv = fw1[(size_t)tid*1024 + f];
            #pragma unroll
            for (int t = 0; t < TT; ++t) z[t] += wv * h0[t][f];
        }
        float v = 0.f;
        #pragma unroll
        for (int t = 0; t < TT; ++t) h1[t][tid] = lif_step(v, z[t] + fb1[tid]);
    }
    __syncthreads();
    if (tid < 256) {
        float z[TT] = {0.f,0.f,0.f,0.f};
        #pragma unroll 4
        for (int f = 0; f < 512; ++f) {
            float wv = fw2[(size_t)tid*512 + f];
            #pragma unroll
            for (int t = 0; t < TT; ++t) z[t] += wv * h1[t][f];
        }
        float v = 0.f;
        #pragma unroll
        for (int t = 0; t < TT; ++t) h2[t][tid] = lif_step(v, z[t] + fb2[tid]);
    }
    __syncthreads();
    if (tid < TT*9) {
        int t = tid/9, oo = tid%9;
        float z = 0.f;
        for (int f = 0; f < 256; ++f) z += fw3[oo*256+f]*h2[t][f];
        h3s[t][oo] = z + fb3[oo];
    }
    __syncthreads();
    if (tid < 9) {
        float m = ((h3s[0][tid]+h3s[1][tid]) + (h3s[2][tid]+h3s[3][tid])) * 0.25f;
        int c = tid/3, dd = tid%3;
        trans[b*9+tid] = m + ((c==dd)?1.0f:0.0f);
    }
}

// apply transform; also emit packed float4 (x,y,z,sq) for KNN
__global__ __launch_bounds__(256) void k_trans(const float* __restrict__ x, const float* __restrict__ tr,
        float* __restrict__ xa, float4* __restrict__ xa4) {
    int i = blockIdx.x*256 + threadIdx.x;
    int b = i >> 11, n = i & 2047;
    float p0 = x[((size_t)b*14+0)*NN+n];
    float p1 = x[((size_t)b*14+1)*NN+n];
    float p2 = x[((size_t)b*14+2)*NN+n];
    const float* tb = tr + b*9;
    float a0 = (p0*tb[0] + p1*tb[3]) + p2*tb[6];
    float a1 = (p0*tb[1] + p1*tb[4]) + p2*tb[7];
    float a2 = (p0*tb[2] + p1*tb[5]) + p2*tb[8];
    xa[((size_t)b*14+0)*NN+n] = a0;
    xa[((size_t)b*14+1)*NN+n] = a1;
    xa[((size_t)b*14+2)*NN+n] = a2;
    for (int c = 3; c < 14; ++c) xa[((size_t)b*14+c)*NN+n] = x[((size_t)b*14+c)*NN+n];
    float4 p;
    p.x = a0; p.y = a1; p.z = a2;
    p.w = (a0*a0 + a1*a1) + a2*a2;
    xa4[(size_t)b*NN+n] = p;
}

// KNN: one wave per query point; 32 candidate distances per lane in registers.
__global__ __launch_bounds__(256) void k_knn(const float4* __restrict__ xa4, int* __restrict__ idx) {
    int wave = threadIdx.x >> 6, lane = threadIdx.x & 63;
    int b = blockIdx.y;
    int n = blockIdx.x*4 + wave;
    const float4* P = xa4 + (size_t)b*NN;
    float4 q = P[n];
    float sn = q.w;
    float vals[32];
    #pragma unroll
    for (int j = 0; j < 32; ++j) {
        float4 p = P[j*64 + lane];
        float inner = (q.x*p.x + q.y*p.y) + q.z*p.z;
        vals[j] = (2.0f*inner - sn) - p.w;
    }
    for (int k = 0; k < KNB; ++k) {
        float bv = -3.4e38f; int bj = 0;
        #pragma unroll
        for (int j = 0; j < 32; ++j) if (vals[j] > bv) { bv = vals[j]; bj = j; }
        int bm = bj*64 + lane;
        u32 fb = __float_as_uint(bv);
        fb = (fb & 0x80000000u) ? ~fb : (fb | 0x80000000u);
        u64 key = ((u64)fb << 32) | (u32)(~bm);
        #pragma unroll
        for (int o2 = 1; o2 < 64; o2 <<= 1) {
            u64 other = __shfl_xor(key, o2, 64);
            key = (other > key) ? other : key;
        }
        int wm = (int)(~(u32)key);
        if (lane == 0) idx[((size_t)b*NN + n)*KNB + k] = wm;
        int wl = wm & 63, wj = wm >> 6;
        if (lane == wl) {
            #pragma unroll
            for (int j = 0; j < 32; ++j) if (j == wj) vals[j] = -3.4e38f;
        }
    }
}

__global__ __launch_bounds__(256) void k_gfeat(const float* __restrict__ xa, const int* __restrict__ idx, float* __restrict__ gf) {
    int i = blockIdx.x*256 + threadIdx.x;
    int b = i >> 15;
    int r = i & 32767;
    int n = r >> 4;
    int mm = idx[((size_t)b*NN+n)*KNB + (r & 15)];
    size_t pbase = (size_t)b*28*PP + r;
    #pragma unroll
    for (int c = 0; c < 14; ++c) {
        float ctr = xa[((size_t)b*14+c)*NN + n];
        float nb  = xa[((size_t)b*14+c)*NN + mm];
        gf[pbase + (size_t)c*PP] = ctr;
        gf[pbase + (size_t)(14+c)*PP] = nb - ctr;
    }
}

// edge conv1 stats partials
__global__ __launch_bounds__(256) void k_estats1(const float* __restrict__ gf, const float* __restrict__ w1, float* __restrict__ part1) {
    __shared__ float gfs[28][256];
    __shared__ float w1s[64*28];
    __shared__ float wsum[4][64], wsq[4][64];
    int pt = blockIdx.x, b = blockIdx.y;
    int p0 = pt*256, tid = threadIdx.x;
    for (int l = tid; l < 28*256; l += 256) gfs[l>>8][l&255] = gf[((size_t)b*28 + (l>>8))*PP + p0 + (l&255)];
    for (int l = tid; l < 64*28; l += 256) w1s[l] = w1[l];
    __syncthreads();
    int wv = tid>>6, lane = tid&63;
    for (int d = 0; d < 64; ++d) {
        float z = 0.f;
        #pragma unroll
        for (int c = 0; c < 28; ++c) z += w1s[d*28+c]*gfs[c][tid];
        float s = z, q = z*z;
        #pragma unroll
        for (int o = 1; o < 64; o <<= 1) { s += __shfl_xor(s, o, 64); q += __shfl_xor(q, o, 64); }
        if (lane == 0) { wsum[wv][d] = s; wsq[wv][d] = q; }
    }
    __syncthreads();
    if (tid < 64) {
        float s = (wsum[0][tid]+wsum[1][tid])+(wsum[2][tid]+wsum[3][tid]);
        float q = (wsq[0][tid]+wsq[1][tid])+(wsq[2][tid]+wsq[3][tid]);
        size_t blk = (size_t)b*128 + pt;
        part1[(blk*64 + tid)*2+0] = s;
        part1[(blk*64 + tid)*2+1] = q;
    }
}

__global__ __launch_bounds__(256) void k_reduce(const float* __restrict__ part, float* __restrict__ stats, int nch, int nblk, double M) {
    __shared__ double sred[256], qred[256];
    int ch = blockIdx.x, tid = threadIdx.x;
    double s = 0.0, q = 0.0;
    for (int i = tid; i < nblk; i += 256) {
        s += (double)part[((size_t)i*nch + ch)*2 + 0];
        q += (double)part[((size_t)i*nch + ch)*2 + 1];
    }
    sred[tid] = s; qred[tid] = q;
    __syncthreads();
    for (int off = 128; off > 0; off >>= 1) {
        if (tid < off) { sred[tid] += sred[tid+off]; qred[tid] += qred[tid+off]; }
        __syncthreads();
    }
    if (tid == 0) {
        double mu = sred[0] / M;
        double var = qred[0] / M - mu*mu;
        if (var < 0.0) var = 0.0;
        stats[ch*2+0] = (float)mu;
        stats[ch*2+1] = 1.0f / sqrtf((float)var + EPSB);
    }
}

// edge conv1 apply: norm+LIF -> h1b (channel-major bits) + h1n (u64 mask per point)
__global__ __launch_bounds__(256) void k_h1(const float* __restrict__ gf, const float* __restrict__ w1,
        const float* __restrict__ st1, const float* __restrict__ g1, const float* __restrict__ be1,
        u64* __restrict__ h1b, u64* __restrict__ h1n) {
    __shared__ float w1s[64*28];
    int tid = threadIdx.x;
    int b = blockIdx.y;
    int p0 = blockIdx.x*256;
    int p = p0 + tid;
    for (int l = tid; l < 64*28; l += 256) w1s[l] = w1[l];
    __syncthreads();
    float gr[28];
    #pragma unroll
    for (int c = 0; c < 28; ++c) gr[c] = gf[((size_t)b*28 + c)*PP + p];
    int wordbase = (p0>>6) + (tid>>6);
    u64 pm[TT] = {0,0,0,0};
    for (int d = 0; d < 64; ++d) {
        float z = 0.f;
        #pragma unroll
        for (int c = 0; c < 28; ++c) z += w1s[d*28+c]*gr[c];
        float mu = st1[d*2+0], iv = st1[d*2+1];
        float v = 0.f;
        #pragma unroll
        for (int t = 0; t < TT; ++t) {
            float y = (z - mu) * iv * g1[t*64+d] + be1[t*64+d];
            float s = lif_step(v, y);
            u64 m = __ballot(s != 0.f);
            if ((tid & 63) == 0) h1b[((size_t)(t*BB+b)*64 + d)*512 + wordbase] = m;
            pm[t] |= ((u64)(s != 0.f)) << d;
        }
    }
    #pragma unroll
    for (int t = 0; t < TT; ++t) h1n[(size_t)(t*BB+b)*PP + p] = pm[t];
}

// Gram of h1 bits
__global__ __launch_bounds__(256) void k_gram_h1(const u64* __restrict__ h1b, float* __restrict__ Mf) {
    __shared__ u64 row[4096];
    __shared__ int red[64][4];
    int c = blockIdx.x, t = blockIdx.y, tid = threadIdx.x;
    for (int l = tid; l < 4096; l += 256) {
        int b = l >> 9, w = l & 511;
        row[l] = h1b[((size_t)(t*BB+b)*64 + c)*512 + w];
    }
    __syncthreads();
    int cp = tid >> 2, part = tid & 3;
    int acc = 0;
    for (int j = 0; j < 1024; ++j) {
        int i = part*1024 + j;
        int b = i >> 9, w = i & 511;
        acc += __popcll(row[i] & h1b[((size_t)(t*BB+b)*64 + cp)*512 + w]);
    }
    red[cp][part] = acc;
    __syncthreads();
    if (part == 0)
        Mf[((size_t)t*64 + c)*64 + cp] = (float)(red[cp][0]+red[cp][1]+red[cp][2]+red[cp][3]);
}

// Gram for bit-packed [tb][C][32] spikes
template<int C>
__global__ __launch_bounds__(256) void k_gram(const u64* __restrict__ bits, float* __restrict__ Mf) {
    __shared__ u64 row[256];
    int c = blockIdx.x, t = blockIdx.y, tid = threadIdx.x;
    row[tid] = bits[((size_t)(t*BB+(tid>>5))*C + c)*32 + (tid&31)];
    __syncthreads();
    if (tid < C) {
        int acc = 0;
        for (int i = 0; i < 256; ++i)
            acc += __popcll(row[i] & bits[((size_t)(t*BB+(i>>5))*C + tid)*32 + (i&31)]);
        Mf[((size_t)t*C + c)*C + tid] = (float)acc;
    }
}

// project Gram through weights -> per-(t,ch) (mean, inv_std)
template<int CIN>
__global__ void k_proj(const float* __restrict__ Mf, const float* __restrict__ w,
        float* __restrict__ st, int COUT, double cnt) {
    __shared__ double z2s[256], mns[256];
    int ch = blockIdx.x, t = blockIdx.y, c2 = threadIdx.x;
    const float* Mt = Mf + (size_t)t*CIN*CIN;
    double y = 0.0;
    for (int c = 0; c < CIN; ++c)
        y += (double)w[(size_t)ch*CIN+c] * (double)Mt[(size_t)c*CIN + c2];
    double wc2 = (double)w[(size_t)ch*CIN+c2];
    z2s[c2] = wc2 * y;
    mns[c2] = wc2 * (double)Mt[(size_t)c2*CIN + c2];
    __syncthreads();
    for (int off = CIN>>1; off > 0; off >>= 1) {
        if (c2 < off) { z2s[c2] += z2s[c2+off]; mns[c2] += mns[c2+off]; }
        __syncthreads();
    }
    if (c2 == 0) {
        double mu = mns[0] / cnt;
        double var = z2s[0] / cnt - mu*mu;
        if (var < 0.0) var = 0.0;
        st[((size_t)t*COUT+ch)*2+0] = (float)mu;
        st[((size_t)t*COUT+ch)*2+1] = 1.0f / sqrtf((float)var + EPSB);
    }
}

// weight prep: fp32 w[F][K] -> exact 3-way bf16 split in MFMA-frag layout [K/8][F][8]
__global__ __launch_bounds__(256) void k_wprep(const float* __restrict__ w,
        short* __restrict__ hi, short* __restrict__ mid, short* __restrict__ lo, int F, int K) {
    int i = blockIdx.x*256 + threadIdx.x;
    if (i >= F*K) return;
    int f = i / K, k = i % K;
    float wv = w[i];
    u32 b0 = __float_as_uint(wv);
    float h = __uint_as_float(b0 & 0xFFFF0000u);
    float r1 = wv - h;
    u32 b1 = __float_as_uint(r1);
    float m = __uint_as_float(b1 & 0xFFFF0000u);
    float r2 = r1 - m;
    u32 b2 = __float_as_uint(r2);
    size_t o = ((size_t)(k>>3)*F + f)*8 + (k&7);
    hi[o]  = (short)(b0 >> 16);
    mid[o] = (short)(b1 >> 16);
    lo[o]  = (short)(b2 >> 16);
}

// ---------------- MFMA spike conv (LDS-staged weights) ----------------
// D[n][f] = S[n][k] * W^T[k][f], exact 3-split bf16.
// Weights staged to LDS per block (k-tile of KT=min(K,128) = 48KB max), shared by 4 waves.
// MODE 0: +bias, LIF, OR over n -> outm (tnet3)
// MODE 1: BNTT norm, LIF -> bf16 u16 spikes outp[t][b][n][F] (conv3)
// MODE 2: BNTT norm, LIF, OR over n -> outm (conv4)
// MODE 3: BNTT norm, LIF, OR over wave's 16 rows -> bf16 u16 outp[t][b][n/16][F] (edge conv2)
// BITS: A rows are u64 bitmasks; else u16 bf16 rows (stride K, 16B loads, no expansion).
template<int K, int F, int MODE, bool BITS>
__global__ __launch_bounds__(256) void k_mconv(
        const void* __restrict__ Asrc,
        const short* __restrict__ Whi, const short* __restrict__ Wmd, const short* __restrict__ Wlo,
        const float* __restrict__ st, const float* __restrict__ ga, const float* __restrict__ be,
        const float* __restrict__ bias,
        u16* __restrict__ outp, u32* __restrict__ outm, int NPTS) {
    constexpr int KT = (K < 128) ? K : 128;
    constexpr int ROWS = (KT/8)*3;          // 1024B rows: [kq][split][64f][8]
    __shared__ short wsm[(KT/8)*3*512];
    __shared__ u32 morr[TT][64];
    int tid = threadIdx.x;
    int wave = tid >> 6, lane = tid & 63;
    int l15 = lane & 15, lg = lane >> 4;
    int b = blockIdx.z;
    int n_base = blockIdx.x*64 + wave*16;
    int f0 = blockIdx.y*64;
    if (MODE == 0 || MODE == 2)
        for (int l = tid; l < TT*64; l += 256) morr[l>>6][l&63] = 0u;

    f4 acc[4][TT];
    #pragma unroll
    for (int i = 0; i < 4; ++i)
        #pragma unroll
        for (int t = 0; t < TT; ++t) acc[i][t] = (f4)0.f;

    const u64* Ab[TT];
    const u16* Au[TT];
    #pragma unroll
    for (int t = 0; t < TT; ++t) {
        if (BITS) Ab[t] = (const u64*)Asrc + ((size_t)(t*BB+b)*NPTS + n_base + l15)*(K/64);
        else      Au[t] = (const u16*)Asrc + ((size_t)(t*BB+b)*NPTS + n_base + l15)*K + lg*8;
    }
    const short* Wsrc[3] = {Whi, Wmd, Wlo};

    for (int kt = 0; kt < K; kt += KT) {
        if (kt > 0) __syncthreads();
        // stage weight k-tile: each wave covers rows wave, wave+4, ...
        for (int r = wave; r < ROWS; r += 4) {
            int kq = r/3, s = r - kq*3;
            const short* g = Wsrc[s] + ((size_t)((kt>>3) + kq)*F + f0)*8 + lane*8;
            GLOAD_LDS16(g, &wsm[r*512]);
        }
        __syncthreads();
        for (int k0 = 0; k0 < KT; k0 += 32) {
            int kg = kt + k0;
            short8 a[TT];
            #pragma unroll
            for (int t = 0; t < TT; ++t) {
                if (BITS) {
                    int kk = kg + lg*8;
                    u64 word = Ab[t][kk >> 6];
                    u32 byte = (u32)(word >> (kk & 63)) & 0xFFu;
                    #pragma unroll
                    for (int j = 0; j < 8; ++j) a[t][j] = (short)(((byte>>j)&1u) * 0x3F80u);
                } else {
                    a[t] = *(const short8*)(Au[t] + kg);
                }
            }
            int kql = (k0>>3) + lg;
            #pragma unroll
            for (int fs = 0; fs < 4; ++fs) {
                const short* base = wsm + kql*1536 + (fs*16+l15)*8;
                short8 whi = *(const short8*)(base);
                short8 wmd = *(const short8*)(base + 512);
                short8 wlo = *(const short8*)(base + 1024);
                #pragma unroll
                for (int t = 0; t < TT; ++t) {
                    acc[fs][t] = __builtin_amdgcn_mfma_f32_16x16x32_bf16(a[t], whi, acc[fs][t], 0, 0, 0);
                    acc[fs][t] = __builtin_amdgcn_mfma_f32_16x16x32_bf16(a[t], wmd, acc[fs][t], 0, 0, 0);
                    acc[fs][t] = __builtin_amdgcn_mfma_f32_16x16x32_bf16(a[t], wlo, acc[fs][t], 0, 0, 0);
                }
            }
        }
    }
    // epilogue: D row = n_base + lg*4 + reg, col f = f0 + fs*16 + l15
    if (MODE == 1) {
        #pragma unroll
        for (int fs = 0; fs < 4; ++fs) {
            int f = f0 + fs*16 + l15;
            #pragma unroll
            for (int reg = 0; reg < 4; ++reg) {
                int n = n_base + lg*4 + reg;
                float v = 0.f;
                #pragma unroll
                for (int t = 0; t < TT; ++t) {
                    int ch = t*F + f;
                    float y = (acc[fs][t][reg] - st[(size_t)ch*2+0])*st[(size_t)ch*2+1]*ga[ch] + be[ch];
                    float s = lif_step(v, y);
                    outp[((size_t)(t*BB+b)*NPTS + n)*F + f] = (s != 0.f) ? (u16)0x3F80 : (u16)0;
                }
            }
        }
    } else if (MODE == 3) {
        #pragma unroll
        for (int fs = 0; fs < 4; ++fs) {
            int f = f0 + fs*16 + l15;
            u32 nib = 0u;
            #pragma unroll
            for (int reg = 0; reg < 4; ++reg) {
                float v = 0.f;
                #pragma unroll
                for (int t = 0; t < TT; ++t) {
                    int ch = t*F + f;
                    float y = (acc[fs][t][reg] - st[(size_t)ch*2+0])*st[(size_t)ch*2+1]*ga[ch] + be[ch];
                    float s = lif_step(v, y);
                    if (s != 0.f) nib |= (1u << t);
                }
            }
            nib |= __shfl_xor(nib, 16, 64);
            nib |= __shfl_xor(nib, 32, 64);
            if (lg == 0) {
                int n_pt = n_base >> 4;
                #pragma unroll
                for (int t = 0; t < TT; ++t)
                    outp[((size_t)(t*BB+b)*(NPTS>>4) + n_pt)*F + f] = ((nib>>t)&1u) ? (u16)0x3F80 : (u16)0;
            }
        }
    } else {
        #pragma unroll
        for (int fs = 0; fs < 4; ++fs) {
            int f = f0 + fs*16 + l15;
            u32 any[TT] = {0,0,0,0};
            float bb = (MODE == 0) ? bias[f] : 0.f;
            #pragma unroll
            for (int reg = 0; reg < 4; ++reg) {
                float v = 0.f;
                #pragma unroll
                for (int t = 0; t < TT; ++t) {
                    float y;
                    if (MODE == 0) y = acc[fs][t][reg] + bb;
                    else {
                        int ch = t*F + f;
                        y = (acc[fs][t][reg] - st[(size_t)ch*2+0])*st[(size_t)ch*2+1]*ga[ch] + be[ch];
                    }
                    float s = lif_step(v, y);
                    if (s != 0.f) any[t] = 1u;
                }
            }
            #pragma unroll
            for (int t = 0; t < TT; ++t) if (any[t]) atomicOr(&morr[t][fs*16+l15], 1u);
        }
        __syncthreads();
        for (int l = tid; l < TT*64; l += 256)
            if (morr[l>>6][l&63]) atomicOr(&outm[((size_t)((l>>6)*BB+b))*F + f0 + (l&63)], 1u);
    }
}

// repack point-major bf16-u16 spikes [t][b][n][C] -> channel-major bits [t][b][C][32 words over n]
template<int C>
__global__ __launch_bounds__(256) void k_repack(const u16* __restrict__ sp, u64* __restrict__ bits) {
    __shared__ u16 tile[64][C+2];   // +2 pad -> lane stride (C+2)*2B, conflict-free ballot reads
    int tid = threadIdx.x;
    int nw = blockIdx.x, b = blockIdx.y, t = blockIdx.z;
    const u16* src = sp + ((size_t)(t*BB+b)*NN + nw*64)*C;
    for (int i = tid*2; i < 64*C; i += 512) {
        u32 v = *(const u32*)(src + i);
        int r = i / C, c = i % C;
        *(u32*)&tile[r][c] = v;
    }
    __syncthreads();
    int wave = tid >> 6, lane = tid & 63;
    for (int c = wave; c < C; c += 4) {
        u64 m = __ballot(tile[lane][c] != 0);
        if (lane == 0) bits[((size_t)(t*BB+b)*C + c)*32 + nw] = m;
    }
}

__global__ __launch_bounds__(256) void k_out(const u32* __restrict__ mx4, float* __restrict__ out) {
    int i = blockIdx.x*256 + threadIdx.x;
    int b = i >> 10, g = i & 1023;
    float s = (float)(mx4[((size_t)0*BB+b)*1024+g] + mx4[((size_t)1*BB+b)*1024+g]
                    + mx4[((size_t)2*BB+b)*1024+g] + mx4[((size_t)3*BB+b)*1024+g]);
    out[i] = s * 0.25f;
}

extern "C" void kernel_launch(void* const* d_in, const int* in_sizes, int n_in,
                              void* d_out, int out_size, void* d_ws, size_t ws_size,
                              hipStream_t stream) {
    (void)in_sizes; (void)n_in; (void)out_size;
    const float* x    = (const float*)d_in[0];
    const float* tw1  = (const float*)d_in[1];
    const float* tb1  = (const float*)d_in[2];
    const float* tw2  = (const float*)d_in[3];
    const float* tb2  = (const float*)d_in[4];
    const float* tw3  = (const float*)d_in[5];
    const float* tb3  = (const float*)d_in[6];
    const float* tfw1 = (const float*)d_in[7];
    const float* tfb1 = (const float*)d_in[8];
    const float* tfw2 = (const float*)d_in[9];
    const float* tfb2 = (const float*)d_in[10];
    const float* tfw3 = (const float*)d_in[11];
    const float* tfb3 = (const float*)d_in[12];
    const float* w1   = (const float*)d_in[13];
    const float* w2   = (const float*)d_in[14];
    const float* w3   = (const float*)d_in[15];
    const float* w4   = (const float*)d_in[16];
    const float* g1   = (const float*)d_in[17];
    const float* be1  = (const float*)d_in[18];
    const float* g2   = (const float*)d_in[19];
    const float* be2  = (const float*)d_in[20];
    const float* g3   = (const float*)d_in[21];
    const float* be3  = (const float*)d_in[22];
    const float* g4   = (const float*)d_in[23];
    const float* be4  = (const float*)d_in[24];

    char* wsb = (char*)d_ws;
    size_t off = 0;
    auto alloc = [&](size_t bytes) -> void* {
        void* p = wsb + off;
        off = (off + bytes + 255) & ~(size_t)255;
        return p;
    };
    u64* s1b   = (u64*)alloc(sizeof(u64)*(size_t)TT*BB*NN);
    u64* s2b   = (u64*)alloc(sizeof(u64)*(size_t)TT*BB*NN*2);
    u32* mx    = (u32*)alloc(sizeof(u32)*(size_t)TT*BB*1024);
    u32* mx4   = (u32*)alloc(sizeof(u32)*(size_t)TT*BB*1024);
    float* trs = (float*)alloc(sizeof(float)*BB*9);
    float* xa  = (float*)alloc(sizeof(float)*(size_t)BB*14*NN);
    float4* xa4 = (float4*)alloc(sizeof(float4)*(size_t)BB*NN);
    int* idx   = (int*)alloc(sizeof(int)*(size_t)BB*NN*KNB);
    float* gf  = (float*)alloc(sizeof(float)*(size_t)BB*28*PP);
    float* part1 = (float*)alloc(sizeof(float)*(size_t)1024*64*2);
    float* st1 = (float*)alloc(sizeof(float)*64*2);
    float* st2 = (float*)alloc(sizeof(float)*512*2);
    float* st3 = (float*)alloc(sizeof(float)*1024*2);
    float* st4 = (float*)alloc(sizeof(float)*4096*2);
    u64* h1b = (u64*)alloc(sizeof(u64)*(size_t)TT*BB*64*512);
    u64* h1n = (u64*)alloc(sizeof(u64)*(size_t)TT*BB*PP);
    u16* m2p = (u16*)alloc(sizeof(u16)*(size_t)TT*BB*NN*128);   // bf16 spikes
    u16* h3p = (u16*)alloc(sizeof(u16)*(size_t)TT*BB*NN*256);
    u64* m2b = (u64*)alloc(sizeof(u64)*(size_t)TT*BB*128*32);
    u64* h3b = (u64*)alloc(sizeof(u64)*(size_t)TT*BB*256*32);
    float* Mf64  = (float*)alloc(sizeof(float)*(size_t)TT*64*64);
    float* Mf128 = (float*)alloc(sizeof(float)*(size_t)TT*128*128);
    float* Mf256 = (float*)alloc(sizeof(float)*(size_t)TT*256*256);
    short* wp2h = (short*)alloc(sizeof(short)*(size_t)128*64);
    short* wp2m = (short*)alloc(sizeof(short)*(size_t)128*64);
    short* wp2l = (short*)alloc(sizeof(short)*(size_t)128*64);
    short* wp3h = (short*)alloc(sizeof(short)*(size_t)256*128);
    short* wp3m = (short*)alloc(sizeof(short)*(size_t)256*128);
    short* wp3l = (short*)alloc(sizeof(short)*(size_t)256*128);
    short* wp4h = (short*)alloc(sizeof(short)*(size_t)1024*256);
    short* wp4m = (short*)alloc(sizeof(short)*(size_t)1024*256);
    short* wp4l = (short*)alloc(sizeof(short)*(size_t)1024*256);
    short* wpth = (short*)alloc(sizeof(short)*(size_t)1024*128);
    short* wptm = (short*)alloc(sizeof(short)*(size_t)1024*128);
    short* wptl = (short*)alloc(sizeof(short)*(size_t)1024*128);
    if (off > ws_size) return;

    hipMemsetAsync(mx, 0, sizeof(u32)*(size_t)TT*BB*1024, stream);
    hipMemsetAsync(mx4, 0, sizeof(u32)*(size_t)TT*BB*1024, stream);

    // weight prep (exact 3-way bf16 split)
    k_wprep<<<dim3((128*64+255)/256), dim3(256), 0, stream>>>(w2, wp2h, wp2m, wp2l, 128, 64);
    k_wprep<<<dim3((256*128+255)/256), dim3(256), 0, stream>>>(w3, wp3h, wp3m, wp3l, 256, 128);
    k_wprep<<<dim3((1024*256+255)/256), dim3(256), 0, stream>>>(w4, wp4h, wp4m, wp4l, 1024, 256);
    k_wprep<<<dim3((1024*128+255)/256), dim3(256), 0, stream>>>(tw3, wpth, wptm, wptl, 1024, 128);

    // T-Net
    k_tnet1<<<dim3(64), dim3(256), 0, stream>>>(x, tw1, tb1, s1b);
    k_tnet2<<<dim3(64, 4), dim3(256), 0, stream>>>(s1b, tw2, tb2, (u32*)s2b);
    k_mconv<128,1024,0,true><<<dim3(32,16,8), dim3(256), 0, stream>>>(
        s2b, wpth, wptm, wptl, nullptr, nullptr, nullptr, tb3, nullptr, mx, NN);
    k_fc<<<dim3(8), dim3(512), 0, stream>>>(mx, tfw1, tfb1, tfw2, tfb2, tfw3, tfb3, trs);
    k_trans<<<dim3(64), dim3(256), 0, stream>>>(x, trs, xa, xa4);
    // KNN (wave-per-query) + graph feature
    k_knn<<<dim3(NN/4, BB), dim3(256), 0, stream>>>(xa4, idx);
    k_gfeat<<<dim3((BB*NN*KNB)/256), dim3(256), 0, stream>>>(xa, idx, gf);
    // edge conv1 stats + apply
    k_estats1<<<dim3(128, 8), dim3(256), 0, stream>>>(gf, w1, part1);
    k_reduce<<<dim3(64), dim3(256), 0, stream>>>(part1, st1, 64, 1024, 262144.0);
    k_h1<<<dim3(128, 8), dim3(256), 0, stream>>>(gf, w1, st1, g1, be1, h1b, h1n);
    // edge conv2: stats via Gram, apply via MFMA (+ max over k)
    k_gram_h1<<<dim3(64, TT), dim3(256), 0, stream>>>(h1b, Mf64);
    k_proj<64><<<dim3(128, TT), dim3(64), 0, stream>>>(Mf64, w2, st2, 128, 262144.0);
    k_mconv<64,128,3,true><<<dim3(PP/64,2,8), dim3(256), 0, stream>>>(
        h1n, wp2h, wp2m, wp2l, st2, g2, be2, nullptr, m2p, nullptr, PP);
    k_repack<128><<<dim3(32,8,4), dim3(256), 0, stream>>>(m2p, m2b);
    // conv3
    k_gram<128><<<dim3(128, TT), dim3(256), 0, stream>>>(m2b, Mf128);
    k_proj<128><<<dim3(256, TT), dim3(128), 0, stream>>>(Mf128, w3, st3, 256, 16384.0);
    k_mconv<128,256,1,false><<<dim3(32,4,8), dim3(256), 0, stream>>>(
        m2p, wp3h, wp3m, wp3l, st3, g3, be3, nullptr, h3p, nullptr, NN);
    k_repack<256><<<dim3(32,8,4), dim3(256), 0, stream>>>(h3p, h3b);
    // conv4
    k_gram<256><<<dim3(256, TT), dim3(256), 0, stream>>>(h3b, Mf256);
    k_proj<256><<<dim3(1024, TT), dim3(256), 0, stream>>>(Mf256, w4, st4, 1024, 16384.0);
    k_mconv<256,1024,2,false><<<dim3(32,16,8), dim3(256), 0, stream>>>(
        h3p, wp4h, wp4m, wp4l, st4, g4, be4, nullptr, nullptr, mx4, NN);
    // output
    k_out<<<dim3(32), dim3(256), 0, stream>>>(mx4, (float*)d_out);
}

// Round 6
// 822.591 us; speedup vs baseline: 5.3217x; 1.2820x over previous
//
#include <hip/hip_runtime.h>
#include <stdint.h>

#define TT 4
#define BB 8
#define NN 2048
#define KNB 16
#define PP (NN*KNB)
#define VTH 1.0f
#define EPSB 1e-5f

typedef unsigned long long u64;
typedef unsigned int u32;
typedef unsigned short u16;
typedef unsigned char u8;
typedef __attribute__((ext_vector_type(8))) short short8;
typedef __attribute__((ext_vector_type(4))) float f4;

#define GLOAD_LDS16(g, l) __builtin_amdgcn_global_load_lds( \
    (const __attribute__((address_space(1))) u32*)(g), \
    (__attribute__((address_space(3))) u32*)(l), 16, 0, 0)

__device__ __forceinline__ float lif_step(float& v, float x) {
    v = v + (x - v) / 2.0f;
    float s = (v - VTH >= 0.0f) ? 1.0f : 0.0f;
    v = v * (1.0f - s);
    return s;
}

// ---------------- T-Net ----------------
__global__ __launch_bounds__(256) void k_tnet1(const float* __restrict__ x, const float* __restrict__ w,
        const float* __restrict__ bi, u64* __restrict__ s1b) {
    int i = blockIdx.x*256 + threadIdx.x;
    int b = i >> 11, n = i & 2047;
    float p0 = x[((size_t)b*14+0)*NN+n];
    float p1 = x[((size_t)b*14+1)*NN+n];
    float p2 = x[((size_t)b*14+2)*NN+n];
    u64 m[TT] = {0,0,0,0};
    for (int d = 0; d < 64; ++d) {
        float z = ((w[d*3+0]*p0 + w[d*3+1]*p1) + w[d*3+2]*p2) + bi[d];
        float v = 0.f;
        #pragma unroll
        for (int t = 0; t < TT; ++t) {
            float s = lif_step(v, z);
            if (s != 0.f) m[t] |= (1ull << d);
        }
    }
    #pragma unroll
    for (int t = 0; t < TT; ++t) s1b[((size_t)t*BB + b)*NN + n] = m[t];
}

// conv2: 64->128, split over 4 channel-chunks of 32 for occupancy
__global__ __launch_bounds__(256) void k_tnet2(const u64* __restrict__ s1b, const float* __restrict__ w,
        const float* __restrict__ bi, u32* __restrict__ s2b32) {
    __shared__ float ws[32*64];
    int tid = threadIdx.x;
    int ec = blockIdx.y;
    for (int l = tid; l < 32*64; l += 256) ws[l] = w[ec*32*64 + l];
    __syncthreads();
    int i = blockIdx.x*256 + tid;
    int b = i >> 11, n = i & 2047;
    u64 m[TT];
    #pragma unroll
    for (int t = 0; t < TT; ++t) m[t] = s1b[((size_t)t*BB+b)*NN+n];
    u32 o[TT] = {0,0,0,0};
    for (int el = 0; el < 32; ++el) {
        float z[TT] = {0.f,0.f,0.f,0.f};
        #pragma unroll 8
        for (int d = 0; d < 64; ++d) {
            float wv = ws[el*64+d];
            #pragma unroll
            for (int t = 0; t < TT; ++t) z[t] += ((m[t]>>d)&1ull) ? wv : 0.f;
        }
        float v = 0.f, bb = bi[ec*32 + el];
        #pragma unroll
        for (int t = 0; t < TT; ++t) {
            float s = lif_step(v, z[t] + bb);
            if (s != 0.f) o[t] |= (1u << el);
        }
    }
    #pragma unroll
    for (int t = 0; t < TT; ++t)
        s2b32[(((size_t)t*BB+b)*NN+n)*4 + ec] = o[t];
}

// FC head: 1024->512->256->9
__global__ __launch_bounds__(512) void k_fc(const u32* __restrict__ mx, const float* __restrict__ fw1, const float* __restrict__ fb1,
        const float* __restrict__ fw2, const float* __restrict__ fb2, const float* __restrict__ fw3, const float* __restrict__ fb3,
        float* __restrict__ trans) {
    __shared__ float h0[TT][1024];
    __shared__ float h1[TT][512];
    __shared__ float h2[TT][256];
    __shared__ float h3s[TT][9];
    int b = blockIdx.x, tid = threadIdx.x;
    for (int l = tid; l < TT*1024; l += 512) h0[l>>10][l&1023] = (float)mx[((size_t)(l>>10)*BB + b)*1024 + (l&1023)];
    __syncthreads();
    {
        float z[TT] = {0.f,0.f,0.f,0.f};
        #pragma unroll 4
        for (int f = 0; f < 1024; ++f) {
            float wv = fw1[(size_t)tid*1024 + f];
            #pragma unroll
            for (int t = 0; t < TT; ++t) z[t] += wv * h0[t][f];
        }
        float v = 0.f;
        #pragma unroll
        for (int t = 0; t < TT; ++t) h1[t][tid] = lif_step(v, z[t] + fb1[tid]);
    }
    __syncthreads();
    if (tid < 256) {
        float z[TT] = {0.f,0.f,0.f,0.f};
        #pragma unroll 4
        for (int f = 0; f < 512; ++f) {
            float wv = fw2[(size_t)tid*512 + f];
            #pragma unroll
            for (int t = 0; t < TT; ++t) z[t] += wv * h1[t][f];
        }
        float v = 0.f;
        #pragma unroll
        for (int t = 0; t < TT; ++t) h2[t][tid] = lif_step(v, z[t] + fb2[tid]);
    }
    __syncthreads();
    if (tid < TT*9) {
        int t = tid/9, oo = tid%9;
        float z = 0.f;
        for (int f = 0; f < 256; ++f) z += fw3[oo*256+f]*h2[t][f];
        h3s[t][oo] = z + fb3[oo];
    }
    __syncthreads();
    if (tid < 9) {
        float m = ((h3s[0][tid]+h3s[1][tid]) + (h3s[2][tid]+h3s[3][tid])) * 0.25f;
        int c = tid/3, dd = tid%3;
        trans[b*9+tid] = m + ((c==dd)?1.0f:0.0f);
    }
}

// apply transform; also emit packed float4 (x,y,z,sq) for KNN
__global__ __launch_bounds__(256) void k_trans(const float* __restrict__ x, const float* __restrict__ tr,
        float* __restrict__ xa, float4* __restrict__ xa4) {
    int i = blockIdx.x*256 + threadIdx.x;
    int b = i >> 11, n = i & 2047;
    float p0 = x[((size_t)b*14+0)*NN+n];
    float p1 = x[((size_t)b*14+1)*NN+n];
    float p2 = x[((size_t)b*14+2)*NN+n];
    const float* tb = tr + b*9;
    float a0 = (p0*tb[0] + p1*tb[3]) + p2*tb[6];
    float a1 = (p0*tb[1] + p1*tb[4]) + p2*tb[7];
    float a2 = (p0*tb[2] + p1*tb[5]) + p2*tb[8];
    xa[((size_t)b*14+0)*NN+n] = a0;
    xa[((size_t)b*14+1)*NN+n] = a1;
    xa[((size_t)b*14+2)*NN+n] = a2;
    for (int c = 3; c < 14; ++c) xa[((size_t)b*14+c)*NN+n] = x[((size_t)b*14+c)*NN+n];
    float4 p;
    p.x = a0; p.y = a1; p.z = a2;
    p.w = (a0*a0 + a1*a1) + a2*a2;
    xa4[(size_t)b*NN+n] = p;
}

// KNN: one wave per query point; 32 candidate distances per lane in registers.
__global__ __launch_bounds__(256) void k_knn(const float4* __restrict__ xa4, int* __restrict__ idx) {
    int wave = threadIdx.x >> 6, lane = threadIdx.x & 63;
    int b = blockIdx.y;
    int n = blockIdx.x*4 + wave;
    const float4* P = xa4 + (size_t)b*NN;
    float4 q = P[n];
    float sn = q.w;
    float vals[32];
    #pragma unroll
    for (int j = 0; j < 32; ++j) {
        float4 p = P[j*64 + lane];
        float inner = (q.x*p.x + q.y*p.y) + q.z*p.z;
        vals[j] = (2.0f*inner - sn) - p.w;
    }
    for (int k = 0; k < KNB; ++k) {
        float bv = -3.4e38f; int bj = 0;
        #pragma unroll
        for (int j = 0; j < 32; ++j) if (vals[j] > bv) { bv = vals[j]; bj = j; }
        int bm = bj*64 + lane;
        u32 fb = __float_as_uint(bv);
        fb = (fb & 0x80000000u) ? ~fb : (fb | 0x80000000u);
        u64 key = ((u64)fb << 32) | (u32)(~bm);
        #pragma unroll
        for (int o2 = 1; o2 < 64; o2 <<= 1) {
            u64 other = __shfl_xor(key, o2, 64);
            key = (other > key) ? other : key;
        }
        int wm = (int)(~(u32)key);
        if (lane == 0) idx[((size_t)b*NN + n)*KNB + k] = wm;
        int wl = wm & 63, wj = wm >> 6;
        if (lane == wl) {
            #pragma unroll
            for (int j = 0; j < 32; ++j) if (j == wj) vals[j] = -3.4e38f;
        }
    }
}

__global__ __launch_bounds__(256) void k_gfeat(const float* __restrict__ xa, const int* __restrict__ idx, float* __restrict__ gf) {
    int i = blockIdx.x*256 + threadIdx.x;
    int b = i >> 15;
    int r = i & 32767;
    int n = r >> 4;
    int mm = idx[((size_t)b*NN+n)*KNB + (r & 15)];
    size_t pbase = (size_t)b*28*PP + r;
    #pragma unroll
    for (int c = 0; c < 14; ++c) {
        float ctr = xa[((size_t)b*14+c)*NN + n];
        float nb  = xa[((size_t)b*14+c)*NN + mm];
        gf[pbase + (size_t)c*PP] = ctr;
        gf[pbase + (size_t)(14+c)*PP] = nb - ctr;
    }
}

// edge conv1 stats partials
__global__ __launch_bounds__(256) void k_estats1(const float* __restrict__ gf, const float* __restrict__ w1, float* __restrict__ part1) {
    __shared__ float gfs[28][256];
    __shared__ float w1s[64*28];
    __shared__ float wsum[4][64], wsq[4][64];
    int pt = blockIdx.x, b = blockIdx.y;
    int p0 = pt*256, tid = threadIdx.x;
    for (int l = tid; l < 28*256; l += 256) gfs[l>>8][l&255] = gf[((size_t)b*28 + (l>>8))*PP + p0 + (l&255)];
    for (int l = tid; l < 64*28; l += 256) w1s[l] = w1[l];
    __syncthreads();
    int wv = tid>>6, lane = tid&63;
    for (int d = 0; d < 64; ++d) {
        float z = 0.f;
        #pragma unroll
        for (int c = 0; c < 28; ++c) z += w1s[d*28+c]*gfs[c][tid];
        float s = z, q = z*z;
        #pragma unroll
        for (int o = 1; o < 64; o <<= 1) { s += __shfl_xor(s, o, 64); q += __shfl_xor(q, o, 64); }
        if (lane == 0) { wsum[wv][d] = s; wsq[wv][d] = q; }
    }
    __syncthreads();
    if (tid < 64) {
        float s = (wsum[0][tid]+wsum[1][tid])+(wsum[2][tid]+wsum[3][tid]);
        float q = (wsq[0][tid]+wsq[1][tid])+(wsq[2][tid]+wsq[3][tid]);
        size_t blk = (size_t)b*128 + pt;
        part1[(blk*64 + tid)*2+0] = s;
        part1[(blk*64 + tid)*2+1] = q;
    }
}

__global__ __launch_bounds__(256) void k_reduce(const float* __restrict__ part, float* __restrict__ stats, int nch, int nblk, double M) {
    __shared__ double sred[256], qred[256];
    int ch = blockIdx.x, tid = threadIdx.x;
    double s = 0.0, q = 0.0;
    for (int i = tid; i < nblk; i += 256) {
        s += (double)part[((size_t)i*nch + ch)*2 + 0];
        q += (double)part[((size_t)i*nch + ch)*2 + 1];
    }
    sred[tid] = s; qred[tid] = q;
    __syncthreads();
    for (int off = 128; off > 0; off >>= 1) {
        if (tid < off) { sred[tid] += sred[tid+off]; qred[tid] += qred[tid+off]; }
        __syncthreads();
    }
    if (tid == 0) {
        double mu = sred[0] / M;
        double var = qred[0] / M - mu*mu;
        if (var < 0.0) var = 0.0;
        stats[ch*2+0] = (float)mu;
        stats[ch*2+1] = 1.0f / sqrtf((float)var + EPSB);
    }
}

// edge conv1 apply: norm+LIF -> h1b (channel-major bits) + h1n (u64 mask per point)
__global__ __launch_bounds__(256) void k_h1(const float* __restrict__ gf, const float* __restrict__ w1,
        const float* __restrict__ st1, const float* __restrict__ g1, const float* __restrict__ be1,
        u64* __restrict__ h1b, u64* __restrict__ h1n) {
    __shared__ float w1s[64*28];
    int tid = threadIdx.x;
    int b = blockIdx.y;
    int p0 = blockIdx.x*256;
    int p = p0 + tid;
    for (int l = tid; l < 64*28; l += 256) w1s[l] = w1[l];
    __syncthreads();
    float gr[28];
    #pragma unroll
    for (int c = 0; c < 28; ++c) gr[c] = gf[((size_t)b*28 + c)*PP + p];
    int wordbase = (p0>>6) + (tid>>6);
    u64 pm[TT] = {0,0,0,0};
    for (int d = 0; d < 64; ++d) {
        float z = 0.f;
        #pragma unroll
        for (int c = 0; c < 28; ++c) z += w1s[d*28+c]*gr[c];
        float mu = st1[d*2+0], iv = st1[d*2+1];
        float v = 0.f;
        #pragma unroll
        for (int t = 0; t < TT; ++t) {
            float y = (z - mu) * iv * g1[t*64+d] + be1[t*64+d];
            float s = lif_step(v, y);
            u64 m = __ballot(s != 0.f);
            if ((tid & 63) == 0) h1b[((size_t)(t*BB+b)*64 + d)*512 + wordbase] = m;
            pm[t] |= ((u64)(s != 0.f)) << d;
        }
    }
    #pragma unroll
    for (int t = 0; t < TT; ++t) h1n[(size_t)(t*BB+b)*PP + p] = pm[t];
}

// ---------------- Tiled popcount Grams (exact int counts) ----------------
// Gram of h1 bits: 64 channels x 512 words x 8 b. Tile = all 64 ch x 64-word chunk in LDS.
// Grid: (512/64, TT*BB). Integer atomicAdd partials (exact, deterministic).
__global__ __launch_bounds__(256) void k_gram_h1(const u64* __restrict__ h1b, int* __restrict__ Mi) {
    __shared__ u64 tw[64*65];
    int tid = threadIdx.x;
    int w0 = blockIdx.x*64;
    int tb = blockIdx.y;
    int t = tb >> 3;
    const u64* src = h1b + (size_t)tb*64*512;
    for (int l = tid; l < 64*64; l += 256) {
        int c = l >> 6, w = l & 63;
        tw[c*65+w] = src[(size_t)c*512 + w0 + w];
    }
    __syncthreads();
    int q = tid >> 4, r = tid & 15;
    int acc[4][4];
    #pragma unroll
    for (int i=0;i<4;++i)
        #pragma unroll
        for (int j=0;j<4;++j) acc[i][j]=0;
    #pragma unroll 4
    for (int w = 0; w < 64; ++w) {
        u64 av[4], bv[4];
        #pragma unroll
        for (int i=0;i<4;++i) av[i] = tw[(q+16*i)*65+w];
        #pragma unroll
        for (int j=0;j<4;++j) bv[j] = tw[(r+16*j)*65+w];
        #pragma unroll
        for (int i=0;i<4;++i)
            #pragma unroll
            for (int j=0;j<4;++j) acc[i][j] += (int)__popcll(av[i]&bv[j]);
    }
    #pragma unroll
    for (int i=0;i<4;++i)
        #pragma unroll
        for (int j=0;j<4;++j)
            atomicAdd(&Mi[((size_t)t*64 + q+16*i)*64 + r+16*j], acc[i][j]);
}

// Gram for bit-packed [tb][C][32] spikes: 64x64-channel tiles, both staged in LDS.
// Grid: (C/64, C/64, TT*BB).
template<int C>
__global__ __launch_bounds__(256) void k_gram2(const u64* __restrict__ bits, int* __restrict__ Mi) {
    __shared__ u64 ta[64*33], tbt[64*33];
    int tid = threadIdx.x;
    int ci0 = blockIdx.x*64, cj0 = blockIdx.y*64;
    int tb = blockIdx.z;
    int t = tb >> 3;
    const u64* srcA = bits + ((size_t)tb*C + ci0)*32;
    const u64* srcB = bits + ((size_t)tb*C + cj0)*32;
    for (int l = tid; l < 64*32; l += 256) {
        int rr = l >> 5, w = l & 31;
        ta[rr*33+w]  = srcA[(size_t)rr*32+w];
        tbt[rr*33+w] = srcB[(size_t)rr*32+w];
    }
    __syncthreads();
    int q = tid >> 4, r = tid & 15;
    int acc[4][4];
    #pragma unroll
    for (int i=0;i<4;++i)
        #pragma unroll
        for (int j=0;j<4;++j) acc[i][j]=0;
    #pragma unroll 4
    for (int w = 0; w < 32; ++w) {
        u64 av[4], bv[4];
        #pragma unroll
        for (int i=0;i<4;++i) av[i] = ta[(q+16*i)*33+w];
        #pragma unroll
        for (int j=0;j<4;++j) bv[j] = tbt[(r+16*j)*33+w];
        #pragma unroll
        for (int i=0;i<4;++i)
            #pragma unroll
            for (int j=0;j<4;++j) acc[i][j] += (int)__popcll(av[i]&bv[j]);
    }
    #pragma unroll
    for (int i=0;i<4;++i)
        #pragma unroll
        for (int j=0;j<4;++j)
            atomicAdd(&Mi[((size_t)t*C + ci0+q+16*i)*C + cj0+r+16*j], acc[i][j]);
}

// project int Gram through weights -> per-(t,ch) (mean, inv_std)
template<int CIN>
__global__ void k_proj(const int* __restrict__ Mf, const float* __restrict__ w,
        float* __restrict__ st, int COUT, double cnt) {
    __shared__ double z2s[256], mns[256];
    int ch = blockIdx.x, t = blockIdx.y, c2 = threadIdx.x;
    const int* Mt = Mf + (size_t)t*CIN*CIN;
    double y = 0.0;
    for (int c = 0; c < CIN; ++c)
        y += (double)w[(size_t)ch*CIN+c] * (double)Mt[(size_t)c*CIN + c2];
    double wc2 = (double)w[(size_t)ch*CIN+c2];
    z2s[c2] = wc2 * y;
    mns[c2] = wc2 * (double)Mt[(size_t)c2*CIN + c2];
    __syncthreads();
    for (int off = CIN>>1; off > 0; off >>= 1) {
        if (c2 < off) { z2s[c2] += z2s[c2+off]; mns[c2] += mns[c2+off]; }
        __syncthreads();
    }
    if (c2 == 0) {
        double mu = mns[0] / cnt;
        double var = z2s[0] / cnt - mu*mu;
        if (var < 0.0) var = 0.0;
        st[((size_t)t*COUT+ch)*2+0] = (float)mu;
        st[((size_t)t*COUT+ch)*2+1] = 1.0f / sqrtf((float)var + EPSB);
    }
}

// weight prep: fp32 w[F][K] -> exact 3-way bf16 split in MFMA-frag layout [K/8][F][8]
__global__ __launch_bounds__(256) void k_wprep(const float* __restrict__ w,
        short* __restrict__ hi, short* __restrict__ mid, short* __restrict__ lo, int F, int K) {
    int i = blockIdx.x*256 + threadIdx.x;
    if (i >= F*K) return;
    int f = i / K, k = i % K;
    float wv = w[i];
    u32 b0 = __float_as_uint(wv);
    float h = __uint_as_float(b0 & 0xFFFF0000u);
    float r1 = wv - h;
    u32 b1 = __float_as_uint(r1);
    float m = __uint_as_float(b1 & 0xFFFF0000u);
    float r2 = r1 - m;
    u32 b2 = __float_as_uint(r2);
    size_t o = ((size_t)(k>>3)*F + f)*8 + (k&7);
    hi[o]  = (short)(b0 >> 16);
    mid[o] = (short)(b1 >> 16);
    lo[o]  = (short)(b2 >> 16);
}

// ---------------- MFMA spike conv (LDS-staged weights) ----------------
template<int K, int F, int MODE, bool BITS>
__global__ __launch_bounds__(256) void k_mconv(
        const void* __restrict__ Asrc,
        const short* __restrict__ Whi, const short* __restrict__ Wmd, const short* __restrict__ Wlo,
        const float* __restrict__ st, const float* __restrict__ ga, const float* __restrict__ be,
        const float* __restrict__ bias,
        u16* __restrict__ outp, u32* __restrict__ outm, int NPTS) {
    constexpr int KT = (K < 128) ? K : 128;
    constexpr int ROWS = (KT/8)*3;
    __shared__ short wsm[(KT/8)*3*512];
    __shared__ u32 morr[TT][64];
    int tid = threadIdx.x;
    int wave = tid >> 6, lane = tid & 63;
    int l15 = lane & 15, lg = lane >> 4;
    int b = blockIdx.z;
    int n_base = blockIdx.x*64 + wave*16;
    int f0 = blockIdx.y*64;
    if (MODE == 0 || MODE == 2)
        for (int l = tid; l < TT*64; l += 256) morr[l>>6][l&63] = 0u;

    f4 acc[4][TT];
    #pragma unroll
    for (int i = 0; i < 4; ++i)
        #pragma unroll
        for (int t = 0; t < TT; ++t) acc[i][t] = (f4)0.f;

    const u64* Ab[TT];
    const u16* Au[TT];
    #pragma unroll
    for (int t = 0; t < TT; ++t) {
        if (BITS) Ab[t] = (const u64*)Asrc + ((size_t)(t*BB+b)*NPTS + n_base + l15)*(K/64);
        else      Au[t] = (const u16*)Asrc + ((size_t)(t*BB+b)*NPTS + n_base + l15)*K + lg*8;
    }
    const short* Wsrc[3] = {Whi, Wmd, Wlo};

    for (int kt = 0; kt < K; kt += KT) {
        if (kt > 0) __syncthreads();
        for (int r = wave; r < ROWS; r += 4) {
            int kq = r/3, s = r - kq*3;
            const short* g = Wsrc[s] + ((size_t)((kt>>3) + kq)*F + f0)*8 + lane*8;
            GLOAD_LDS16(g, &wsm[r*512]);
        }
        __syncthreads();
        for (int k0 = 0; k0 < KT; k0 += 32) {
            int kg = kt + k0;
            short8 a[TT];
            #pragma unroll
            for (int t = 0; t < TT; ++t) {
                if (BITS) {
                    int kk = kg + lg*8;
                    u64 word = Ab[t][kk >> 6];
                    u32 byte = (u32)(word >> (kk & 63)) & 0xFFu;
                    #pragma unroll
                    for (int j = 0; j < 8; ++j) a[t][j] = (short)(((byte>>j)&1u) * 0x3F80u);
                } else {
                    a[t] = *(const short8*)(Au[t] + kg);
                }
            }
            int kql = (k0>>3) + lg;
            #pragma unroll
            for (int fs = 0; fs < 4; ++fs) {
                const short* base = wsm + kql*1536 + (fs*16+l15)*8;
                short8 whi = *(const short8*)(base);
                short8 wmd = *(const short8*)(base + 512);
                short8 wlo = *(const short8*)(base + 1024);
                #pragma unroll
                for (int t = 0; t < TT; ++t) {
                    acc[fs][t] = __builtin_amdgcn_mfma_f32_16x16x32_bf16(a[t], whi, acc[fs][t], 0, 0, 0);
                    acc[fs][t] = __builtin_amdgcn_mfma_f32_16x16x32_bf16(a[t], wmd, acc[fs][t], 0, 0, 0);
                    acc[fs][t] = __builtin_amdgcn_mfma_f32_16x16x32_bf16(a[t], wlo, acc[fs][t], 0, 0, 0);
                }
            }
        }
    }
    if (MODE == 1) {
        #pragma unroll
        for (int fs = 0; fs < 4; ++fs) {
            int f = f0 + fs*16 + l15;
            #pragma unroll
            for (int reg = 0; reg < 4; ++reg) {
                int n = n_base + lg*4 + reg;
                float v = 0.f;
                #pragma unroll
                for (int t = 0; t < TT; ++t) {
                    int ch = t*F + f;
                    float y = (acc[fs][t][reg] - st[(size_t)ch*2+0])*st[(size_t)ch*2+1]*ga[ch] + be[ch];
                    float s = lif_step(v, y);
                    outp[((size_t)(t*BB+b)*NPTS + n)*F + f] = (s != 0.f) ? (u16)0x3F80 : (u16)0;
                }
            }
        }
    } else if (MODE == 3) {
        #pragma unroll
        for (int fs = 0; fs < 4; ++fs) {
            int f = f0 + fs*16 + l15;
            u32 nib = 0u;
            #pragma unroll
            for (int reg = 0; reg < 4; ++reg) {
                float v = 0.f;
                #pragma unroll
                for (int t = 0; t < TT; ++t) {
                    int ch = t*F + f;
                    float y = (acc[fs][t][reg] - st[(size_t)ch*2+0])*st[(size_t)ch*2+1]*ga[ch] + be[ch];
                    float s = lif_step(v, y);
                    if (s != 0.f) nib |= (1u << t);
                }
            }
            nib |= __shfl_xor(nib, 16, 64);
            nib |= __shfl_xor(nib, 32, 64);
            if (lg == 0) {
                int n_pt = n_base >> 4;
                #pragma unroll
                for (int t = 0; t < TT; ++t)
                    outp[((size_t)(t*BB+b)*(NPTS>>4) + n_pt)*F + f] = ((nib>>t)&1u) ? (u16)0x3F80 : (u16)0;
            }
        }
    } else {
        #pragma unroll
        for (int fs = 0; fs < 4; ++fs) {
            int f = f0 + fs*16 + l15;
            u32 any[TT] = {0,0,0,0};
            float bb = (MODE == 0) ? bias[f] : 0.f;
            #pragma unroll
            for (int reg = 0; reg < 4; ++reg) {
                float v = 0.f;
                #pragma unroll
                for (int t = 0; t < TT; ++t) {
                    float y;
                    if (MODE == 0) y = acc[fs][t][reg] + bb;
                    else {
                        int ch = t*F + f;
                        y = (acc[fs][t][reg] - st[(size_t)ch*2+0])*st[(size_t)ch*2+1]*ga[ch] + be[ch];
                    }
                    float s = lif_step(v, y);
                    if (s != 0.f) any[t] = 1u;
                }
            }
            #pragma unroll
            for (int t = 0; t < TT; ++t) if (any[t]) atomicOr(&morr[t][fs*16+l15], 1u);
        }
        __syncthreads();
        for (int l = tid; l < TT*64; l += 256)
            if (morr[l>>6][l&63]) atomicOr(&outm[((size_t)((l>>6)*BB+b))*F + f0 + (l&63)], 1u);
    }
}

// repack point-major bf16-u16 spikes [t][b][n][C] -> channel-major bits [t][b][C][32 words over n]
template<int C>
__global__ __launch_bounds__(256) void k_repack(const u16* __restrict__ sp, u64* __restrict__ bits) {
    __shared__ u16 tile[64][C+2];
    int tid = threadIdx.x;
    int nw = blockIdx.x, b = blockIdx.y, t = blockIdx.z;
    const u16* src = sp + ((size_t)(t*BB+b)*NN + nw*64)*C;
    for (int i = tid*2; i < 64*C; i += 512) {
        u32 v = *(const u32*)(src + i);
        int r = i / C, c = i % C;
        *(u32*)&tile[r][c] = v;
    }
    __syncthreads();
    int wave = tid >> 6, lane = tid & 63;
    for (int c = wave; c < C; c += 4) {
        u64 m = __ballot(tile[lane][c] != 0);
        if (lane == 0) bits[((size_t)(t*BB+b)*C + c)*32 + nw] = m;
    }
}

__global__ __launch_bounds__(256) void k_out(const u32* __restrict__ mx4, float* __restrict__ out) {
    int i = blockIdx.x*256 + threadIdx.x;
    int b = i >> 10, g = i & 1023;
    float s = (float)(mx4[((size_t)0*BB+b)*1024+g] + mx4[((size_t)1*BB+b)*1024+g]
                    + mx4[((size_t)2*BB+b)*1024+g] + mx4[((size_t)3*BB+b)*1024+g]);
    out[i] = s * 0.25f;
}

extern "C" void kernel_launch(void* const* d_in, const int* in_sizes, int n_in,
                              void* d_out, int out_size, void* d_ws, size_t ws_size,
                              hipStream_t stream) {
    (void)in_sizes; (void)n_in; (void)out_size;
    const float* x    = (const float*)d_in[0];
    const float* tw1  = (const float*)d_in[1];
    const float* tb1  = (const float*)d_in[2];
    const float* tw2  = (const float*)d_in[3];
    const float* tb2  = (const float*)d_in[4];
    const float* tw3  = (const float*)d_in[5];
    const float* tb3  = (const float*)d_in[6];
    const float* tfw1 = (const float*)d_in[7];
    const float* tfb1 = (const float*)d_in[8];
    const float* tfw2 = (const float*)d_in[9];
    const float* tfb2 = (const float*)d_in[10];
    const float* tfw3 = (const float*)d_in[11];
    const float* tfb3 = (const float*)d_in[12];
    const float* w1   = (const float*)d_in[13];
    const float* w2   = (const float*)d_in[14];
    const float* w3   = (const float*)d_in[15];
    const float* w4   = (const float*)d_in[16];
    const float* g1   = (const float*)d_in[17];
    const float* be1  = (const float*)d_in[18];
    const float* g2   = (const float*)d_in[19];
    const float* be2  = (const float*)d_in[20];
    const float* g3   = (const float*)d_in[21];
    const float* be3  = (const float*)d_in[22];
    const float* g4   = (const float*)d_in[23];
    const float* be4  = (const float*)d_in[24];

    char* wsb = (char*)d_ws;
    size_t off = 0;
    auto alloc = [&](size_t bytes) -> void* {
        void* p = wsb + off;
        off = (off + bytes + 255) & ~(size_t)255;
        return p;
    };
    u64* s1b   = (u64*)alloc(sizeof(u64)*(size_t)TT*BB*NN);
    u64* s2b   = (u64*)alloc(sizeof(u64)*(size_t)TT*BB*NN*2);
    u32* mx    = (u32*)alloc(sizeof(u32)*(size_t)TT*BB*1024);
    u32* mx4   = (u32*)alloc(sizeof(u32)*(size_t)TT*BB*1024);
    float* trs = (float*)alloc(sizeof(float)*BB*9);
    float* xa  = (float*)alloc(sizeof(float)*(size_t)BB*14*NN);
    float4* xa4 = (float4*)alloc(sizeof(float4)*(size_t)BB*NN);
    int* idx   = (int*)alloc(sizeof(int)*(size_t)BB*NN*KNB);
    float* gf  = (float*)alloc(sizeof(float)*(size_t)BB*28*PP);
    float* part1 = (float*)alloc(sizeof(float)*(size_t)1024*64*2);
    float* st1 = (float*)alloc(sizeof(float)*64*2);
    float* st2 = (float*)alloc(sizeof(float)*512*2);
    float* st3 = (float*)alloc(sizeof(float)*1024*2);
    float* st4 = (float*)alloc(sizeof(float)*4096*2);
    u64* h1b = (u64*)alloc(sizeof(u64)*(size_t)TT*BB*64*512);
    u64* h1n = (u64*)alloc(sizeof(u64)*(size_t)TT*BB*PP);
    u16* m2p = (u16*)alloc(sizeof(u16)*(size_t)TT*BB*NN*128);
    u16* h3p = (u16*)alloc(sizeof(u16)*(size_t)TT*BB*NN*256);
    u64* m2b = (u64*)alloc(sizeof(u64)*(size_t)TT*BB*128*32);
    u64* h3b = (u64*)alloc(sizeof(u64)*(size_t)TT*BB*256*32);
    int* Mi64  = (int*)alloc(sizeof(int)*(size_t)TT*64*64);
    int* Mi128 = (int*)alloc(sizeof(int)*(size_t)TT*128*128);
    int* Mi256 = (int*)alloc(sizeof(int)*(size_t)TT*256*256);
    short* wp2h = (short*)alloc(sizeof(short)*(size_t)128*64);
    short* wp2m = (short*)alloc(sizeof(short)*(size_t)128*64);
    short* wp2l = (short*)alloc(sizeof(short)*(size_t)128*64);
    short* wp3h = (short*)alloc(sizeof(short)*(size_t)256*128);
    short* wp3m = (short*)alloc(sizeof(short)*(size_t)256*128);
    short* wp3l = (short*)alloc(sizeof(short)*(size_t)256*128);
    short* wp4h = (short*)alloc(sizeof(short)*(size_t)1024*256);
    short* wp4m = (short*)alloc(sizeof(short)*(size_t)1024*256);
    short* wp4l = (short*)alloc(sizeof(short)*(size_t)1024*256);
    short* wpth = (short*)alloc(sizeof(short)*(size_t)1024*128);
    short* wptm = (short*)alloc(sizeof(short)*(size_t)1024*128);
    short* wptl = (short*)alloc(sizeof(short)*(size_t)1024*128);
    if (off > ws_size) return;

    hipMemsetAsync(mx, 0, sizeof(u32)*(size_t)TT*BB*1024, stream);
    hipMemsetAsync(mx4, 0, sizeof(u32)*(size_t)TT*BB*1024, stream);
    hipMemsetAsync(Mi64, 0, sizeof(int)*(size_t)TT*64*64, stream);
    hipMemsetAsync(Mi128, 0, sizeof(int)*(size_t)TT*128*128, stream);
    hipMemsetAsync(Mi256, 0, sizeof(int)*(size_t)TT*256*256, stream);

    // weight prep (exact 3-way bf16 split)
    k_wprep<<<dim3((128*64+255)/256), dim3(256), 0, stream>>>(w2, wp2h, wp2m, wp2l, 128, 64);
    k_wprep<<<dim3((256*128+255)/256), dim3(256), 0, stream>>>(w3, wp3h, wp3m, wp3l, 256, 128);
    k_wprep<<<dim3((1024*256+255)/256), dim3(256), 0, stream>>>(w4, wp4h, wp4m, wp4l, 1024, 256);
    k_wprep<<<dim3((1024*128+255)/256), dim3(256), 0, stream>>>(tw3, wpth, wptm, wptl, 1024, 128);

    // T-Net
    k_tnet1<<<dim3(64), dim3(256), 0, stream>>>(x, tw1, tb1, s1b);
    k_tnet2<<<dim3(64, 4), dim3(256), 0, stream>>>(s1b, tw2, tb2, (u32*)s2b);
    k_mconv<128,1024,0,true><<<dim3(32,16,8), dim3(256), 0, stream>>>(
        s2b, wpth, wptm, wptl, nullptr, nullptr, nullptr, tb3, nullptr, mx, NN);
    k_fc<<<dim3(8), dim3(512), 0, stream>>>(mx, tfw1, tfb1, tfw2, tfb2, tfw3, tfb3, trs);
    k_trans<<<dim3(64), dim3(256), 0, stream>>>(x, trs, xa, xa4);
    // KNN (wave-per-query) + graph feature
    k_knn<<<dim3(NN/4, BB), dim3(256), 0, stream>>>(xa4, idx);
    k_gfeat<<<dim3((BB*NN*KNB)/256), dim3(256), 0, stream>>>(xa, idx, gf);
    // edge conv1 stats + apply
    k_estats1<<<dim3(128, 8), dim3(256), 0, stream>>>(gf, w1, part1);
    k_reduce<<<dim3(64), dim3(256), 0, stream>>>(part1, st1, 64, 1024, 262144.0);
    k_h1<<<dim3(128, 8), dim3(256), 0, stream>>>(gf, w1, st1, g1, be1, h1b, h1n);
    // edge conv2: stats via tiled Gram, apply via MFMA (+ max over k)
    k_gram_h1<<<dim3(8, TT*BB), dim3(256), 0, stream>>>(h1b, Mi64);
    k_proj<64><<<dim3(128, TT), dim3(64), 0, stream>>>(Mi64, w2, st2, 128, 262144.0);
    k_mconv<64,128,3,true><<<dim3(PP/64,2,8), dim3(256), 0, stream>>>(
        h1n, wp2h, wp2m, wp2l, st2, g2, be2, nullptr, m2p, nullptr, PP);
    k_repack<128><<<dim3(32,8,4), dim3(256), 0, stream>>>(m2p, m2b);
    // conv3
    k_gram2<128><<<dim3(2,2,TT*BB), dim3(256), 0, stream>>>(m2b, Mi128);
    k_proj<128><<<dim3(256, TT), dim3(128), 0, stream>>>(Mi128, w3, st3, 256, 16384.0);
    k_mconv<128,256,1,false><<<dim3(32,4,8), dim3(256), 0, stream>>>(
        m2p, wp3h, wp3m, wp3l, st3, g3, be3, nullptr, h3p, nullptr, NN);
    k_repack<256><<<dim3(32,8,4), dim3(256), 0, stream>>>(h3p, h3b);
    // conv4
    k_gram2<256><<<dim3(4,4,TT*BB), dim3(256), 0, stream>>>(h3b, Mi256);
    k_proj<256><<<dim3(1024, TT), dim3(256), 0, stream>>>(Mi256, w4, st4, 1024, 16384.0);
    k_mconv<256,1024,2,false><<<dim3(32,16,8), dim3(256), 0, stream>>>(
        h3p, wp4h, wp4m, wp4l, st4, g4, be4, nullptr, nullptr, mx4, NN);
    // output
    k_out<<<dim3(32), dim3(256), 0, stream>>>(mx4, (float*)d_out);
}

// Round 7
// 730.669 us; speedup vs baseline: 5.9912x; 1.1258x over previous
//
#include <hip/hip_runtime.h>
#include <stdint.h>

#define TT 4
#define BB 8
#define NN 2048
#define KNB 16
#define PP (NN*KNB)
#define VTH 1.0f
#define EPSB 1e-5f

typedef unsigned long long u64;
typedef unsigned int u32;
typedef unsigned short u16;
typedef unsigned char u8;
typedef __attribute__((ext_vector_type(8))) short short8;
typedef __attribute__((ext_vector_type(4))) float f4;

#define GLOAD_LDS16(g, l) __builtin_amdgcn_global_load_lds( \
    (const __attribute__((address_space(1))) u32*)(g), \
    (__attribute__((address_space(3))) u32*)(l), 16, 0, 0)

__device__ __forceinline__ float lif_step(float& v, float x) {
    v = v + (x - v) / 2.0f;
    float s = (v - VTH >= 0.0f) ? 1.0f : 0.0f;
    v = v * (1.0f - s);
    return s;
}

// ---------------- T-Net ----------------
__global__ __launch_bounds__(256) void k_tnet1(const float* __restrict__ x, const float* __restrict__ w,
        const float* __restrict__ bi, u64* __restrict__ s1b) {
    int i = blockIdx.x*256 + threadIdx.x;
    int b = i >> 11, n = i & 2047;
    float p0 = x[((size_t)b*14+0)*NN+n];
    float p1 = x[((size_t)b*14+1)*NN+n];
    float p2 = x[((size_t)b*14+2)*NN+n];
    u64 m[TT] = {0,0,0,0};
    for (int d = 0; d < 64; ++d) {
        float z = ((w[d*3+0]*p0 + w[d*3+1]*p1) + w[d*3+2]*p2) + bi[d];
        float v = 0.f;
        #pragma unroll
        for (int t = 0; t < TT; ++t) {
            float s = lif_step(v, z);
            if (s != 0.f) m[t] |= (1ull << d);
        }
    }
    #pragma unroll
    for (int t = 0; t < TT; ++t) s1b[((size_t)t*BB + b)*NN + n] = m[t];
}

// conv2: 64->128, split over 4 channel-chunks of 32 for occupancy
__global__ __launch_bounds__(256) void k_tnet2(const u64* __restrict__ s1b, const float* __restrict__ w,
        const float* __restrict__ bi, u32* __restrict__ s2b32) {
    __shared__ float ws[32*64];
    int tid = threadIdx.x;
    int ec = blockIdx.y;
    for (int l = tid; l < 32*64; l += 256) ws[l] = w[ec*32*64 + l];
    __syncthreads();
    int i = blockIdx.x*256 + tid;
    int b = i >> 11, n = i & 2047;
    u64 m[TT];
    #pragma unroll
    for (int t = 0; t < TT; ++t) m[t] = s1b[((size_t)t*BB+b)*NN+n];
    u32 o[TT] = {0,0,0,0};
    for (int el = 0; el < 32; ++el) {
        float z[TT] = {0.f,0.f,0.f,0.f};
        #pragma unroll 8
        for (int d = 0; d < 64; ++d) {
            float wv = ws[el*64+d];
            #pragma unroll
            for (int t = 0; t < TT; ++t) z[t] += ((m[t]>>d)&1ull) ? wv : 0.f;
        }
        float v = 0.f, bb = bi[ec*32 + el];
        #pragma unroll
        for (int t = 0; t < TT; ++t) {
            float s = lif_step(v, z[t] + bb);
            if (s != 0.f) o[t] |= (1u << el);
        }
    }
    #pragma unroll
    for (int t = 0; t < TT; ++t)
        s2b32[(((size_t)t*BB+b)*NN+n)*4 + ec] = o[t];
}

// FC head, wave-parallel: fc1 one wave per (f,b); 16-chunk lane-split dot + butterfly reduce
__global__ __launch_bounds__(64) void k_fc1(const u32* __restrict__ mx, const float* __restrict__ fw1,
        const float* __restrict__ fb1, float* __restrict__ h1v) {
    int f = blockIdx.x, b = blockIdx.y, lane = threadIdx.x;
    float wr[16];
    #pragma unroll
    for (int j = 0; j < 16; ++j) wr[j] = fw1[(size_t)f*1024 + j*64 + lane];
    float z[TT];
    #pragma unroll
    for (int t = 0; t < TT; ++t) {
        float s = 0.f;
        #pragma unroll
        for (int j = 0; j < 16; ++j)
            s += wr[j] * (float)mx[((size_t)t*BB+b)*1024 + j*64 + lane];
        #pragma unroll
        for (int o = 1; o < 64; o <<= 1) s += __shfl_xor(s, o, 64);
        z[t] = s;
    }
    if (lane == 0) {
        float v = 0.f;
        #pragma unroll
        for (int t = 0; t < TT; ++t)
            h1v[((size_t)t*BB+b)*512 + f] = lif_step(v, z[t] + fb1[f]);
    }
}

__global__ __launch_bounds__(64) void k_fc2(const float* __restrict__ h1v, const float* __restrict__ fw2,
        const float* __restrict__ fb2, float* __restrict__ h2v) {
    int f = blockIdx.x, b = blockIdx.y, lane = threadIdx.x;
    float wr[8];
    #pragma unroll
    for (int j = 0; j < 8; ++j) wr[j] = fw2[(size_t)f*512 + j*64 + lane];
    float z[TT];
    #pragma unroll
    for (int t = 0; t < TT; ++t) {
        float s = 0.f;
        #pragma unroll
        for (int j = 0; j < 8; ++j)
            s += wr[j] * h1v[((size_t)t*BB+b)*512 + j*64 + lane];
        #pragma unroll
        for (int o = 1; o < 64; o <<= 1) s += __shfl_xor(s, o, 64);
        z[t] = s;
    }
    if (lane == 0) {
        float v = 0.f;
        #pragma unroll
        for (int t = 0; t < TT; ++t)
            h2v[((size_t)t*BB+b)*256 + f] = lif_step(v, z[t] + fb2[f]);
    }
}

__global__ __launch_bounds__(64) void k_fc3(const float* __restrict__ h2v, const float* __restrict__ fw3,
        const float* __restrict__ fb3, float* __restrict__ trans) {
    __shared__ float h3s[TT][9];
    int b = blockIdx.x, tid = threadIdx.x;
    if (tid < TT*9) {
        int t = tid/9, oo = tid%9;
        float z = 0.f;
        for (int c = 0; c < 256; ++c) z += fw3[oo*256+c]*h2v[((size_t)t*BB+b)*256 + c];
        h3s[t][oo] = z + fb3[oo];
    }
    __syncthreads();
    if (tid < 9) {
        float m = ((h3s[0][tid]+h3s[1][tid]) + (h3s[2][tid]+h3s[3][tid])) * 0.25f;
        int c = tid/3, dd = tid%3;
        trans[b*9+tid] = m + ((c==dd)?1.0f:0.0f);
    }
}

// apply transform; also emit packed float4 (x,y,z,sq) for KNN
__global__ __launch_bounds__(256) void k_trans(const float* __restrict__ x, const float* __restrict__ tr,
        float* __restrict__ xa, float4* __restrict__ xa4) {
    int i = blockIdx.x*256 + threadIdx.x;
    int b = i >> 11, n = i & 2047;
    float p0 = x[((size_t)b*14+0)*NN+n];
    float p1 = x[((size_t)b*14+1)*NN+n];
    float p2 = x[((size_t)b*14+2)*NN+n];
    const float* tb = tr + b*9;
    float a0 = (p0*tb[0] + p1*tb[3]) + p2*tb[6];
    float a1 = (p0*tb[1] + p1*tb[4]) + p2*tb[7];
    float a2 = (p0*tb[2] + p1*tb[5]) + p2*tb[8];
    xa[((size_t)b*14+0)*NN+n] = a0;
    xa[((size_t)b*14+1)*NN+n] = a1;
    xa[((size_t)b*14+2)*NN+n] = a2;
    for (int c = 3; c < 14; ++c) xa[((size_t)b*14+c)*NN+n] = x[((size_t)b*14+c)*NN+n];
    float4 p;
    p.x = a0; p.y = a1; p.z = a2;
    p.w = (a0*a0 + a1*a1) + a2*a2;
    xa4[(size_t)b*NN+n] = p;
}

// KNN: one wave per query point
__global__ __launch_bounds__(256) void k_knn(const float4* __restrict__ xa4, int* __restrict__ idx) {
    int wave = threadIdx.x >> 6, lane = threadIdx.x & 63;
    int b = blockIdx.y;
    int n = blockIdx.x*4 + wave;
    const float4* P = xa4 + (size_t)b*NN;
    float4 q = P[n];
    float sn = q.w;
    float vals[32];
    #pragma unroll
    for (int j = 0; j < 32; ++j) {
        float4 p = P[j*64 + lane];
        float inner = (q.x*p.x + q.y*p.y) + q.z*p.z;
        vals[j] = (2.0f*inner - sn) - p.w;
    }
    for (int k = 0; k < KNB; ++k) {
        float bv = -3.4e38f; int bj = 0;
        #pragma unroll
        for (int j = 0; j < 32; ++j) if (vals[j] > bv) { bv = vals[j]; bj = j; }
        int bm = bj*64 + lane;
        u32 fb = __float_as_uint(bv);
        fb = (fb & 0x80000000u) ? ~fb : (fb | 0x80000000u);
        u64 key = ((u64)fb << 32) | (u32)(~bm);
        #pragma unroll
        for (int o2 = 1; o2 < 64; o2 <<= 1) {
            u64 other = __shfl_xor(key, o2, 64);
            key = (other > key) ? other : key;
        }
        int wm = (int)(~(u32)key);
        if (lane == 0) idx[((size_t)b*NN + n)*KNB + k] = wm;
        int wl = wm & 63, wj = wm >> 6;
        if (lane == wl) {
            #pragma unroll
            for (int j = 0; j < 32; ++j) if (j == wj) vals[j] = -3.4e38f;
        }
    }
}

__global__ __launch_bounds__(256) void k_gfeat(const float* __restrict__ xa, const int* __restrict__ idx, float* __restrict__ gf) {
    int i = blockIdx.x*256 + threadIdx.x;
    int b = i >> 15;
    int r = i & 32767;
    int n = r >> 4;
    int mm = idx[((size_t)b*NN+n)*KNB + (r & 15)];
    size_t pbase = (size_t)b*28*PP + r;
    #pragma unroll
    for (int c = 0; c < 14; ++c) {
        float ctr = xa[((size_t)b*14+c)*NN + n];
        float nb  = xa[((size_t)b*14+c)*NN + mm];
        gf[pbase + (size_t)c*PP] = ctr;
        gf[pbase + (size_t)(14+c)*PP] = nb - ctr;
    }
}

// edge conv1 stats partials
__global__ __launch_bounds__(256) void k_estats1(const float* __restrict__ gf, const float* __restrict__ w1, float* __restrict__ part1) {
    __shared__ float gfs[28][256];
    __shared__ float w1s[64*28];
    __shared__ float wsum[4][64], wsq[4][64];
    int pt = blockIdx.x, b = blockIdx.y;
    int p0 = pt*256, tid = threadIdx.x;
    for (int l = tid; l < 28*256; l += 256) gfs[l>>8][l&255] = gf[((size_t)b*28 + (l>>8))*PP + p0 + (l&255)];
    for (int l = tid; l < 64*28; l += 256) w1s[l] = w1[l];
    __syncthreads();
    int wv = tid>>6, lane = tid&63;
    for (int d = 0; d < 64; ++d) {
        float z = 0.f;
        #pragma unroll
        for (int c = 0; c < 28; ++c) z += w1s[d*28+c]*gfs[c][tid];
        float s = z, q = z*z;
        #pragma unroll
        for (int o = 1; o < 64; o <<= 1) { s += __shfl_xor(s, o, 64); q += __shfl_xor(q, o, 64); }
        if (lane == 0) { wsum[wv][d] = s; wsq[wv][d] = q; }
    }
    __syncthreads();
    if (tid < 64) {
        float s = (wsum[0][tid]+wsum[1][tid])+(wsum[2][tid]+wsum[3][tid]);
        float q = (wsq[0][tid]+wsq[1][tid])+(wsq[2][tid]+wsq[3][tid]);
        size_t blk = (size_t)b*128 + pt;
        part1[(blk*64 + tid)*2+0] = s;
        part1[(blk*64 + tid)*2+1] = q;
    }
}

__global__ __launch_bounds__(256) void k_reduce(const float* __restrict__ part, float* __restrict__ stats, int nch, int nblk, double M) {
    __shared__ double sred[256], qred[256];
    int ch = blockIdx.x, tid = threadIdx.x;
    double s = 0.0, q = 0.0;
    for (int i = tid; i < nblk; i += 256) {
        s += (double)part[((size_t)i*nch + ch)*2 + 0];
        q += (double)part[((size_t)i*nch + ch)*2 + 1];
    }
    sred[tid] = s; qred[tid] = q;
    __syncthreads();
    for (int off = 128; off > 0; off >>= 1) {
        if (tid < off) { sred[tid] += sred[tid+off]; qred[tid] += qred[tid+off]; }
        __syncthreads();
    }
    if (tid == 0) {
        double mu = sred[0] / M;
        double var = qred[0] / M - mu*mu;
        if (var < 0.0) var = 0.0;
        stats[ch*2+0] = (float)mu;
        stats[ch*2+1] = 1.0f / sqrtf((float)var + EPSB);
    }
}

// edge conv1 apply: norm+LIF -> h1b (channel-major bits) + h1n (u64 mask per point)
__global__ __launch_bounds__(256) void k_h1(const float* __restrict__ gf, const float* __restrict__ w1,
        const float* __restrict__ st1, const float* __restrict__ g1, const float* __restrict__ be1,
        u64* __restrict__ h1b, u64* __restrict__ h1n) {
    __shared__ float w1s[64*28];
    int tid = threadIdx.x;
    int b = blockIdx.y;
    int p0 = blockIdx.x*256;
    int p = p0 + tid;
    for (int l = tid; l < 64*28; l += 256) w1s[l] = w1[l];
    __syncthreads();
    float gr[28];
    #pragma unroll
    for (int c = 0; c < 28; ++c) gr[c] = gf[((size_t)b*28 + c)*PP + p];
    int wordbase = (p0>>6) + (tid>>6);
    u64 pm[TT] = {0,0,0,0};
    for (int d = 0; d < 64; ++d) {
        float z = 0.f;
        #pragma unroll
        for (int c = 0; c < 28; ++c) z += w1s[d*28+c]*gr[c];
        float mu = st1[d*2+0], iv = st1[d*2+1];
        float v = 0.f;
        #pragma unroll
        for (int t = 0; t < TT; ++t) {
            float y = (z - mu) * iv * g1[t*64+d] + be1[t*64+d];
            float s = lif_step(v, y);
            u64 m = __ballot(s != 0.f);
            if ((tid & 63) == 0) h1b[((size_t)(t*BB+b)*64 + d)*512 + wordbase] = m;
            pm[t] |= ((u64)(s != 0.f)) << d;
        }
    }
    #pragma unroll
    for (int t = 0; t < TT; ++t) h1n[(size_t)(t*BB+b)*PP + p] = pm[t];
}

// ---------------- Tiled popcount Grams (exact int counts) ----------------
__global__ __launch_bounds__(256) void k_gram_h1(const u64* __restrict__ h1b, int* __restrict__ Mi) {
    __shared__ u64 tw[64*65];
    int tid = threadIdx.x;
    int w0 = blockIdx.x*64;
    int tb = blockIdx.y;
    int t = tb >> 3;
    const u64* src = h1b + (size_t)tb*64*512;
    for (int l = tid; l < 64*64; l += 256) {
        int c = l >> 6, w = l & 63;
        tw[c*65+w] = src[(size_t)c*512 + w0 + w];
    }
    __syncthreads();
    int q = tid >> 4, r = tid & 15;
    int acc[4][4];
    #pragma unroll
    for (int i=0;i<4;++i)
        #pragma unroll
        for (int j=0;j<4;++j) acc[i][j]=0;
    #pragma unroll 4
    for (int w = 0; w < 64; ++w) {
        u64 av[4], bv[4];
        #pragma unroll
        for (int i=0;i<4;++i) av[i] = tw[(q+16*i)*65+w];
        #pragma unroll
        for (int j=0;j<4;++j) bv[j] = tw[(r+16*j)*65+w];
        #pragma unroll
        for (int i=0;i<4;++i)
            #pragma unroll
            for (int j=0;j<4;++j) acc[i][j] += (int)__popcll(av[i]&bv[j]);
    }
    #pragma unroll
    for (int i=0;i<4;++i)
        #pragma unroll
        for (int j=0;j<4;++j)
            atomicAdd(&Mi[((size_t)t*64 + q+16*i)*64 + r+16*j], acc[i][j]);
}

template<int C>
__global__ __launch_bounds__(256) void k_gram2(const u64* __restrict__ bits, int* __restrict__ Mi) {
    __shared__ u64 ta[64*33], tbt[64*33];
    int tid = threadIdx.x;
    int ci0 = blockIdx.x*64, cj0 = blockIdx.y*64;
    int tb = blockIdx.z;
    int t = tb >> 3;
    const u64* srcA = bits + ((size_t)tb*C + ci0)*32;
    const u64* srcB = bits + ((size_t)tb*C + cj0)*32;
    for (int l = tid; l < 64*32; l += 256) {
        int rr = l >> 5, w = l & 31;
        ta[rr*33+w]  = srcA[(size_t)rr*32+w];
        tbt[rr*33+w] = srcB[(size_t)rr*32+w];
    }
    __syncthreads();
    int q = tid >> 4, r = tid & 15;
    int acc[4][4];
    #pragma unroll
    for (int i=0;i<4;++i)
        #pragma unroll
        for (int j=0;j<4;++j) acc[i][j]=0;
    #pragma unroll 4
    for (int w = 0; w < 32; ++w) {
        u64 av[4], bv[4];
        #pragma unroll
        for (int i=0;i<4;++i) av[i] = ta[(q+16*i)*33+w];
        #pragma unroll
        for (int j=0;j<4;++j) bv[j] = tbt[(r+16*j)*33+w];
        #pragma unroll
        for (int i=0;i<4;++i)
            #pragma unroll
            for (int j=0;j<4;++j) acc[i][j] += (int)__popcll(av[i]&bv[j]);
    }
    #pragma unroll
    for (int i=0;i<4;++i)
        #pragma unroll
        for (int j=0;j<4;++j)
            atomicAdd(&Mi[((size_t)t*C + ci0+q+16*i)*C + cj0+r+16*j], acc[i][j]);
}

// project int Gram through weights -> per-(t,ch) (mean, inv_std)
template<int CIN>
__global__ void k_proj(const int* __restrict__ Mf, const float* __restrict__ w,
        float* __restrict__ st, int COUT, double cnt) {
    __shared__ double z2s[256], mns[256];
    int ch = blockIdx.x, t = blockIdx.y, c2 = threadIdx.x;
    const int* Mt = Mf + (size_t)t*CIN*CIN;
    double y = 0.0;
    for (int c = 0; c < CIN; ++c)
        y += (double)w[(size_t)ch*CIN+c] * (double)Mt[(size_t)c*CIN + c2];
    double wc2 = (double)w[(size_t)ch*CIN+c2];
    z2s[c2] = wc2 * y;
    mns[c2] = wc2 * (double)Mt[(size_t)c2*CIN + c2];
    __syncthreads();
    for (int off = CIN>>1; off > 0; off >>= 1) {
        if (c2 < off) { z2s[c2] += z2s[c2+off]; mns[c2] += mns[c2+off]; }
        __syncthreads();
    }
    if (c2 == 0) {
        double mu = mns[0] / cnt;
        double var = z2s[0] / cnt - mu*mu;
        if (var < 0.0) var = 0.0;
        st[((size_t)t*COUT+ch)*2+0] = (float)mu;
        st[((size_t)t*COUT+ch)*2+1] = 1.0f / sqrtf((float)var + EPSB);
    }
}

// weight prep: fp32 w[F][K] -> exact 3-way bf16 split in MFMA-frag layout [K/8][F][8]
__global__ __launch_bounds__(256) void k_wprep(const float* __restrict__ w,
        short* __restrict__ hi, short* __restrict__ mid, short* __restrict__ lo, int F, int K) {
    int i = blockIdx.x*256 + threadIdx.x;
    if (i >= F*K) return;
    int f = i / K, k = i % K;
    float wv = w[i];
    u32 b0 = __float_as_uint(wv);
    float h = __uint_as_float(b0 & 0xFFFF0000u);
    float r1 = wv - h;
    u32 b1 = __float_as_uint(r1);
    float m = __uint_as_float(b1 & 0xFFFF0000u);
    float r2 = r1 - m;
    u32 b2 = __float_as_uint(r2);
    size_t o = ((size_t)(k>>3)*F + f)*8 + (k&7);
    hi[o]  = (short)(b0 >> 16);
    mid[o] = (short)(b1 >> 16);
    lo[o]  = (short)(b2 >> 16);
}

// ---------------- MFMA spike conv (KT=64 LDS weight tiles + LUT A-expansion) ----------------
template<int K, int F, int MODE, bool BITS>
__global__ __launch_bounds__(256) void k_mconv(
        const void* __restrict__ Asrc,
        const short* __restrict__ Whi, const short* __restrict__ Wmd, const short* __restrict__ Wlo,
        const float* __restrict__ st, const float* __restrict__ ga, const float* __restrict__ be,
        const float* __restrict__ bias,
        u16* __restrict__ outp, u32* __restrict__ outm, int NPTS) {
    constexpr int KT = 64;
    constexpr int ROWS = (KT/8)*3;          // 24 rows of 1KB: [kq][split][64f][8]
    constexpr int NW = (K+63)/64;
    __shared__ short wsm[ROWS*512];
    __shared__ short sptab[BITS ? 256*8 : 8];
    __shared__ u32 morr[TT][64];
    int tid = threadIdx.x;
    int wave = tid >> 6, lane = tid & 63;
    int l15 = lane & 15, lg = lane >> 4;
    int b = blockIdx.z;
    int n_base = blockIdx.x*64 + wave*16;
    int f0 = blockIdx.y*64;
    if (MODE == 0 || MODE == 2)
        for (int l = tid; l < TT*64; l += 256) morr[l>>6][l&63] = 0u;
    if (BITS) {
        #pragma unroll
        for (int j = 0; j < 8; ++j) sptab[tid*8+j] = (short)(((tid>>j)&1) * 0x3F80);
    }

    f4 acc[4][TT];
    #pragma unroll
    for (int i = 0; i < 4; ++i)
        #pragma unroll
        for (int t = 0; t < TT; ++t) acc[i][t] = (f4)0.f;

    u64 aw[TT][NW];
    const u16* Au[TT];
    #pragma unroll
    for (int t = 0; t < TT; ++t) {
        if (BITS) {
            const u64* Ab = (const u64*)Asrc + ((size_t)(t*BB+b)*NPTS + n_base + l15)*NW;
            #pragma unroll
            for (int wq = 0; wq < NW; ++wq) aw[t][wq] = Ab[wq];
        } else {
            Au[t] = (const u16*)Asrc + ((size_t)(t*BB+b)*NPTS + n_base + l15)*K + lg*8;
        }
    }
    const short* Wsrc[3] = {Whi, Wmd, Wlo};

    #pragma unroll
    for (int kt = 0; kt < K; kt += KT) {
        if (kt > 0) __syncthreads();
        #pragma unroll
        for (int r = wave; r < ROWS; r += 4) {
            int kq = r/3, s = r - kq*3;
            const short* g = Wsrc[s] + ((size_t)((kt>>3) + kq)*F + f0)*8 + lane*8;
            GLOAD_LDS16(g, &wsm[r*512]);
        }
        __syncthreads();
        #pragma unroll
        for (int k0 = 0; k0 < KT; k0 += 32) {
            int kg = kt + k0;
            short8 a[TT];
            #pragma unroll
            for (int t = 0; t < TT; ++t) {
                if (BITS) {
                    u32 byte = (u32)(aw[t][kg>>6] >> ((kg&63) + lg*8)) & 0xFFu;
                    a[t] = *(const short8*)(sptab + byte*8);
                } else {
                    a[t] = *(const short8*)(Au[t] + kg);
                }
            }
            int kql = (k0>>3) + lg;
            #pragma unroll
            for (int fs = 0; fs < 4; ++fs) {
                const short* base = wsm + kql*1536 + (fs*16+l15)*8;
                short8 whi = *(const short8*)(base);
                short8 wmd = *(const short8*)(base + 512);
                short8 wlo = *(const short8*)(base + 1024);
                #pragma unroll
                for (int t = 0; t < TT; ++t) {
                    acc[fs][t] = __builtin_amdgcn_mfma_f32_16x16x32_bf16(a[t], whi, acc[fs][t], 0, 0, 0);
                    acc[fs][t] = __builtin_amdgcn_mfma_f32_16x16x32_bf16(a[t], wmd, acc[fs][t], 0, 0, 0);
                    acc[fs][t] = __builtin_amdgcn_mfma_f32_16x16x32_bf16(a[t], wlo, acc[fs][t], 0, 0, 0);
                }
            }
        }
    }
    if (MODE == 1) {
        #pragma unroll
        for (int fs = 0; fs < 4; ++fs) {
            int f = f0 + fs*16 + l15;
            #pragma unroll
            for (int reg = 0; reg < 4; ++reg) {
                int n = n_base + lg*4 + reg;
                float v = 0.f;
                #pragma unroll
                for (int t = 0; t < TT; ++t) {
                    int ch = t*F + f;
                    float y = (acc[fs][t][reg] - st[(size_t)ch*2+0])*st[(size_t)ch*2+1]*ga[ch] + be[ch];
                    float s = lif_step(v, y);
                    outp[((size_t)(t*BB+b)*NPTS + n)*F + f] = (s != 0.f) ? (u16)0x3F80 : (u16)0;
                }
            }
        }
    } else if (MODE == 3) {
        #pragma unroll
        for (int fs = 0; fs < 4; ++fs) {
            int f = f0 + fs*16 + l15;
            u32 nib = 0u;
            #pragma unroll
            for (int reg = 0; reg < 4; ++reg) {
                float v = 0.f;
                #pragma unroll
                for (int t = 0; t < TT; ++t) {
                    int ch = t*F + f;
                    float y = (acc[fs][t][reg] - st[(size_t)ch*2+0])*st[(size_t)ch*2+1]*ga[ch] + be[ch];
                    float s = lif_step(v, y);
                    if (s != 0.f) nib |= (1u << t);
                }
            }
            nib |= __shfl_xor(nib, 16, 64);
            nib |= __shfl_xor(nib, 32, 64);
            if (lg == 0) {
                int n_pt = n_base >> 4;
                #pragma unroll
                for (int t = 0; t < TT; ++t)
                    outp[((size_t)(t*BB+b)*(NPTS>>4) + n_pt)*F + f] = ((nib>>t)&1u) ? (u16)0x3F80 : (u16)0;
            }
        }
    } else {
        #pragma unroll
        for (int fs = 0; fs < 4; ++fs) {
            int f = f0 + fs*16 + l15;
            u32 any[TT] = {0,0,0,0};
            float bb = (MODE == 0) ? bias[f] : 0.f;
            #pragma unroll
            for (int reg = 0; reg < 4; ++reg) {
                float v = 0.f;
                #pragma unroll
                for (int t = 0; t < TT; ++t) {
                    float y;
                    if (MODE == 0) y = acc[fs][t][reg] + bb;
                    else {
                        int ch = t*F + f;
                        y = (acc[fs][t][reg] - st[(size_t)ch*2+0])*st[(size_t)ch*2+1]*ga[ch] + be[ch];
                    }
                    float s = lif_step(v, y);
                    if (s != 0.f) any[t] = 1u;
                }
            }
            #pragma unroll
            for (int t = 0; t < TT; ++t) if (any[t]) atomicOr(&morr[t][fs*16+l15], 1u);
        }
        __syncthreads();
        for (int l = tid; l < TT*64; l += 256)
            if (morr[l>>6][l&63]) atomicOr(&outm[((size_t)((l>>6)*BB+b))*F + f0 + (l&63)], 1u);
    }
}

// repack point-major bf16-u16 spikes [t][b][n][C] -> channel-major bits [t][b][C][32 words over n]
template<int C>
__global__ __launch_bounds__(256) void k_repack(const u16* __restrict__ sp, u64* __restrict__ bits) {
    __shared__ u16 tile[64][C+2];
    int tid = threadIdx.x;
    int nw = blockIdx.x, b = blockIdx.y, t = blockIdx.z;
    const u16* src = sp + ((size_t)(t*BB+b)*NN + nw*64)*C;
    for (int i = tid*2; i < 64*C; i += 512) {
        u32 v = *(const u32*)(src + i);
        int r = i / C, c = i % C;
        *(u32*)&tile[r][c] = v;
    }
    __syncthreads();
    int wave = tid >> 6, lane = tid & 63;
    for (int c = wave; c < C; c += 4) {
        u64 m = __ballot(tile[lane][c] != 0);
        if (lane == 0) bits[((size_t)(t*BB+b)*C + c)*32 + nw] = m;
    }
}

__global__ __launch_bounds__(256) void k_out(const u32* __restrict__ mx4, float* __restrict__ out) {
    int i = blockIdx.x*256 + threadIdx.x;
    int b = i >> 10, g = i & 1023;
    float s = (float)(mx4[((size_t)0*BB+b)*1024+g] + mx4[((size_t)1*BB+b)*1024+g]
                    + mx4[((size_t)2*BB+b)*1024+g] + mx4[((size_t)3*BB+b)*1024+g]);
    out[i] = s * 0.25f;
}

extern "C" void kernel_launch(void* const* d_in, const int* in_sizes, int n_in,
                              void* d_out, int out_size, void* d_ws, size_t ws_size,
                              hipStream_t stream) {
    (void)in_sizes; (void)n_in; (void)out_size;
    const float* x    = (const float*)d_in[0];
    const float* tw1  = (const float*)d_in[1];
    const float* tb1  = (const float*)d_in[2];
    const float* tw2  = (const float*)d_in[3];
    const float* tb2  = (const float*)d_in[4];
    const float* tw3  = (const float*)d_in[5];
    const float* tb3  = (const float*)d_in[6];
    const float* tfw1 = (const float*)d_in[7];
    const float* tfb1 = (const float*)d_in[8];
    const float* tfw2 = (const float*)d_in[9];
    const float* tfb2 = (const float*)d_in[10];
    const float* tfw3 = (const float*)d_in[11];
    const float* tfb3 = (const float*)d_in[12];
    const float* w1   = (const float*)d_in[13];
    const float* w2   = (const float*)d_in[14];
    const float* w3   = (const float*)d_in[15];
    const float* w4   = (const float*)d_in[16];
    const float* g1   = (const float*)d_in[17];
    const float* be1  = (const float*)d_in[18];
    const float* g2   = (const float*)d_in[19];
    const float* be2  = (const float*)d_in[20];
    const float* g3   = (const float*)d_in[21];
    const float* be3  = (const float*)d_in[22];
    const float* g4   = (const float*)d_in[23];
    const float* be4  = (const float*)d_in[24];

    char* wsb = (char*)d_ws;
    size_t off = 0;
    auto alloc = [&](size_t bytes) -> void* {
        void* p = wsb + off;
        off = (off + bytes + 255) & ~(size_t)255;
        return p;
    };
    u64* s1b   = (u64*)alloc(sizeof(u64)*(size_t)TT*BB*NN);
    u64* s2b   = (u64*)alloc(sizeof(u64)*(size_t)TT*BB*NN*2);
    u32* mx    = (u32*)alloc(sizeof(u32)*(size_t)TT*BB*1024);
    u32* mx4   = (u32*)alloc(sizeof(u32)*(size_t)TT*BB*1024);
    float* trs = (float*)alloc(sizeof(float)*BB*9);
    float* xa  = (float*)alloc(sizeof(float)*(size_t)BB*14*NN);
    float4* xa4 = (float4*)alloc(sizeof(float4)*(size_t)BB*NN);
    int* idx   = (int*)alloc(sizeof(int)*(size_t)BB*NN*KNB);
    float* gf  = (float*)alloc(sizeof(float)*(size_t)BB*28*PP);
    float* part1 = (float*)alloc(sizeof(float)*(size_t)1024*64*2);
    float* st1 = (float*)alloc(sizeof(float)*64*2);
    float* st2 = (float*)alloc(sizeof(float)*512*2);
    float* st3 = (float*)alloc(sizeof(float)*1024*2);
    float* st4 = (float*)alloc(sizeof(float)*4096*2);
    float* h1v = (float*)alloc(sizeof(float)*(size_t)TT*BB*512);
    float* h2v = (float*)alloc(sizeof(float)*(size_t)TT*BB*256);
    u64* h1b = (u64*)alloc(sizeof(u64)*(size_t)TT*BB*64*512);
    u64* h1n = (u64*)alloc(sizeof(u64)*(size_t)TT*BB*PP);
    u16* m2p = (u16*)alloc(sizeof(u16)*(size_t)TT*BB*NN*128);
    u16* h3p = (u16*)alloc(sizeof(u16)*(size_t)TT*BB*NN*256);
    u64* m2b = (u64*)alloc(sizeof(u64)*(size_t)TT*BB*128*32);
    u64* h3b = (u64*)alloc(sizeof(u64)*(size_t)TT*BB*256*32);
    int* Mi64  = (int*)alloc(sizeof(int)*(size_t)TT*64*64);
    int* Mi128 = (int*)alloc(sizeof(int)*(size_t)TT*128*128);
    int* Mi256 = (int*)alloc(sizeof(int)*(size_t)TT*256*256);
    short* wp2h = (short*)alloc(sizeof(short)*(size_t)128*64);
    short* wp2m = (short*)alloc(sizeof(short)*(size_t)128*64);
    short* wp2l = (short*)alloc(sizeof(short)*(size_t)128*64);
    short* wp3h = (short*)alloc(sizeof(short)*(size_t)256*128);
    short* wp3m = (short*)alloc(sizeof(short)*(size_t)256*128);
    short* wp3l = (short*)alloc(sizeof(short)*(size_t)256*128);
    short* wp4h = (short*)alloc(sizeof(short)*(size_t)1024*256);
    short* wp4m = (short*)alloc(sizeof(short)*(size_t)1024*256);
    short* wp4l = (short*)alloc(sizeof(short)*(size_t)1024*256);
    short* wpth = (short*)alloc(sizeof(short)*(size_t)1024*128);
    short* wptm = (short*)alloc(sizeof(short)*(size_t)1024*128);
    short* wptl = (short*)alloc(sizeof(short)*(size_t)1024*128);
    if (off > ws_size) return;

    hipMemsetAsync(mx, 0, sizeof(u32)*(size_t)TT*BB*1024, stream);
    hipMemsetAsync(mx4, 0, sizeof(u32)*(size_t)TT*BB*1024, stream);
    hipMemsetAsync(Mi64, 0, sizeof(int)*(size_t)TT*64*64, stream);
    hipMemsetAsync(Mi128, 0, sizeof(int)*(size_t)TT*128*128, stream);
    hipMemsetAsync(Mi256, 0, sizeof(int)*(size_t)TT*256*256, stream);

    // weight prep (exact 3-way bf16 split)
    k_wprep<<<dim3((128*64+255)/256), dim3(256), 0, stream>>>(w2, wp2h, wp2m, wp2l, 128, 64);
    k_wprep<<<dim3((256*128+255)/256), dim3(256), 0, stream>>>(w3, wp3h, wp3m, wp3l, 256, 128);
    k_wprep<<<dim3((1024*256+255)/256), dim3(256), 0, stream>>>(w4, wp4h, wp4m, wp4l, 1024, 256);
    k_wprep<<<dim3((1024*128+255)/256), dim3(256), 0, stream>>>(tw3, wpth, wptm, wptl, 1024, 128);

    // T-Net
    k_tnet1<<<dim3(64), dim3(256), 0, stream>>>(x, tw1, tb1, s1b);
    k_tnet2<<<dim3(64, 4), dim3(256), 0, stream>>>(s1b, tw2, tb2, (u32*)s2b);
    k_mconv<128,1024,0,true><<<dim3(32,16,8), dim3(256), 0, stream>>>(
        s2b, wpth, wptm, wptl, nullptr, nullptr, nullptr, tb3, nullptr, mx, NN);
    k_fc1<<<dim3(512, 8), dim3(64), 0, stream>>>(mx, tfw1, tfb1, h1v);
    k_fc2<<<dim3(256, 8), dim3(64), 0, stream>>>(h1v, tfw2, tfb2, h2v);
    k_fc3<<<dim3(8), dim3(64), 0, stream>>>(h2v, tfw3, tfb3, trs);
    k_trans<<<dim3(64), dim3(256), 0, stream>>>(x, trs, xa, xa4);
    // KNN (wave-per-query) + graph feature
    k_knn<<<dim3(NN/4, BB), dim3(256), 0, stream>>>(xa4, idx);
    k_gfeat<<<dim3((BB*NN*KNB)/256), dim3(256), 0, stream>>>(xa, idx, gf);
    // edge conv1 stats + apply
    k_estats1<<<dim3(128, 8), dim3(256), 0, stream>>>(gf, w1, part1);
    k_reduce<<<dim3(64), dim3(256), 0, stream>>>(part1, st1, 64, 1024, 262144.0);
    k_h1<<<dim3(128, 8), dim3(256), 0, stream>>>(gf, w1, st1, g1, be1, h1b, h1n);
    // edge conv2: stats via tiled Gram, apply via MFMA (+ max over k)
    k_gram_h1<<<dim3(8, TT*BB), dim3(256), 0, stream>>>(h1b, Mi64);
    k_proj<64><<<dim3(128, TT), dim3(64), 0, stream>>>(Mi64, w2, st2, 128, 262144.0);
    k_mconv<64,128,3,true><<<dim3(PP/64,2,8), dim3(256), 0, stream>>>(
        h1n, wp2h, wp2m, wp2l, st2, g2, be2, nullptr, m2p, nullptr, PP);
    k_repack<128><<<dim3(32,8,4), dim3(256), 0, stream>>>(m2p, m2b);
    // conv3
    k_gram2<128><<<dim3(2,2,TT*BB), dim3(256), 0, stream>>>(m2b, Mi128);
    k_proj<128><<<dim3(256, TT), dim3(128), 0, stream>>>(Mi128, w3, st3, 256, 16384.0);
    k_mconv<128,256,1,false><<<dim3(32,4,8), dim3(256), 0, stream>>>(
        m2p, wp3h, wp3m, wp3l, st3, g3, be3, nullptr, h3p, nullptr, NN);
    k_repack<256><<<dim3(32,8,4), dim3(256), 0, stream>>>(h3p, h3b);
    // conv4
    k_gram2<256><<<dim3(4,4,TT*BB), dim3(256), 0, stream>>>(h3b, Mi256);
    k_proj<256><<<dim3(1024, TT), dim3(256), 0, stream>>>(Mi256, w4, st4, 1024, 16384.0);
    k_mconv<256,1024,2,false><<<dim3(32,16,8), dim3(256), 0, stream>>>(
        h3p, wp4h, wp4m, wp4l, st4, g4, be4, nullptr, nullptr, mx4, NN);
    // output
    k_out<<<dim3(32), dim3(256), 0, stream>>>(mx4, (float*)d_out);
}

// Round 8
// 722.334 us; speedup vs baseline: 6.0603x; 1.0115x over previous
//
#include <hip/hip_runtime.h>
#include <stdint.h>

#define TT 4
#define BB 8
#define NN 2048
#define KNB 16
#define PP (NN*KNB)
#define VTH 1.0f
#define EPSB 1e-5f

typedef unsigned long long u64;
typedef unsigned int u32;
typedef unsigned short u16;
typedef unsigned char u8;
typedef __attribute__((ext_vector_type(8))) short short8;
typedef __attribute__((ext_vector_type(4))) float f4;

#define GLOAD_LDS16(g, l) __builtin_amdgcn_global_load_lds( \
    (const __attribute__((address_space(1))) u32*)(g), \
    (__attribute__((address_space(3))) u32*)(l), 16, 0, 0)

__device__ __forceinline__ float lif_step(float& v, float x) {
    v = v + (x - v) / 2.0f;
    float s = (v - VTH >= 0.0f) ? 1.0f : 0.0f;
    v = v * (1.0f - s);
    return s;
}

// ---------------- T-Net ----------------
__global__ __launch_bounds__(256) void k_tnet1(const float* __restrict__ x, const float* __restrict__ w,
        const float* __restrict__ bi, u64* __restrict__ s1b) {
    int i = blockIdx.x*256 + threadIdx.x;
    int b = i >> 11, n = i & 2047;
    float p0 = x[((size_t)b*14+0)*NN+n];
    float p1 = x[((size_t)b*14+1)*NN+n];
    float p2 = x[((size_t)b*14+2)*NN+n];
    u64 m[TT] = {0,0,0,0};
    for (int d = 0; d < 64; ++d) {
        float z = ((w[d*3+0]*p0 + w[d*3+1]*p1) + w[d*3+2]*p2) + bi[d];
        float v = 0.f;
        #pragma unroll
        for (int t = 0; t < TT; ++t) {
            float s = lif_step(v, z);
            if (s != 0.f) m[t] |= (1ull << d);
        }
    }
    #pragma unroll
    for (int t = 0; t < TT; ++t) s1b[((size_t)t*BB + b)*NN + n] = m[t];
}

// conv2: 64->128, split over 4 channel-chunks of 32 for occupancy
__global__ __launch_bounds__(256) void k_tnet2(const u64* __restrict__ s1b, const float* __restrict__ w,
        const float* __restrict__ bi, u32* __restrict__ s2b32) {
    __shared__ float ws[32*64];
    int tid = threadIdx.x;
    int ec = blockIdx.y;
    for (int l = tid; l < 32*64; l += 256) ws[l] = w[ec*32*64 + l];
    __syncthreads();
    int i = blockIdx.x*256 + tid;
    int b = i >> 11, n = i & 2047;
    u64 m[TT];
    #pragma unroll
    for (int t = 0; t < TT; ++t) m[t] = s1b[((size_t)t*BB+b)*NN+n];
    u32 o[TT] = {0,0,0,0};
    for (int el = 0; el < 32; ++el) {
        float z[TT] = {0.f,0.f,0.f,0.f};
        #pragma unroll 8
        for (int d = 0; d < 64; ++d) {
            float wv = ws[el*64+d];
            #pragma unroll
            for (int t = 0; t < TT; ++t) z[t] += ((m[t]>>d)&1ull) ? wv : 0.f;
        }
        float v = 0.f, bb = bi[ec*32 + el];
        #pragma unroll
        for (int t = 0; t < TT; ++t) {
            float s = lif_step(v, z[t] + bb);
            if (s != 0.f) o[t] |= (1u << el);
        }
    }
    #pragma unroll
    for (int t = 0; t < TT; ++t)
        s2b32[(((size_t)t*BB+b)*NN+n)*4 + ec] = o[t];
}

// FC head, wave-parallel
__global__ __launch_bounds__(64) void k_fc1(const u32* __restrict__ mx, const float* __restrict__ fw1,
        const float* __restrict__ fb1, float* __restrict__ h1v) {
    int f = blockIdx.x, b = blockIdx.y, lane = threadIdx.x;
    float wr[16];
    #pragma unroll
    for (int j = 0; j < 16; ++j) wr[j] = fw1[(size_t)f*1024 + j*64 + lane];
    float z[TT];
    #pragma unroll
    for (int t = 0; t < TT; ++t) {
        float s = 0.f;
        #pragma unroll
        for (int j = 0; j < 16; ++j)
            s += wr[j] * (float)mx[((size_t)t*BB+b)*1024 + j*64 + lane];
        #pragma unroll
        for (int o = 1; o < 64; o <<= 1) s += __shfl_xor(s, o, 64);
        z[t] = s;
    }
    if (lane == 0) {
        float v = 0.f;
        #pragma unroll
        for (int t = 0; t < TT; ++t)
            h1v[((size_t)t*BB+b)*512 + f] = lif_step(v, z[t] + fb1[f]);
    }
}

__global__ __launch_bounds__(64) void k_fc2(const float* __restrict__ h1v, const float* __restrict__ fw2,
        const float* __restrict__ fb2, float* __restrict__ h2v) {
    int f = blockIdx.x, b = blockIdx.y, lane = threadIdx.x;
    float wr[8];
    #pragma unroll
    for (int j = 0; j < 8; ++j) wr[j] = fw2[(size_t)f*512 + j*64 + lane];
    float z[TT];
    #pragma unroll
    for (int t = 0; t < TT; ++t) {
        float s = 0.f;
        #pragma unroll
        for (int j = 0; j < 8; ++j)
            s += wr[j] * h1v[((size_t)t*BB+b)*512 + j*64 + lane];
        #pragma unroll
        for (int o = 1; o < 64; o <<= 1) s += __shfl_xor(s, o, 64);
        z[t] = s;
    }
    if (lane == 0) {
        float v = 0.f;
        #pragma unroll
        for (int t = 0; t < TT; ++t)
            h2v[((size_t)t*BB+b)*256 + f] = lif_step(v, z[t] + fb2[f]);
    }
}

__global__ __launch_bounds__(64) void k_fc3(const float* __restrict__ h2v, const float* __restrict__ fw3,
        const float* __restrict__ fb3, float* __restrict__ trans) {
    __shared__ float h3s[TT][9];
    int b = blockIdx.x, tid = threadIdx.x;
    if (tid < TT*9) {
        int t = tid/9, oo = tid%9;
        float z = 0.f;
        for (int c = 0; c < 256; ++c) z += fw3[oo*256+c]*h2v[((size_t)t*BB+b)*256 + c];
        h3s[t][oo] = z + fb3[oo];
    }
    __syncthreads();
    if (tid < 9) {
        float m = ((h3s[0][tid]+h3s[1][tid]) + (h3s[2][tid]+h3s[3][tid])) * 0.25f;
        int c = tid/3, dd = tid%3;
        trans[b*9+tid] = m + ((c==dd)?1.0f:0.0f);
    }
}

// apply transform; also emit packed float4 (x,y,z,sq) for KNN
__global__ __launch_bounds__(256) void k_trans(const float* __restrict__ x, const float* __restrict__ tr,
        float* __restrict__ xa, float4* __restrict__ xa4) {
    int i = blockIdx.x*256 + threadIdx.x;
    int b = i >> 11, n = i & 2047;
    float p0 = x[((size_t)b*14+0)*NN+n];
    float p1 = x[((size_t)b*14+1)*NN+n];
    float p2 = x[((size_t)b*14+2)*NN+n];
    const float* tb = tr + b*9;
    float a0 = (p0*tb[0] + p1*tb[3]) + p2*tb[6];
    float a1 = (p0*tb[1] + p1*tb[4]) + p2*tb[7];
    float a2 = (p0*tb[2] + p1*tb[5]) + p2*tb[8];
    xa[((size_t)b*14+0)*NN+n] = a0;
    xa[((size_t)b*14+1)*NN+n] = a1;
    xa[((size_t)b*14+2)*NN+n] = a2;
    for (int c = 3; c < 14; ++c) xa[((size_t)b*14+c)*NN+n] = x[((size_t)b*14+c)*NN+n];
    float4 p;
    p.x = a0; p.y = a1; p.z = a2;
    p.w = (a0*a0 + a1*a1) + a2*a2;
    xa4[(size_t)b*NN+n] = p;
}

// KNN: one wave per query point
__global__ __launch_bounds__(256) void k_knn(const float4* __restrict__ xa4, int* __restrict__ idx) {
    int wave = threadIdx.x >> 6, lane = threadIdx.x & 63;
    int b = blockIdx.y;
    int n = blockIdx.x*4 + wave;
    const float4* P = xa4 + (size_t)b*NN;
    float4 q = P[n];
    float sn = q.w;
    float vals[32];
    #pragma unroll
    for (int j = 0; j < 32; ++j) {
        float4 p = P[j*64 + lane];
        float inner = (q.x*p.x + q.y*p.y) + q.z*p.z;
        vals[j] = (2.0f*inner - sn) - p.w;
    }
    for (int k = 0; k < KNB; ++k) {
        float bv = -3.4e38f; int bj = 0;
        #pragma unroll
        for (int j = 0; j < 32; ++j) if (vals[j] > bv) { bv = vals[j]; bj = j; }
        int bm = bj*64 + lane;
        u32 fb = __float_as_uint(bv);
        fb = (fb & 0x80000000u) ? ~fb : (fb | 0x80000000u);
        u64 key = ((u64)fb << 32) | (u32)(~bm);
        #pragma unroll
        for (int o2 = 1; o2 < 64; o2 <<= 1) {
            u64 other = __shfl_xor(key, o2, 64);
            key = (other > key) ? other : key;
        }
        int wm = (int)(~(u32)key);
        if (lane == 0) idx[((size_t)b*NN + n)*KNB + k] = wm;
        int wl = wm & 63, wj = wm >> 6;
        if (lane == wl) {
            #pragma unroll
            for (int j = 0; j < 32; ++j) if (j == wj) vals[j] = -3.4e38f;
        }
    }
}

// fused graph-feature + edge conv1 GEMM: computes z = w1*g on the fly (g from xa+idx),
// writes z1 (d-major) + per-block stats partials. Bit-identical z to the old gfeat->estats path.
__global__ __launch_bounds__(256) void k_zstats(const float* __restrict__ xa, const int* __restrict__ idx,
        const float* __restrict__ w1, float* __restrict__ part1, float* __restrict__ z1) {
    __shared__ float w1s[64*28];
    __shared__ float wsum[4][64], wsq[4][64];
    int pt = blockIdx.x, b = blockIdx.y;
    int p0 = pt*256, tid = threadIdx.x;
    int p = p0 + tid;
    for (int l = tid; l < 64*28; l += 256) w1s[l] = w1[l];
    __syncthreads();
    int n = p >> 4;
    int mm = idx[((size_t)b*NN+n)*KNB + (p & 15)];
    float gr[28];
    #pragma unroll
    for (int c = 0; c < 14; ++c) {
        float ctr = xa[((size_t)b*14+c)*NN + n];
        float nb  = xa[((size_t)b*14+c)*NN + mm];
        gr[c] = ctr;
        gr[14+c] = nb - ctr;
    }
    int wv = tid>>6, lane = tid&63;
    for (int d = 0; d < 64; ++d) {
        float z = 0.f;
        #pragma unroll
        for (int c = 0; c < 28; ++c) z += w1s[d*28+c]*gr[c];
        z1[((size_t)b*64+d)*PP + p] = z;
        float s = z, q = z*z;
        #pragma unroll
        for (int o = 1; o < 64; o <<= 1) { s += __shfl_xor(s, o, 64); q += __shfl_xor(q, o, 64); }
        if (lane == 0) { wsum[wv][d] = s; wsq[wv][d] = q; }
    }
    __syncthreads();
    if (tid < 64) {
        float s = (wsum[0][tid]+wsum[1][tid])+(wsum[2][tid]+wsum[3][tid]);
        float q = (wsq[0][tid]+wsq[1][tid])+(wsq[2][tid]+wsq[3][tid]);
        size_t blk = (size_t)b*128 + pt;
        part1[(blk*64 + tid)*2+0] = s;
        part1[(blk*64 + tid)*2+1] = q;
    }
}

__global__ __launch_bounds__(256) void k_reduce(const float* __restrict__ part, float* __restrict__ stats, int nch, int nblk, double M) {
    __shared__ double sred[256], qred[256];
    int ch = blockIdx.x, tid = threadIdx.x;
    double s = 0.0, q = 0.0;
    for (int i = tid; i < nblk; i += 256) {
        s += (double)part[((size_t)i*nch + ch)*2 + 0];
        q += (double)part[((size_t)i*nch + ch)*2 + 1];
    }
    sred[tid] = s; qred[tid] = q;
    __syncthreads();
    for (int off = 128; off > 0; off >>= 1) {
        if (tid < off) { sred[tid] += sred[tid+off]; qred[tid] += qred[tid+off]; }
        __syncthreads();
    }
    if (tid == 0) {
        double mu = sred[0] / M;
        double var = qred[0] / M - mu*mu;
        if (var < 0.0) var = 0.0;
        stats[ch*2+0] = (float)mu;
        stats[ch*2+1] = 1.0f / sqrtf((float)var + EPSB);
    }
}

// edge conv1 apply from stored z1: norm+LIF -> h1b (channel-major bits) + h1n (per-point mask)
__global__ __launch_bounds__(256) void k_h1(const float* __restrict__ z1,
        const float* __restrict__ st1, const float* __restrict__ g1, const float* __restrict__ be1,
        u64* __restrict__ h1b, u64* __restrict__ h1n) {
    int tid = threadIdx.x;
    int b = blockIdx.y;
    int p0 = blockIdx.x*256;
    int p = p0 + tid;
    int wordbase = (p0>>6) + (tid>>6);
    u64 pm[TT] = {0,0,0,0};
    for (int d = 0; d < 64; ++d) {
        float z = z1[((size_t)b*64+d)*PP + p];
        float mu = st1[d*2+0], iv = st1[d*2+1];
        float v = 0.f;
        #pragma unroll
        for (int t = 0; t < TT; ++t) {
            float y = (z - mu) * iv * g1[t*64+d] + be1[t*64+d];
            float s = lif_step(v, y);
            u64 m = __ballot(s != 0.f);
            if ((tid & 63) == 0) h1b[((size_t)(t*BB+b)*64 + d)*512 + wordbase] = m;
            pm[t] |= ((u64)(s != 0.f)) << d;
        }
    }
    #pragma unroll
    for (int t = 0; t < TT; ++t) h1n[(size_t)(t*BB+b)*PP + p] = pm[t];
}

// ---------------- Tiled popcount Grams (exact int counts) ----------------
__global__ __launch_bounds__(256) void k_gram_h1(const u64* __restrict__ h1b, int* __restrict__ Mi) {
    __shared__ u64 tw[64*65];
    int tid = threadIdx.x;
    int w0 = blockIdx.x*64;
    int tb = blockIdx.y;
    int t = tb >> 3;
    const u64* src = h1b + (size_t)tb*64*512;
    for (int l = tid; l < 64*64; l += 256) {
        int c = l >> 6, w = l & 63;
        tw[c*65+w] = src[(size_t)c*512 + w0 + w];
    }
    __syncthreads();
    int q = tid >> 4, r = tid & 15;
    int acc[4][4];
    #pragma unroll
    for (int i=0;i<4;++i)
        #pragma unroll
        for (int j=0;j<4;++j) acc[i][j]=0;
    #pragma unroll 4
    for (int w = 0; w < 64; ++w) {
        u64 av[4], bv[4];
        #pragma unroll
        for (int i=0;i<4;++i) av[i] = tw[(q+16*i)*65+w];
        #pragma unroll
        for (int j=0;j<4;++j) bv[j] = tw[(r+16*j)*65+w];
        #pragma unroll
        for (int i=0;i<4;++i)
            #pragma unroll
            for (int j=0;j<4;++j) acc[i][j] += (int)__popcll(av[i]&bv[j]);
    }
    #pragma unroll
    for (int i=0;i<4;++i)
        #pragma unroll
        for (int j=0;j<4;++j)
            atomicAdd(&Mi[((size_t)t*64 + q+16*i)*64 + r+16*j], acc[i][j]);
}

template<int C>
__global__ __launch_bounds__(256) void k_gram2(const u64* __restrict__ bits, int* __restrict__ Mi) {
    __shared__ u64 ta[64*33], tbt[64*33];
    int tid = threadIdx.x;
    int ci0 = blockIdx.x*64, cj0 = blockIdx.y*64;
    int tb = blockIdx.z;
    int t = tb >> 3;
    const u64* srcA = bits + ((size_t)tb*C + ci0)*32;
    const u64* srcB = bits + ((size_t)tb*C + cj0)*32;
    for (int l = tid; l < 64*32; l += 256) {
        int rr = l >> 5, w = l & 31;
        ta[rr*33+w]  = srcA[(size_t)rr*32+w];
        tbt[rr*33+w] = srcB[(size_t)rr*32+w];
    }
    __syncthreads();
    int q = tid >> 4, r = tid & 15;
    int acc[4][4];
    #pragma unroll
    for (int i=0;i<4;++i)
        #pragma unroll
        for (int j=0;j<4;++j) acc[i][j]=0;
    #pragma unroll 4
    for (int w = 0; w < 32; ++w) {
        u64 av[4], bv[4];
        #pragma unroll
        for (int i=0;i<4;++i) av[i] = ta[(q+16*i)*33+w];
        #pragma unroll
        for (int j=0;j<4;++j) bv[j] = tbt[(r+16*j)*33+w];
        #pragma unroll
        for (int i=0;i<4;++i)
            #pragma unroll
            for (int j=0;j<4;++j) acc[i][j] += (int)__popcll(av[i]&bv[j]);
    }
    #pragma unroll
    for (int i=0;i<4;++i)
        #pragma unroll
        for (int j=0;j<4;++j)
            atomicAdd(&Mi[((size_t)t*C + ci0+q+16*i)*C + cj0+r+16*j], acc[i][j]);
}

// project int Gram through weights -> per-(t,ch) (mean, inv_std)
template<int CIN>
__global__ void k_proj(const int* __restrict__ Mf, const float* __restrict__ w,
        float* __restrict__ st, int COUT, double cnt) {
    __shared__ double z2s[256], mns[256];
    int ch = blockIdx.x, t = blockIdx.y, c2 = threadIdx.x;
    const int* Mt = Mf + (size_t)t*CIN*CIN;
    double y = 0.0;
    for (int c = 0; c < CIN; ++c)
        y += (double)w[(size_t)ch*CIN+c] * (double)Mt[(size_t)c*CIN + c2];
    double wc2 = (double)w[(size_t)ch*CIN+c2];
    z2s[c2] = wc2 * y;
    mns[c2] = wc2 * (double)Mt[(size_t)c2*CIN + c2];
    __syncthreads();
    for (int off = CIN>>1; off > 0; off >>= 1) {
        if (c2 < off) { z2s[c2] += z2s[c2+off]; mns[c2] += mns[c2+off]; }
        __syncthreads();
    }
    if (c2 == 0) {
        double mu = mns[0] / cnt;
        double var = z2s[0] / cnt - mu*mu;
        if (var < 0.0) var = 0.0;
        st[((size_t)t*COUT+ch)*2+0] = (float)mu;
        st[((size_t)t*COUT+ch)*2+1] = 1.0f / sqrtf((float)var + EPSB);
    }
}

// weight prep: fp32 w[F][K] -> exact 3-way bf16 split in MFMA-frag layout [K/8][F][8]
__global__ __launch_bounds__(256) void k_wprep(const float* __restrict__ w,
        short* __restrict__ hi, short* __restrict__ mid, short* __restrict__ lo, int F, int K) {
    int i = blockIdx.x*256 + threadIdx.x;
    if (i >= F*K) return;
    int f = i / K, k = i % K;
    float wv = w[i];
    u32 b0 = __float_as_uint(wv);
    float h = __uint_as_float(b0 & 0xFFFF0000u);
    float r1 = wv - h;
    u32 b1 = __float_as_uint(r1);
    float m = __uint_as_float(b1 & 0xFFFF0000u);
    float r2 = r1 - m;
    u32 b2 = __float_as_uint(r2);
    size_t o = ((size_t)(k>>3)*F + f)*8 + (k&7);
    hi[o]  = (short)(b0 >> 16);
    mid[o] = (short)(b1 >> 16);
    lo[o]  = (short)(b2 >> 16);
}

// ---------------- MFMA spike conv (KT=64 LDS weight tiles + LUT A-expansion) ----------------
template<int K, int F, int MODE, bool BITS>
__global__ __launch_bounds__(256) void k_mconv(
        const void* __restrict__ Asrc,
        const short* __restrict__ Whi, const short* __restrict__ Wmd, const short* __restrict__ Wlo,
        const float* __restrict__ st, const float* __restrict__ ga, const float* __restrict__ be,
        const float* __restrict__ bias,
        u16* __restrict__ outp, u32* __restrict__ outm, int NPTS) {
    constexpr int KT = 64;
    constexpr int ROWS = (KT/8)*3;
    constexpr int NW = (K+63)/64;
    __shared__ short wsm[ROWS*512];
    __shared__ short sptab[BITS ? 256*8 : 8];
    __shared__ u32 morr[TT][64];
    int tid = threadIdx.x;
    int wave = tid >> 6, lane = tid & 63;
    int l15 = lane & 15, lg = lane >> 4;
    int b = blockIdx.z;
    int n_base = blockIdx.x*64 + wave*16;
    int f0 = blockIdx.y*64;
    if (MODE == 0 || MODE == 2)
        for (int l = tid; l < TT*64; l += 256) morr[l>>6][l&63] = 0u;
    if (BITS) {
        #pragma unroll
        for (int j = 0; j < 8; ++j) sptab[tid*8+j] = (short)(((tid>>j)&1) * 0x3F80);
    }

    f4 acc[4][TT];
    #pragma unroll
    for (int i = 0; i < 4; ++i)
        #pragma unroll
        for (int t = 0; t < TT; ++t) acc[i][t] = (f4)0.f;

    u64 aw[TT][NW];
    const u16* Au[TT];
    #pragma unroll
    for (int t = 0; t < TT; ++t) {
        if (BITS) {
            const u64* Ab = (const u64*)Asrc + ((size_t)(t*BB+b)*NPTS + n_base + l15)*NW;
            #pragma unroll
            for (int wq = 0; wq < NW; ++wq) aw[t][wq] = Ab[wq];
        } else {
            Au[t] = (const u16*)Asrc + ((size_t)(t*BB+b)*NPTS + n_base + l15)*K + lg*8;
        }
    }
    const short* Wsrc[3] = {Whi, Wmd, Wlo};

    #pragma unroll
    for (int kt = 0; kt < K; kt += KT) {
        if (kt > 0) __syncthreads();
        #pragma unroll
        for (int r = wave; r < ROWS; r += 4) {
            int kq = r/3, s = r - kq*3;
            const short* g = Wsrc[s] + ((size_t)((kt>>3) + kq)*F + f0)*8 + lane*8;
            GLOAD_LDS16(g, &wsm[r*512]);
        }
        __syncthreads();
        #pragma unroll
        for (int k0 = 0; k0 < KT; k0 += 32) {
            int kg = kt + k0;
            short8 a[TT];
            #pragma unroll
            for (int t = 0; t < TT; ++t) {
                if (BITS) {
                    u32 byte = (u32)(aw[t][kg>>6] >> ((kg&63) + lg*8)) & 0xFFu;
                    a[t] = *(const short8*)(sptab + byte*8);
                } else {
                    a[t] = *(const short8*)(Au[t] + kg);
                }
            }
            int kql = (k0>>3) + lg;
            #pragma unroll
            for (int fs = 0; fs < 4; ++fs) {
                const short* base = wsm + kql*1536 + (fs*16+l15)*8;
                short8 whi = *(const short8*)(base);
                short8 wmd = *(const short8*)(base + 512);
                short8 wlo = *(const short8*)(base + 1024);
                #pragma unroll
                for (int t = 0; t < TT; ++t) {
                    acc[fs][t] = __builtin_amdgcn_mfma_f32_16x16x32_bf16(a[t], whi, acc[fs][t], 0, 0, 0);
                    acc[fs][t] = __builtin_amdgcn_mfma_f32_16x16x32_bf16(a[t], wmd, acc[fs][t], 0, 0, 0);
                    acc[fs][t] = __builtin_amdgcn_mfma_f32_16x16x32_bf16(a[t], wlo, acc[fs][t], 0, 0, 0);
                }
            }
        }
    }
    if (MODE == 1) {
        #pragma unroll
        for (int fs = 0; fs < 4; ++fs) {
            int f = f0 + fs*16 + l15;
            #pragma unroll
            for (int reg = 0; reg < 4; ++reg) {
                int n = n_base + lg*4 + reg;
                float v = 0.f;
                #pragma unroll
                for (int t = 0; t < TT; ++t) {
                    int ch = t*F + f;
                    float y = (acc[fs][t][reg] - st[(size_t)ch*2+0])*st[(size_t)ch*2+1]*ga[ch] + be[ch];
                    float s = lif_step(v, y);
                    outp[((size_t)(t*BB+b)*NPTS + n)*F + f] = (s != 0.f) ? (u16)0x3F80 : (u16)0;
                }
            }
        }
    } else if (MODE == 3) {
        #pragma unroll
        for (int fs = 0; fs < 4; ++fs) {
            int f = f0 + fs*16 + l15;
            u32 nib = 0u;
            #pragma unroll
            for (int reg = 0; reg < 4; ++reg) {
                float v = 0.f;
                #pragma unroll
                for (int t = 0; t < TT; ++t) {
                    int ch = t*F + f;
                    float y = (acc[fs][t][reg] - st[(size_t)ch*2+0])*st[(size_t)ch*2+1]*ga[ch] + be[ch];
                    float s = lif_step(v, y);
                    if (s != 0.f) nib |= (1u << t);
                }
            }
            nib |= __shfl_xor(nib, 16, 64);
            nib |= __shfl_xor(nib, 32, 64);
            if (lg == 0) {
                int n_pt = n_base >> 4;
                #pragma unroll
                for (int t = 0; t < TT; ++t)
                    outp[((size_t)(t*BB+b)*(NPTS>>4) + n_pt)*F + f] = ((nib>>t)&1u) ? (u16)0x3F80 : (u16)0;
            }
        }
    } else {
        #pragma unroll
        for (int fs = 0; fs < 4; ++fs) {
            int f = f0 + fs*16 + l15;
            u32 any[TT] = {0,0,0,0};
            float bb = (MODE == 0) ? bias[f] : 0.f;
            #pragma unroll
            for (int reg = 0; reg < 4; ++reg) {
                float v = 0.f;
                #pragma unroll
                for (int t = 0; t < TT; ++t) {
                    float y;
                    if (MODE == 0) y = acc[fs][t][reg] + bb;
                    else {
                        int ch = t*F + f;
                        y = (acc[fs][t][reg] - st[(size_t)ch*2+0])*st[(size_t)ch*2+1]*ga[ch] + be[ch];
                    }
                    float s = lif_step(v, y);
                    if (s != 0.f) any[t] = 1u;
                }
            }
            #pragma unroll
            for (int t = 0; t < TT; ++t) if (any[t]) atomicOr(&morr[t][fs*16+l15], 1u);
        }
        __syncthreads();
        for (int l = tid; l < TT*64; l += 256)
            if (morr[l>>6][l&63]) atomicOr(&outm[((size_t)((l>>6)*BB+b))*F + f0 + (l&63)], 1u);
    }
}

// repack point-major bf16-u16 spikes [t][b][n][C] -> channel-major bits [t][b][C][32 words over n]
template<int C>
__global__ __launch_bounds__(256) void k_repack(const u16* __restrict__ sp, u64* __restrict__ bits) {
    __shared__ u16 tile[64][C+2];
    int tid = threadIdx.x;
    int nw = blockIdx.x, b = blockIdx.y, t = blockIdx.z;
    const u16* src = sp + ((size_t)(t*BB+b)*NN + nw*64)*C;
    for (int i = tid*2; i < 64*C; i += 512) {
        u32 v = *(const u32*)(src + i);
        int r = i / C, c = i % C;
        *(u32*)&tile[r][c] = v;
    }
    __syncthreads();
    int wave = tid >> 6, lane = tid & 63;
    for (int c = wave; c < C; c += 4) {
        u64 m = __ballot(tile[lane][c] != 0);
        if (lane == 0) bits[((size_t)(t*BB+b)*C + c)*32 + nw] = m;
    }
}

__global__ __launch_bounds__(256) void k_out(const u32* __restrict__ mx4, float* __restrict__ out) {
    int i = blockIdx.x*256 + threadIdx.x;
    int b = i >> 10, g = i & 1023;
    float s = (float)(mx4[((size_t)0*BB+b)*1024+g] + mx4[((size_t)1*BB+b)*1024+g]
                    + mx4[((size_t)2*BB+b)*1024+g] + mx4[((size_t)3*BB+b)*1024+g]);
    out[i] = s * 0.25f;
}

extern "C" void kernel_launch(void* const* d_in, const int* in_sizes, int n_in,
                              void* d_out, int out_size, void* d_ws, size_t ws_size,
                              hipStream_t stream) {
    (void)in_sizes; (void)n_in; (void)out_size;
    const float* x    = (const float*)d_in[0];
    const float* tw1  = (const float*)d_in[1];
    const float* tb1  = (const float*)d_in[2];
    const float* tw2  = (const float*)d_in[3];
    const float* tb2  = (const float*)d_in[4];
    const float* tw3  = (const float*)d_in[5];
    const float* tb3  = (const float*)d_in[6];
    const float* tfw1 = (const float*)d_in[7];
    const float* tfb1 = (const float*)d_in[8];
    const float* tfw2 = (const float*)d_in[9];
    const float* tfb2 = (const float*)d_in[10];
    const float* tfw3 = (const float*)d_in[11];
    const float* tfb3 = (const float*)d_in[12];
    const float* w1   = (const float*)d_in[13];
    const float* w2   = (const float*)d_in[14];
    const float* w3   = (const float*)d_in[15];
    const float* w4   = (const float*)d_in[16];
    const float* g1   = (const float*)d_in[17];
    const float* be1  = (const float*)d_in[18];
    const float* g2   = (const float*)d_in[19];
    const float* be2  = (const float*)d_in[20];
    const float* g3   = (const float*)d_in[21];
    const float* be3  = (const float*)d_in[22];
    const float* g4   = (const float*)d_in[23];
    const float* be4  = (const float*)d_in[24];

    char* wsb = (char*)d_ws;
    size_t off = 0;
    auto alloc = [&](size_t bytes) -> void* {
        void* p = wsb + off;
        off = (off + bytes + 255) & ~(size_t)255;
        return p;
    };
    u64* s1b   = (u64*)alloc(sizeof(u64)*(size_t)TT*BB*NN);
    u64* s2b   = (u64*)alloc(sizeof(u64)*(size_t)TT*BB*NN*2);
    u32* mx    = (u32*)alloc(sizeof(u32)*(size_t)TT*BB*1024);
    u32* mx4   = (u32*)alloc(sizeof(u32)*(size_t)TT*BB*1024);
    float* trs = (float*)alloc(sizeof(float)*BB*9);
    float* xa  = (float*)alloc(sizeof(float)*(size_t)BB*14*NN);
    float4* xa4 = (float4*)alloc(sizeof(float4)*(size_t)BB*NN);
    int* idx   = (int*)alloc(sizeof(int)*(size_t)BB*NN*KNB);
    float* z1  = (float*)alloc(sizeof(float)*(size_t)BB*64*PP);
    float* part1 = (float*)alloc(sizeof(float)*(size_t)1024*64*2);
    float* st1 = (float*)alloc(sizeof(float)*64*2);
    float* st2 = (float*)alloc(sizeof(float)*512*2);
    float* st3 = (float*)alloc(sizeof(float)*1024*2);
    float* st4 = (float*)alloc(sizeof(float)*4096*2);
    float* h1v = (float*)alloc(sizeof(float)*(size_t)TT*BB*512);
    float* h2v = (float*)alloc(sizeof(float)*(size_t)TT*BB*256);
    u64* h1b = (u64*)alloc(sizeof(u64)*(size_t)TT*BB*64*512);
    u64* h1n = (u64*)alloc(sizeof(u64)*(size_t)TT*BB*PP);
    u16* m2p = (u16*)alloc(sizeof(u16)*(size_t)TT*BB*NN*128);
    u16* h3p = (u16*)alloc(sizeof(u16)*(size_t)TT*BB*NN*256);
    u64* m2b = (u64*)alloc(sizeof(u64)*(size_t)TT*BB*128*32);
    u64* h3b = (u64*)alloc(sizeof(u64)*(size_t)TT*BB*256*32);
    int* Mi64  = (int*)alloc(sizeof(int)*(size_t)TT*64*64);
    int* Mi128 = (int*)alloc(sizeof(int)*(size_t)TT*128*128);
    int* Mi256 = (int*)alloc(sizeof(int)*(size_t)TT*256*256);
    short* wp2h = (short*)alloc(sizeof(short)*(size_t)128*64);
    short* wp2m = (short*)alloc(sizeof(short)*(size_t)128*64);
    short* wp2l = (short*)alloc(sizeof(short)*(size_t)128*64);
    short* wp3h = (short*)alloc(sizeof(short)*(size_t)256*128);
    short* wp3m = (short*)alloc(sizeof(short)*(size_t)256*128);
    short* wp3l = (short*)alloc(sizeof(short)*(size_t)256*128);
    short* wp4h = (short*)alloc(sizeof(short)*(size_t)1024*256);
    short* wp4m = (short*)alloc(sizeof(short)*(size_t)1024*256);
    short* wp4l = (short*)alloc(sizeof(short)*(size_t)1024*256);
    short* wpth = (short*)alloc(sizeof(short)*(size_t)1024*128);
    short* wptm = (short*)alloc(sizeof(short)*(size_t)1024*128);
    short* wptl = (short*)alloc(sizeof(short)*(size_t)1024*128);
    if (off > ws_size) return;

    hipMemsetAsync(mx, 0, sizeof(u32)*(size_t)TT*BB*1024, stream);
    hipMemsetAsync(mx4, 0, sizeof(u32)*(size_t)TT*BB*1024, stream);
    hipMemsetAsync(Mi64, 0, sizeof(int)*(size_t)TT*64*64, stream);
    hipMemsetAsync(Mi128, 0, sizeof(int)*(size_t)TT*128*128, stream);
    hipMemsetAsync(Mi256, 0, sizeof(int)*(size_t)TT*256*256, stream);

    // weight prep (exact 3-way bf16 split)
    k_wprep<<<dim3((128*64+255)/256), dim3(256), 0, stream>>>(w2, wp2h, wp2m, wp2l, 128, 64);
    k_wprep<<<dim3((256*128+255)/256), dim3(256), 0, stream>>>(w3, wp3h, wp3m, wp3l, 256, 128);
    k_wprep<<<dim3((1024*256+255)/256), dim3(256), 0, stream>>>(w4, wp4h, wp4m, wp4l, 1024, 256);
    k_wprep<<<dim3((1024*128+255)/256), dim3(256), 0, stream>>>(tw3, wpth, wptm, wptl, 1024, 128);

    // T-Net
    k_tnet1<<<dim3(64), dim3(256), 0, stream>>>(x, tw1, tb1, s1b);
    k_tnet2<<<dim3(64, 4), dim3(256), 0, stream>>>(s1b, tw2, tb2, (u32*)s2b);
    k_mconv<128,1024,0,true><<<dim3(32,16,8), dim3(256), 0, stream>>>(
        s2b, wpth, wptm, wptl, nullptr, nullptr, nullptr, tb3, nullptr, mx, NN);
    k_fc1<<<dim3(512, 8), dim3(64), 0, stream>>>(mx, tfw1, tfb1, h1v);
    k_fc2<<<dim3(256, 8), dim3(64), 0, stream>>>(h1v, tfw2, tfb2, h2v);
    k_fc3<<<dim3(8), dim3(64), 0, stream>>>(h2v, tfw3, tfb3, trs);
    k_trans<<<dim3(64), dim3(256), 0, stream>>>(x, trs, xa, xa4);
    // KNN (wave-per-query)
    k_knn<<<dim3(NN/4, BB), dim3(256), 0, stream>>>(xa4, idx);
    // fused graph-feature + edge conv1 GEMM (z once) + stats partials
    k_zstats<<<dim3(128, 8), dim3(256), 0, stream>>>(xa, idx, w1, part1, z1);
    k_reduce<<<dim3(64), dim3(256), 0, stream>>>(part1, st1, 64, 1024, 262144.0);
    k_h1<<<dim3(128, 8), dim3(256), 0, stream>>>(z1, st1, g1, be1, h1b, h1n);
    // edge conv2: stats via tiled Gram, apply via MFMA (+ max over k)
    k_gram_h1<<<dim3(8, TT*BB), dim3(256), 0, stream>>>(h1b, Mi64);
    k_proj<64><<<dim3(128, TT), dim3(64), 0, stream>>>(Mi64, w2, st2, 128, 262144.0);
    k_mconv<64,128,3,true><<<dim3(PP/64,2,8), dim3(256), 0, stream>>>(
        h1n, wp2h, wp2m, wp2l, st2, g2, be2, nullptr, m2p, nullptr, PP);
    k_repack<128><<<dim3(32,8,4), dim3(256), 0, stream>>>(m2p, m2b);
    // conv3
    k_gram2<128><<<dim3(2,2,TT*BB), dim3(256), 0, stream>>>(m2b, Mi128);
    k_proj<128><<<dim3(256, TT), dim3(128), 0, stream>>>(Mi128, w3, st3, 256, 16384.0);
    k_mconv<128,256,1,false><<<dim3(32,4,8), dim3(256), 0, stream>>>(
        m2p, wp3h, wp3m, wp3l, st3, g3, be3, nullptr, h3p, nullptr, NN);
    k_repack<256><<<dim3(32,8,4), dim3(256), 0, stream>>>(h3p, h3b);
    // conv4
    k_gram2<256><<<dim3(4,4,TT*BB), dim3(256), 0, stream>>>(h3b, Mi256);
    k_proj<256><<<dim3(1024, TT), dim3(256), 0, stream>>>(Mi256, w4, st4, 1024, 16384.0);
    k_mconv<256,1024,2,false><<<dim3(32,16,8), dim3(256), 0, stream>>>(
        h3p, wp4h, wp4m, wp4l, st4, g4, be4, nullptr, nullptr, mx4, NN);
    // output
    k_out<<<dim3(32), dim3(256), 0, stream>>>(mx4, (float*)d_out);
}